// Round 1
// baseline (1935.458 us; speedup 1.0000x reference)
//
#include <hip/hip_runtime.h>
#include <hip/hip_bf16.h>

#define B_ 8
#define S_ 2048
#define E_ 256
#define FF_ 1024
#define NQ_ 8
#define NC_ 10
#define BS_ (B_*S_)

typedef __bf16 bf16x8 __attribute__((ext_vector_type(8)));
typedef float f32x4 __attribute__((ext_vector_type(4)));

#define MFMA16(a,b,c) __builtin_amdgcn_mfma_f32_16x16x32_bf16(a,b,c,0,0,0)

// ---------------- embed + positional encoding ----------------
__global__ __launch_bounds__(256) void k_embed(const int* __restrict__ tokens,
                                               const float* __restrict__ emb,
                                               float* __restrict__ x) {
    int row = blockIdx.x;           // 0..BS_-1
    int e = threadIdx.x;            // 0..255
    int s = row & (S_ - 1);
    int tok = tokens[row];
    int i2 = e & ~1;                // 2*(e/2)
    float d = expf((float)i2 * (-9.210340371976184f / 256.0f));
    float ang = (float)s * d;
    float pe = (e & 1) ? cosf(ang) : sinf(ang);
    x[(size_t)row * E_ + e] = emb[(size_t)tok * E_ + e] + pe;
}

// ---------------- quantum attention: q from x ----------------
__global__ __launch_bounds__(256) void k_qcompute(const float* __restrict__ x,
                                                  const float* __restrict__ phi_l,
                                                  __hip_bfloat16* __restrict__ qbf) {
    int t = blockIdx.x * 256 + threadIdx.x;   // over BS_*32 heads
    int head = t & 31;
    size_t row = (size_t)(t >> 5);
    const float* xp = x + row * E_ + head * 8;
    f32x4 x0 = *(const f32x4*)xp;
    f32x4 x1 = *(const f32x4*)(xp + 4);
    float c[8];
#pragma unroll
    for (int j = 0; j < 4; j++) {
        c[j]     = cosf(x0[j] + phi_l[j]);
        c[4 + j] = cosf(x1[j] + phi_l[4 + j]);
    }
    float q[8];
    float run = c[0];
#pragma unroll
    for (int i = 1; i < 8; i++) { run *= c[i]; q[i] = run; }
    float o0 = c[1];
#pragma unroll
    for (int i = 2; i < 8; i++) o0 *= c[i];
    q[0] = o0;
    bf16x8 v;
#pragma unroll
    for (int j = 0; j < 8; j++) v[j] = (__bf16)q[j];
    *(bf16x8*)(qbf + row * E_ + head * 8) = v;
}

// ---------------- transpose q: (b,t,e) -> (b,e,t) ----------------
__global__ __launch_bounds__(256) void k_qtrans(const __hip_bfloat16* __restrict__ qbf,
                                                __hip_bfloat16* __restrict__ qT) {
    __shared__ __align__(16) __bf16 tile[64][72];
    int t0 = blockIdx.x * 64;
    int e0 = blockIdx.y * 64;
    int b  = blockIdx.z;
    int tid = threadIdx.x;
#pragma unroll
    for (int half = 0; half < 2; half++) {
        int r  = half * 32 + (tid >> 3);
        int c8 = (tid & 7) * 8;
        *(bf16x8*)&tile[r][c8] =
            *(const bf16x8*)(qbf + ((size_t)b * S_ + t0 + r) * E_ + e0 + c8);
    }
    __syncthreads();
#pragma unroll
    for (int half = 0; half < 2; half++) {
        int el = half * 32 + (tid >> 3);
        int t8 = (tid & 7) * 8;
        bf16x8 v;
#pragma unroll
        for (int j = 0; j < 8; j++) v[j] = tile[t8 + j][el];
        *(bf16x8*)(qT + ((size_t)b * E_ + e0 + el) * S_ + t0 + t8) = v;
    }
}

// ---------------- flash attention (bf16 MFMA) ----------------
// grid (64, 8): blockIdx.x = 32-row q-tile, blockIdx.y = batch. 256 thr = 4 waves.
// wave: rows = qtile*32 + (w>>1)*16, E-half = (w&1)*128.
__global__ __launch_bounds__(256) void k_attn(const __hip_bfloat16* __restrict__ qbf,
                                              const __hip_bfloat16* __restrict__ qT,
                                              float* __restrict__ out) {
    __shared__ __align__(16) __bf16 plds[4][16][40];   // per-wave P tile, 80B rows
    const float SCALE = 0.3535533905932738f;           // 1/sqrt(8)
    int b    = blockIdx.y;
    int wv   = threadIdx.x >> 6;
    int lane = threadIdx.x & 63;
    int r16  = lane & 15;
    int kg   = lane >> 4;
    int qbase = blockIdx.x * 32 + (wv >> 1) * 16;
    int ebase = (wv & 1) * 128;

    bf16x8 aq[8];
#pragma unroll
    for (int kk = 0; kk < 8; kk++)
        aq[kk] = *(const bf16x8*)(qbf + ((size_t)b * S_ + qbase + r16) * E_ + kk * 32 + kg * 8);

    f32x4 acc[8];
#pragma unroll
    for (int cf = 0; cf < 8; cf++) acc[cf] = (f32x4){0.f, 0.f, 0.f, 0.f};
    float mrow[4] = {-1e30f, -1e30f, -1e30f, -1e30f};
    float lrow[4] = {0.f, 0.f, 0.f, 0.f};

    for (int kt = 0; kt < 64; kt++) {
        int kbase = kt * 32;
        f32x4 s0 = (f32x4){0.f,0.f,0.f,0.f}, s1 = (f32x4){0.f,0.f,0.f,0.f};
#pragma unroll
        for (int kk = 0; kk < 8; kk++) {
            bf16x8 b0 = *(const bf16x8*)(qbf + ((size_t)b * S_ + kbase + r16) * E_ + kk * 32 + kg * 8);
            bf16x8 b1 = *(const bf16x8*)(qbf + ((size_t)b * S_ + kbase + 16 + r16) * E_ + kk * 32 + kg * 8);
            s0 = MFMA16(aq[kk], b0, s0);
            s1 = MFMA16(aq[kk], b1, s1);
        }
        float p0[4], p1[4], corr[4];
#pragma unroll
        for (int i = 0; i < 4; i++) {
            float a0 = s0[i] * SCALE, a1 = s1[i] * SCALE;
            float tm = fmaxf(a0, a1);
            tm = fmaxf(tm, __shfl_xor(tm, 1));
            tm = fmaxf(tm, __shfl_xor(tm, 2));
            tm = fmaxf(tm, __shfl_xor(tm, 4));
            tm = fmaxf(tm, __shfl_xor(tm, 8));
            float mn = fmaxf(mrow[i], tm);
            corr[i] = __expf(mrow[i] - mn);
            mrow[i] = mn;
            p0[i] = __expf(a0 - mn);
            p1[i] = __expf(a1 - mn);
            float rs = p0[i] + p1[i];
            rs += __shfl_xor(rs, 1);
            rs += __shfl_xor(rs, 2);
            rs += __shfl_xor(rs, 4);
            rs += __shfl_xor(rs, 8);
            lrow[i] = lrow[i] * corr[i] + rs;
        }
#pragma unroll
        for (int cf = 0; cf < 8; cf++)
#pragma unroll
            for (int i = 0; i < 4; i++) acc[cf][i] *= corr[i];

        // P (C-layout) -> LDS -> A-fragment
#pragma unroll
        for (int i = 0; i < 4; i++) {
            plds[wv][kg * 4 + i][r16]      = (__bf16)p0[i];
            plds[wv][kg * 4 + i][16 + r16] = (__bf16)p1[i];
        }
        asm volatile("s_waitcnt lgkmcnt(0)" ::: "memory");
        bf16x8 pa = *(const bf16x8*)&plds[wv][r16][kg * 8];

        // PV: B-operand from transposed q
#pragma unroll
        for (int cf = 0; cf < 8; cf++) {
            bf16x8 bv = *(const bf16x8*)(qT + ((size_t)b * E_ + ebase + cf * 16 + r16) * S_ + kbase + kg * 8);
            acc[cf] = MFMA16(pa, bv, acc[cf]);
        }
    }
#pragma unroll
    for (int i = 0; i < 4; i++) {
        float inv = 1.0f / lrow[i];
        size_t orow = (size_t)b * S_ + qbase + kg * 4 + i;
#pragma unroll
        for (int cf = 0; cf < 8; cf++)
            out[orow * E_ + ebase + cf * 16 + r16] = acc[cf][i] * inv;
    }
}

// ---------------- layernorm: x = LN(x + y)*g + b ----------------
__global__ __launch_bounds__(256) void k_ln(float* __restrict__ x, const float* __restrict__ y,
                                            const float* __restrict__ g, const float* __restrict__ bb) {
    int wv = threadIdx.x >> 6, lane = threadIdx.x & 63;
    size_t row = (size_t)blockIdx.x * 4 + wv;
    f32x4 xv = ((const f32x4*)(x + row * E_))[lane];
    f32x4 yv = ((const f32x4*)(y + row * E_))[lane];
    f32x4 v;
    float s = 0.f, sq = 0.f;
#pragma unroll
    for (int j = 0; j < 4; j++) { v[j] = xv[j] + yv[j]; s += v[j]; sq += v[j] * v[j]; }
#pragma unroll
    for (int m = 1; m <= 32; m <<= 1) { s += __shfl_xor(s, m); sq += __shfl_xor(sq, m); }
    float mean = s * (1.f / E_);
    float var = sq * (1.f / E_) - mean * mean;
    float rstd = rsqrtf(var + 1e-5f);
    f32x4 gv = ((const f32x4*)g)[lane];
    f32x4 bv = ((const f32x4*)bb)[lane];
    f32x4 o;
#pragma unroll
    for (int j = 0; j < 4; j++) o[j] = (v[j] - mean) * rstd * gv[j] + bv[j];
    ((f32x4*)(x + row * E_))[lane] = o;
}

// ---------------- W2 transpose to bf16: (1024,256) -> (256,1024) ----------------
__global__ __launch_bounds__(256) void k_w2t(const float* __restrict__ W2l,
                                             __hip_bfloat16* __restrict__ w2t) {
    int o = blockIdx.x * 256 + threadIdx.x;   // 0..E_*FF_-1
    int e = o >> 10, k = o & (FF_ - 1);
    w2t[o] = __float2bfloat16(W2l[(size_t)k * E_ + e]);
}

// ---------------- FFN stage 1: h = relu(qm@W1 + b1) (bf16 out) ----------------
__global__ __launch_bounds__(256) void k_ffn1(const float* __restrict__ x,
                                              const float* __restrict__ theta_l,
                                              const float* __restrict__ W1l,
                                              const float* __restrict__ b1l,
                                              __hip_bfloat16* __restrict__ hbf) {
    __shared__ float qm[8][8];
    int tid = threadIdx.x;
    int rbase = blockIdx.x * 8;
    if (tid < 64) {
        int r = tid >> 3, i = tid & 7;
        qm[r][i] = cosf(x[(size_t)(rbase + r) * E_ + i]) * cosf(theta_l[i]);
    }
    __syncthreads();
#pragma unroll
    for (int jj = 0; jj < 4; jj++) {
        int j = jj * 256 + tid;
        float w1v[8];
#pragma unroll
        for (int i = 0; i < 8; i++) w1v[i] = W1l[i * FF_ + j];
        float bj = b1l[j];
#pragma unroll
        for (int r = 0; r < 8; r++) {
            float a = bj;
#pragma unroll
            for (int i = 0; i < 8; i++) a += qm[r][i] * w1v[i];
            hbf[(size_t)(rbase + r) * FF_ + j] = __float2bfloat16(fmaxf(a, 0.f));
        }
    }
}

// ---------------- FFN stage 2: f = h@W2 + b2 (MFMA) ----------------
// grid 512: 32 rows per block; wave: 16 rows x 128-col E-half.
__global__ __launch_bounds__(256) void k_ffn2(const __hip_bfloat16* __restrict__ hbf,
                                              const __hip_bfloat16* __restrict__ w2t,
                                              const float* __restrict__ b2l,
                                              float* __restrict__ fout) {
    int wv = threadIdx.x >> 6, lane = threadIdx.x & 63;
    int r16 = lane & 15, kg = lane >> 4;
    int rbase = blockIdx.x * 32 + (wv >> 1) * 16;
    int ebase = (wv & 1) * 128;
    f32x4 acc[8];
#pragma unroll
    for (int cf = 0; cf < 8; cf++) acc[cf] = (f32x4){0.f, 0.f, 0.f, 0.f};
    for (int kt = 0; kt < FF_ / 32; kt++) {
        bf16x8 ah = *(const bf16x8*)(hbf + (size_t)(rbase + r16) * FF_ + kt * 32 + kg * 8);
#pragma unroll
        for (int cf = 0; cf < 8; cf++) {
            bf16x8 bw = *(const bf16x8*)(w2t + (size_t)(ebase + cf * 16 + r16) * FF_ + kt * 32 + kg * 8);
            acc[cf] = MFMA16(ah, bw, acc[cf]);
        }
    }
#pragma unroll
    for (int i = 0; i < 4; i++) {
        size_t orow = (size_t)rbase + kg * 4 + i;
#pragma unroll
        for (int cf = 0; cf < 8; cf++) {
            int e = ebase + cf * 16 + r16;
            fout[orow * E_ + e] = acc[cf][i] + b2l[e];
        }
    }
}

// ---------------- mean over S (two-stage, deterministic) ----------------
__global__ __launch_bounds__(256) void k_mean(const float* __restrict__ x, float* __restrict__ psum) {
    int c = blockIdx.x, b = blockIdx.y, e = threadIdx.x;
    float s = 0.f;
    size_t base = ((size_t)b * S_ + c * 128) * E_ + e;
    for (int r = 0; r < 128; r++) s += x[base + (size_t)r * E_];
    psum[(c * 8 + b) * E_ + e] = s;
}

__global__ __launch_bounds__(256) void k_mean2(const float* __restrict__ psum, float* __restrict__ xmean) {
    int idx = blockIdx.x * 256 + threadIdx.x;   // 0..2047 -> (b,e)
    int b = idx >> 8, e = idx & 255;
    float s = 0.f;
    for (int c = 0; c < 16; c++) s += psum[(c * 8 + b) * E_ + e];
    xmean[idx] = s * (1.f / S_);
}

// ---------------- classifier ----------------
__global__ __launch_bounds__(128) void k_cls(const float* __restrict__ xmean,
                                             const float* __restrict__ Wc,
                                             const float* __restrict__ bc,
                                             float* __restrict__ outp) {
    int t = threadIdx.x;
    if (t >= B_ * NC_) return;
    int b = t / NC_, c = t % NC_;
    float s = bc[c];
    for (int e = 0; e < E_; e++) s += xmean[b * E_ + e] * Wc[e * NC_ + c];
    outp[t] = s;
}

extern "C" void kernel_launch(void* const* d_in, const int* in_sizes, int n_in,
                              void* d_out, int out_size, void* d_ws, size_t ws_size,
                              hipStream_t stream) {
    (void)in_sizes; (void)n_in; (void)out_size; (void)ws_size;
    const int*   tokens = (const int*)d_in[0];
    const float* emb    = (const float*)d_in[1];
    const float* phi    = (const float*)d_in[2];
    const float* theta  = (const float*)d_in[3];
    const float* W1     = (const float*)d_in[4];
    const float* b1     = (const float*)d_in[5];
    const float* W2     = (const float*)d_in[6];
    const float* b2     = (const float*)d_in[7];
    const float* g1     = (const float*)d_in[8];
    const float* beta1  = (const float*)d_in[9];
    const float* g2     = (const float*)d_in[10];
    const float* beta2  = (const float*)d_in[11];
    const float* Wc     = (const float*)d_in[12];
    const float* bc     = (const float*)d_in[13];
    float* outp = (float*)d_out;

    // workspace layout
    float* xbuf = (float*)d_ws;                                   // BS_*E_ f32
    float* ybuf = xbuf + (size_t)BS_ * E_;                        // BS_*E_ f32
    __hip_bfloat16* qbf = (__hip_bfloat16*)(ybuf + (size_t)BS_ * E_);  // BS_*E_ bf16
    __hip_bfloat16* qT  = qbf + (size_t)BS_ * E_;                 // BS_*E_ bf16
    __hip_bfloat16* hbf = qT + (size_t)BS_ * E_;                  // BS_*FF_ bf16
    __hip_bfloat16* w2t = hbf + (size_t)BS_ * FF_;                // E_*FF_ bf16
    float* psum  = (float*)(w2t + (size_t)E_ * FF_);              // 16*8*E_ f32
    float* xmean = psum + 16 * 8 * E_;                            // B_*E_ f32

    k_embed<<<BS_, 256, 0, stream>>>(tokens, emb, xbuf);

    for (int l = 0; l < 4; l++) {
        k_qcompute<<<BS_ * 32 / 256, 256, 0, stream>>>(xbuf, phi + l * NQ_, qbf);
        k_qtrans<<<dim3(S_ / 64, E_ / 64, B_), 256, 0, stream>>>(qbf, qT);
        k_attn<<<dim3(S_ / 32, B_), 256, 0, stream>>>(qbf, qT, ybuf);
        k_ln<<<BS_ / 4, 256, 0, stream>>>(xbuf, ybuf, g1 + l * E_, beta1 + l * E_);
        k_w2t<<<E_ * FF_ / 256, 256, 0, stream>>>(W2 + (size_t)l * FF_ * E_, w2t);
        k_ffn1<<<BS_ / 8, 256, 0, stream>>>(xbuf, theta + l * NQ_,
                                            W1 + (size_t)l * NQ_ * FF_, b1 + (size_t)l * FF_, hbf);
        k_ffn2<<<BS_ / 32, 256, 0, stream>>>(hbf, w2t, b2 + (size_t)l * E_, ybuf);
        k_ln<<<BS_ / 4, 256, 0, stream>>>(xbuf, ybuf, g2 + l * E_, beta2 + l * E_);
    }

    k_mean<<<dim3(16, B_), 256, 0, stream>>>(xbuf, psum);
    k_mean2<<<8, 256, 0, stream>>>(psum, xmean);
    k_cls<<<1, 128, 0, stream>>>(xmean, Wc, bc, outp);
}

// Round 2
// 1911.643 us; speedup vs baseline: 1.0125x; 1.0125x over previous
//
#include <hip/hip_runtime.h>
#include <hip/hip_bf16.h>

#define B_ 8
#define S_ 2048
#define E_ 256
#define FF_ 1024
#define NQ_ 8
#define NC_ 10
#define BS_ (B_*S_)
#define NSPLIT 2
#define KVBLK 64

typedef __bf16 bf16x8 __attribute__((ext_vector_type(8)));
typedef float f32x4 __attribute__((ext_vector_type(4)));

#define MFMA16(a,b,c) __builtin_amdgcn_mfma_f32_16x16x32_bf16(a,b,c,0,0,0)

// ---------------- embed + positional encoding ----------------
__global__ __launch_bounds__(256) void k_embed(const int* __restrict__ tokens,
                                               const float* __restrict__ emb,
                                               float* __restrict__ x) {
    int row = blockIdx.x;           // 0..BS_-1
    int e = threadIdx.x;            // 0..255
    int s = row & (S_ - 1);
    int tok = tokens[row];
    int i2 = e & ~1;                // 2*(e/2)
    float d = expf((float)i2 * (-9.210340371976184f / 256.0f));
    float ang = (float)s * d;
    float pe = (e & 1) ? cosf(ang) : sinf(ang);
    x[(size_t)row * E_ + e] = emb[(size_t)tok * E_ + e] + pe;
}

// ---------------- quantum attention: q from x ----------------
__global__ __launch_bounds__(256) void k_qcompute(const float* __restrict__ x,
                                                  const float* __restrict__ phi_l,
                                                  __hip_bfloat16* __restrict__ qbf) {
    int t = blockIdx.x * 256 + threadIdx.x;   // over BS_*32 heads
    int head = t & 31;
    size_t row = (size_t)(t >> 5);
    const float* xp = x + row * E_ + head * 8;
    f32x4 x0 = *(const f32x4*)xp;
    f32x4 x1 = *(const f32x4*)(xp + 4);
    float c[8];
#pragma unroll
    for (int j = 0; j < 4; j++) {
        c[j]     = cosf(x0[j] + phi_l[j]);
        c[4 + j] = cosf(x1[j] + phi_l[4 + j]);
    }
    float q[8];
    float run = c[0];
#pragma unroll
    for (int i = 1; i < 8; i++) { run *= c[i]; q[i] = run; }
    float o0 = c[1];
#pragma unroll
    for (int i = 2; i < 8; i++) o0 *= c[i];
    q[0] = o0;
    bf16x8 v;
#pragma unroll
    for (int j = 0; j < 8; j++) v[j] = (__bf16)q[j];
    *(bf16x8*)(qbf + row * E_ + head * 8) = v;
}

// ---------------- transpose q: (b,t,e) -> (b,e,t) ----------------
__global__ __launch_bounds__(256) void k_qtrans(const __hip_bfloat16* __restrict__ qbf,
                                                __hip_bfloat16* __restrict__ qT) {
    __shared__ __align__(16) __bf16 tile[64][72];
    int t0 = blockIdx.x * 64;
    int e0 = blockIdx.y * 64;
    int b  = blockIdx.z;
    int tid = threadIdx.x;
#pragma unroll
    for (int half = 0; half < 2; half++) {
        int r  = half * 32 + (tid >> 3);
        int c8 = (tid & 7) * 8;
        *(bf16x8*)&tile[r][c8] =
            *(const bf16x8*)(qbf + ((size_t)b * S_ + t0 + r) * E_ + e0 + c8);
    }
    __syncthreads();
#pragma unroll
    for (int half = 0; half < 2; half++) {
        int el = half * 32 + (tid >> 3);
        int t8 = (tid & 7) * 8;
        bf16x8 v;
#pragma unroll
        for (int j = 0; j < 8; j++) v[j] = tile[t8 + j][el];
        *(bf16x8*)(qT + ((size_t)b * E_ + e0 + el) * S_ + t0 + t8) = v;
    }
}

// ---------------- flash attention, KV-split partials (bf16 MFMA) ----------------
// grid (S_/32, B_, NSPLIT). 256 thr = 4 waves.
// wave: rows = qtile*32 + (w>>1)*16, E-half = (w&1)*128. KV tile = 64 keys.
__global__ __launch_bounds__(256, 4) void k_attn(const __hip_bfloat16* __restrict__ qbf,
                                                 const __hip_bfloat16* __restrict__ qT,
                                                 float* __restrict__ pacc,
                                                 float* __restrict__ pm,
                                                 float* __restrict__ pl) {
    __shared__ __align__(16) __bf16 plds[4][16][72];   // per-wave P tile (16x64 + pad)
    const float SCALE = 0.3535533905932738f;           // 1/sqrt(8)
    int b    = blockIdx.y;
    int z    = blockIdx.z;
    int wv   = threadIdx.x >> 6;
    int lane = threadIdx.x & 63;
    int r16  = lane & 15;
    int kg   = lane >> 4;
    int qbase = blockIdx.x * 32 + (wv >> 1) * 16;
    int ebase = (wv & 1) * 128;

    bf16x8 aq[8];
#pragma unroll
    for (int kk = 0; kk < 8; kk++)
        aq[kk] = *(const bf16x8*)(qbf + ((size_t)b * S_ + qbase + r16) * E_ + kk * 32 + kg * 8);

    f32x4 acc[8];
#pragma unroll
    for (int cf = 0; cf < 8; cf++) acc[cf] = (f32x4){0.f, 0.f, 0.f, 0.f};
    float mrow[4] = {-1e30f, -1e30f, -1e30f, -1e30f};
    float lrow[4] = {0.f, 0.f, 0.f, 0.f};

    int k0 = z * (S_ / NSPLIT);
    for (int kt = 0; kt < (S_ / NSPLIT) / KVBLK; kt++) {
        int kbase = k0 + kt * KVBLK;
        f32x4 s[4];
#pragma unroll
        for (int c = 0; c < 4; c++) s[c] = (f32x4){0.f, 0.f, 0.f, 0.f};
#pragma unroll
        for (int c = 0; c < 4; c++) {
#pragma unroll
            for (int kk = 0; kk < 8; kk++) {
                bf16x8 bk = *(const bf16x8*)(qbf + ((size_t)b * S_ + kbase + c * 16 + r16) * E_ + kk * 32 + kg * 8);
                s[c] = MFMA16(aq[kk], bk, s[c]);
            }
        }
        float corr[4];
#pragma unroll
        for (int i = 0; i < 4; i++) {
            float a0 = s[0][i] * SCALE, a1 = s[1][i] * SCALE;
            float a2 = s[2][i] * SCALE, a3 = s[3][i] * SCALE;
            float tm = fmaxf(fmaxf(a0, a1), fmaxf(a2, a3));
            tm = fmaxf(tm, __shfl_xor(tm, 1));
            tm = fmaxf(tm, __shfl_xor(tm, 2));
            tm = fmaxf(tm, __shfl_xor(tm, 4));
            tm = fmaxf(tm, __shfl_xor(tm, 8));
            float mn = fmaxf(mrow[i], tm);
            corr[i] = __expf(mrow[i] - mn);
            mrow[i] = mn;
            float p0 = __expf(a0 - mn), p1 = __expf(a1 - mn);
            float p2 = __expf(a2 - mn), p3 = __expf(a3 - mn);
            plds[wv][kg * 4 + i][r16]      = (__bf16)p0;
            plds[wv][kg * 4 + i][16 + r16] = (__bf16)p1;
            plds[wv][kg * 4 + i][32 + r16] = (__bf16)p2;
            plds[wv][kg * 4 + i][48 + r16] = (__bf16)p3;
            // per-lane partial sum; 16-lane reduce deferred to epilogue
            lrow[i] = lrow[i] * corr[i] + ((p0 + p1) + (p2 + p3));
        }
#pragma unroll
        for (int cf = 0; cf < 8; cf++)
#pragma unroll
            for (int i = 0; i < 4; i++) acc[cf][i] *= corr[i];

        asm volatile("s_waitcnt lgkmcnt(0)" ::: "memory");
        bf16x8 pa0 = *(const bf16x8*)&plds[wv][r16][kg * 8];
        bf16x8 pa1 = *(const bf16x8*)&plds[wv][r16][32 + kg * 8];

#pragma unroll
        for (int cf = 0; cf < 8; cf++) {
            bf16x8 bv0 = *(const bf16x8*)(qT + ((size_t)b * E_ + ebase + cf * 16 + r16) * S_ + kbase + kg * 8);
            bf16x8 bv1 = *(const bf16x8*)(qT + ((size_t)b * E_ + ebase + cf * 16 + r16) * S_ + kbase + 32 + kg * 8);
            acc[cf] = MFMA16(pa0, bv0, acc[cf]);
            acc[cf] = MFMA16(pa1, bv1, acc[cf]);
        }
    }

    // epilogue: reduce lrow across the 16 lanes of the row group
#pragma unroll
    for (int i = 0; i < 4; i++) {
        lrow[i] += __shfl_xor(lrow[i], 1);
        lrow[i] += __shfl_xor(lrow[i], 2);
        lrow[i] += __shfl_xor(lrow[i], 4);
        lrow[i] += __shfl_xor(lrow[i], 8);
    }
    size_t prow = (size_t)z * BS_ + (size_t)b * S_ + qbase;
#pragma unroll
    for (int i = 0; i < 4; i++) {
        size_t orow = prow + kg * 4 + i;
#pragma unroll
        for (int cf = 0; cf < 8; cf++)
            pacc[orow * E_ + ebase + cf * 16 + r16] = acc[cf][i];
    }
    if ((wv & 1) == 0 && r16 == 0) {
#pragma unroll
        for (int i = 0; i < 4; i++) {
            pm[prow + kg * 4 + i] = mrow[i];
            pl[prow + kg * 4 + i] = lrow[i];
        }
    }
}

// ---------------- merge the NSPLIT partials ----------------
__global__ __launch_bounds__(256) void k_amerge(const float* __restrict__ pacc,
                                                const float* __restrict__ pm,
                                                const float* __restrict__ pl,
                                                float* __restrict__ out) {
    int wv = threadIdx.x >> 6, lane = threadIdx.x & 63;
    size_t row = (size_t)blockIdx.x * 4 + wv;     // 0..BS_-1
    float m0 = pm[row], m1 = pm[BS_ + row];
    float l0 = pl[row], l1 = pl[BS_ + row];
    float M = fmaxf(m0, m1);
    float w0 = __expf(m0 - M), w1 = __expf(m1 - M);
    float inv = 1.0f / (w0 * l0 + w1 * l1);
    w0 *= inv; w1 *= inv;
    f32x4 a0 = ((const f32x4*)(pacc + row * E_))[lane];
    f32x4 a1 = ((const f32x4*)(pacc + (size_t)BS_ * E_ + row * E_))[lane];
    f32x4 o;
#pragma unroll
    for (int j = 0; j < 4; j++) o[j] = w0 * a0[j] + w1 * a1[j];
    ((f32x4*)(out + row * E_))[lane] = o;
}

// ---------------- layernorm: x = LN(x + y)*g + b ----------------
__global__ __launch_bounds__(256) void k_ln(float* __restrict__ x, const float* __restrict__ y,
                                            const float* __restrict__ g, const float* __restrict__ bb) {
    int wv = threadIdx.x >> 6, lane = threadIdx.x & 63;
    size_t row = (size_t)blockIdx.x * 4 + wv;
    f32x4 xv = ((const f32x4*)(x + row * E_))[lane];
    f32x4 yv = ((const f32x4*)(y + row * E_))[lane];
    f32x4 v;
    float s = 0.f, sq = 0.f;
#pragma unroll
    for (int j = 0; j < 4; j++) { v[j] = xv[j] + yv[j]; s += v[j]; sq += v[j] * v[j]; }
#pragma unroll
    for (int m = 1; m <= 32; m <<= 1) { s += __shfl_xor(s, m); sq += __shfl_xor(sq, m); }
    float mean = s * (1.f / E_);
    float var = sq * (1.f / E_) - mean * mean;
    float rstd = rsqrtf(var + 1e-5f);
    f32x4 gv = ((const f32x4*)g)[lane];
    f32x4 bv = ((const f32x4*)bb)[lane];
    f32x4 o;
#pragma unroll
    for (int j = 0; j < 4; j++) o[j] = (v[j] - mean) * rstd * gv[j] + bv[j];
    ((f32x4*)(x + row * E_))[lane] = o;
}

// ---------------- W2 transpose to bf16 (tiled): (1024,256) -> (256,1024) ----------------
__global__ __launch_bounds__(256) void k_w2t(const float* __restrict__ W2l,
                                             __hip_bfloat16* __restrict__ w2t) {
    __shared__ __align__(16) __bf16 tile[64][72];
    int k0 = blockIdx.x * 64, e0 = blockIdx.y * 64;
    int tid = threadIdx.x;
#pragma unroll
    for (int half = 0; half < 2; half++) {
        int r  = half * 32 + (tid >> 3);      // k row
        int c8 = (tid & 7) * 8;               // e offset
        f32x4 v0 = *(const f32x4*)(W2l + (size_t)(k0 + r) * E_ + e0 + c8);
        f32x4 v1 = *(const f32x4*)(W2l + (size_t)(k0 + r) * E_ + e0 + c8 + 4);
#pragma unroll
        for (int j = 0; j < 4; j++) { tile[r][c8 + j] = (__bf16)v0[j]; tile[r][c8 + 4 + j] = (__bf16)v1[j]; }
    }
    __syncthreads();
#pragma unroll
    for (int half = 0; half < 2; half++) {
        int e  = half * 32 + (tid >> 3);
        int k8 = (tid & 7) * 8;
        bf16x8 v;
#pragma unroll
        for (int j = 0; j < 8; j++) v[j] = tile[k8 + j][e];
        *(bf16x8*)(w2t + (size_t)(e0 + e) * FF_ + k0 + k8) = v;
    }
}

// ---------------- FFN stage 1: h = relu(qm@W1 + b1) (bf16 out) ----------------
__global__ __launch_bounds__(256) void k_ffn1(const float* __restrict__ x,
                                              const float* __restrict__ theta_l,
                                              const float* __restrict__ W1l,
                                              const float* __restrict__ b1l,
                                              __hip_bfloat16* __restrict__ hbf) {
    __shared__ float qm[8][8];
    int tid = threadIdx.x;
    int rbase = blockIdx.x * 8;
    if (tid < 64) {
        int r = tid >> 3, i = tid & 7;
        qm[r][i] = cosf(x[(size_t)(rbase + r) * E_ + i]) * cosf(theta_l[i]);
    }
    __syncthreads();
#pragma unroll
    for (int jj = 0; jj < 4; jj++) {
        int j = jj * 256 + tid;
        float w1v[8];
#pragma unroll
        for (int i = 0; i < 8; i++) w1v[i] = W1l[i * FF_ + j];
        float bj = b1l[j];
#pragma unroll
        for (int r = 0; r < 8; r++) {
            float a = bj;
#pragma unroll
            for (int i = 0; i < 8; i++) a += qm[r][i] * w1v[i];
            hbf[(size_t)(rbase + r) * FF_ + j] = __float2bfloat16(fmaxf(a, 0.f));
        }
    }
}

// ---------------- FFN stage 2: f = h@W2 + b2 (MFMA) ----------------
__global__ __launch_bounds__(256) void k_ffn2(const __hip_bfloat16* __restrict__ hbf,
                                              const __hip_bfloat16* __restrict__ w2t,
                                              const float* __restrict__ b2l,
                                              float* __restrict__ fout) {
    int wv = threadIdx.x >> 6, lane = threadIdx.x & 63;
    int r16 = lane & 15, kg = lane >> 4;
    int rbase = blockIdx.x * 32 + (wv >> 1) * 16;
    int ebase = (wv & 1) * 128;
    f32x4 acc[8];
#pragma unroll
    for (int cf = 0; cf < 8; cf++) acc[cf] = (f32x4){0.f, 0.f, 0.f, 0.f};
    for (int kt = 0; kt < FF_ / 32; kt++) {
        bf16x8 ah = *(const bf16x8*)(hbf + (size_t)(rbase + r16) * FF_ + kt * 32 + kg * 8);
#pragma unroll
        for (int cf = 0; cf < 8; cf++) {
            bf16x8 bw = *(const bf16x8*)(w2t + (size_t)(ebase + cf * 16 + r16) * FF_ + kt * 32 + kg * 8);
            acc[cf] = MFMA16(ah, bw, acc[cf]);
        }
    }
#pragma unroll
    for (int i = 0; i < 4; i++) {
        size_t orow = (size_t)rbase + kg * 4 + i;
#pragma unroll
        for (int cf = 0; cf < 8; cf++) {
            int e = ebase + cf * 16 + r16;
            fout[orow * E_ + e] = acc[cf][i] + b2l[e];
        }
    }
}

// ---------------- mean over S (two-stage, deterministic) ----------------
__global__ __launch_bounds__(256) void k_mean(const float* __restrict__ x, float* __restrict__ psum) {
    int c = blockIdx.x, b = blockIdx.y, e = threadIdx.x;
    float s = 0.f;
    size_t base = ((size_t)b * S_ + c * 128) * E_ + e;
    for (int r = 0; r < 128; r++) s += x[base + (size_t)r * E_];
    psum[(c * 8 + b) * E_ + e] = s;
}

__global__ __launch_bounds__(256) void k_mean2(const float* __restrict__ psum, float* __restrict__ xmean) {
    int idx = blockIdx.x * 256 + threadIdx.x;   // 0..2047 -> (b,e)
    int b = idx >> 8, e = idx & 255;
    float s = 0.f;
    for (int c = 0; c < 16; c++) s += psum[(c * 8 + b) * E_ + e];
    xmean[idx] = s * (1.f / S_);
}

// ---------------- classifier ----------------
__global__ __launch_bounds__(128) void k_cls(const float* __restrict__ xmean,
                                             const float* __restrict__ Wc,
                                             const float* __restrict__ bc,
                                             float* __restrict__ outp) {
    int t = threadIdx.x;
    if (t >= B_ * NC_) return;
    int b = t / NC_, c = t % NC_;
    float s = bc[c];
    for (int e = 0; e < E_; e++) s += xmean[b * E_ + e] * Wc[e * NC_ + c];
    outp[t] = s;
}

extern "C" void kernel_launch(void* const* d_in, const int* in_sizes, int n_in,
                              void* d_out, int out_size, void* d_ws, size_t ws_size,
                              hipStream_t stream) {
    (void)in_sizes; (void)n_in; (void)out_size; (void)ws_size;
    const int*   tokens = (const int*)d_in[0];
    const float* emb    = (const float*)d_in[1];
    const float* phi    = (const float*)d_in[2];
    const float* theta  = (const float*)d_in[3];
    const float* W1     = (const float*)d_in[4];
    const float* b1     = (const float*)d_in[5];
    const float* W2     = (const float*)d_in[6];
    const float* b2     = (const float*)d_in[7];
    const float* g1     = (const float*)d_in[8];
    const float* beta1  = (const float*)d_in[9];
    const float* g2     = (const float*)d_in[10];
    const float* beta2  = (const float*)d_in[11];
    const float* Wc     = (const float*)d_in[12];
    const float* bc     = (const float*)d_in[13];
    float* outp = (float*)d_out;

    // workspace layout
    float* xbuf = (float*)d_ws;                                   // BS_*E_ f32
    float* ybuf = xbuf + (size_t)BS_ * E_;                        // BS_*E_ f32
    __hip_bfloat16* qbf = (__hip_bfloat16*)(ybuf + (size_t)BS_ * E_);  // BS_*E_ bf16
    __hip_bfloat16* qT  = qbf + (size_t)BS_ * E_;                 // BS_*E_ bf16
    __hip_bfloat16* hbf = qT + (size_t)BS_ * E_;                  // BS_*FF_ bf16
    __hip_bfloat16* w2t = hbf + (size_t)BS_ * FF_;                // E_*FF_ bf16
    float* psum  = (float*)(w2t + (size_t)E_ * FF_);              // 16*8*E_ f32
    float* xmean = psum + 16 * 8 * E_;                            // B_*E_ f32
    float* pm    = xmean + B_ * E_;                               // NSPLIT*BS_ f32
    float* pl    = pm + NSPLIT * BS_;                             // NSPLIT*BS_ f32
    float* pacc  = (float*)hbf;                                   // overlay: NSPLIT*BS_*E_ f32 == BS_*FF_ bf16

    k_embed<<<BS_, 256, 0, stream>>>(tokens, emb, xbuf);

    for (int l = 0; l < 4; l++) {
        k_qcompute<<<BS_ * 32 / 256, 256, 0, stream>>>(xbuf, phi + l * NQ_, qbf);
        k_qtrans<<<dim3(S_ / 64, E_ / 64, B_), 256, 0, stream>>>(qbf, qT);
        k_attn<<<dim3(S_ / 32, B_, NSPLIT), 256, 0, stream>>>(qbf, qT, pacc, pm, pl);
        k_amerge<<<BS_ / 4, 256, 0, stream>>>(pacc, pm, pl, ybuf);
        k_ln<<<BS_ / 4, 256, 0, stream>>>(xbuf, ybuf, g1 + l * E_, beta1 + l * E_);
        k_w2t<<<dim3(FF_ / 64, E_ / 64), 256, 0, stream>>>(W2 + (size_t)l * FF_ * E_, w2t);
        k_ffn1<<<BS_ / 8, 256, 0, stream>>>(xbuf, theta + l * NQ_,
                                            W1 + (size_t)l * NQ_ * FF_, b1 + (size_t)l * FF_, hbf);
        k_ffn2<<<BS_ / 32, 256, 0, stream>>>(hbf, w2t, b2 + (size_t)l * E_, ybuf);
        k_ln<<<BS_ / 4, 256, 0, stream>>>(xbuf, ybuf, g2 + l * E_, beta2 + l * E_);
    }

    k_mean<<<dim3(16, B_), 256, 0, stream>>>(xbuf, psum);
    k_mean2<<<8, 256, 0, stream>>>(psum, xmean);
    k_cls<<<1, 128, 0, stream>>>(xmean, Wc, bc, outp);
}

// Round 3
// 1908.557 us; speedup vs baseline: 1.0141x; 1.0016x over previous
//
#include <hip/hip_runtime.h>
#include <hip/hip_bf16.h>

#define B_ 8
#define S_ 2048
#define E_ 256
#define FF_ 1024
#define NQ_ 8
#define NC_ 10
#define BS_ (B_*S_)
#define NSPLIT 2
#define KVBLK 64

typedef __bf16 bf16x8 __attribute__((ext_vector_type(8)));
typedef float f32x4 __attribute__((ext_vector_type(4)));

#define MFMA16(a,b,c) __builtin_amdgcn_mfma_f32_16x16x32_bf16(a,b,c,0,0,0)

// ---------------- embed + positional encoding ----------------
__global__ __launch_bounds__(256) void k_embed(const int* __restrict__ tokens,
                                               const float* __restrict__ emb,
                                               float* __restrict__ x) {
    int row = blockIdx.x;           // 0..BS_-1
    int e = threadIdx.x;            // 0..255
    int s = row & (S_ - 1);
    int tok = tokens[row];
    int i2 = e & ~1;                // 2*(e/2)
    float d = expf((float)i2 * (-9.210340371976184f / 256.0f));
    float ang = (float)s * d;
    float pe = (e & 1) ? cosf(ang) : sinf(ang);
    x[(size_t)row * E_ + e] = emb[(size_t)tok * E_ + e] + pe;
}

// ---------------- quantum attention: q from x ----------------
__global__ __launch_bounds__(256) void k_qcompute(const float* __restrict__ x,
                                                  const float* __restrict__ phi_l,
                                                  __hip_bfloat16* __restrict__ qbf) {
    int t = blockIdx.x * 256 + threadIdx.x;   // over BS_*32 heads
    int head = t & 31;
    size_t row = (size_t)(t >> 5);
    const float* xp = x + row * E_ + head * 8;
    f32x4 x0 = *(const f32x4*)xp;
    f32x4 x1 = *(const f32x4*)(xp + 4);
    float c[8];
#pragma unroll
    for (int j = 0; j < 4; j++) {
        c[j]     = cosf(x0[j] + phi_l[j]);
        c[4 + j] = cosf(x1[j] + phi_l[4 + j]);
    }
    float q[8];
    float run = c[0];
#pragma unroll
    for (int i = 1; i < 8; i++) { run *= c[i]; q[i] = run; }
    float o0 = c[1];
#pragma unroll
    for (int i = 2; i < 8; i++) o0 *= c[i];
    q[0] = o0;
    bf16x8 v;
#pragma unroll
    for (int j = 0; j < 8; j++) v[j] = (__bf16)q[j];
    *(bf16x8*)(qbf + row * E_ + head * 8) = v;
}

// ---------------- transpose q: (b,t,e) -> (b,e,t) ----------------
__global__ __launch_bounds__(256) void k_qtrans(const __hip_bfloat16* __restrict__ qbf,
                                                __hip_bfloat16* __restrict__ qT) {
    __shared__ __align__(16) __bf16 tile[64][72];
    int t0 = blockIdx.x * 64;
    int e0 = blockIdx.y * 64;
    int b  = blockIdx.z;
    int tid = threadIdx.x;
#pragma unroll
    for (int half = 0; half < 2; half++) {
        int r  = half * 32 + (tid >> 3);
        int c8 = (tid & 7) * 8;
        *(bf16x8*)&tile[r][c8] =
            *(const bf16x8*)(qbf + ((size_t)b * S_ + t0 + r) * E_ + e0 + c8);
    }
    __syncthreads();
#pragma unroll
    for (int half = 0; half < 2; half++) {
        int el = half * 32 + (tid >> 3);
        int t8 = (tid & 7) * 8;
        bf16x8 v;
#pragma unroll
        for (int j = 0; j < 8; j++) v[j] = tile[t8 + j][el];
        *(bf16x8*)(qT + ((size_t)b * E_ + e0 + el) * S_ + t0 + t8) = v;
    }
}

// ---------------- flash attention, shifted-exp softmax (no max tracking) ----------------
// p = exp(s - 44): s in [-90.5, 90.5] (|q_i|<=1), diag s_ii >= 0 guarantees
// row-sum >= e^-44 (no underflow-to-zero); max term e^46.5 < f32/bf16 max.
// Mathematically identical to softmax; shift cancels in acc/l.
// grid (S_/32, B_, NSPLIT). 256 thr = 4 waves.
__global__ __launch_bounds__(256, 4) void k_attn(const __hip_bfloat16* __restrict__ qbf,
                                                 const __hip_bfloat16* __restrict__ qT,
                                                 float* __restrict__ pacc,
                                                 float* __restrict__ pl) {
    __shared__ __align__(16) __bf16 plds[4][16][72];   // per-wave P tile (16x64 + pad)
    const float SCALE = 0.3535533905932738f;           // 1/sqrt(8)
    int b    = blockIdx.y;
    int z    = blockIdx.z;
    int wv   = threadIdx.x >> 6;
    int lane = threadIdx.x & 63;
    int r16  = lane & 15;
    int kg   = lane >> 4;
    int qbase = blockIdx.x * 32 + (wv >> 1) * 16;
    int ebase = (wv & 1) * 128;

    bf16x8 aq[8];
#pragma unroll
    for (int kk = 0; kk < 8; kk++)
        aq[kk] = *(const bf16x8*)(qbf + ((size_t)b * S_ + qbase + r16) * E_ + kk * 32 + kg * 8);

    f32x4 acc[8];
#pragma unroll
    for (int cf = 0; cf < 8; cf++) acc[cf] = (f32x4){0.f, 0.f, 0.f, 0.f};
    float lrow[4] = {0.f, 0.f, 0.f, 0.f};

    int k0 = z * (S_ / NSPLIT);
    for (int kt = 0; kt < (S_ / NSPLIT) / KVBLK; kt++) {
        int kbase = k0 + kt * KVBLK;
        f32x4 s[4];
#pragma unroll
        for (int c = 0; c < 4; c++) s[c] = (f32x4){0.f, 0.f, 0.f, 0.f};
#pragma unroll
        for (int c = 0; c < 4; c++) {
#pragma unroll
            for (int kk = 0; kk < 8; kk++) {
                bf16x8 bk = *(const bf16x8*)(qbf + ((size_t)b * S_ + kbase + c * 16 + r16) * E_ + kk * 32 + kg * 8);
                s[c] = MFMA16(aq[kk], bk, s[c]);
            }
        }
        // p = exp(s*SCALE - 44), no cross-lane ops, no rescale
#pragma unroll
        for (int c = 0; c < 4; c++) {
#pragma unroll
            for (int i = 0; i < 4; i++) {
                float p = __expf(fmaf(s[c][i], SCALE, -44.0f));
                plds[wv][kg * 4 + i][c * 16 + r16] = (__bf16)p;
                lrow[i] += p;
            }
        }
        asm volatile("s_waitcnt lgkmcnt(0)" ::: "memory");
        bf16x8 pa0 = *(const bf16x8*)&plds[wv][r16][kg * 8];
        bf16x8 pa1 = *(const bf16x8*)&plds[wv][r16][32 + kg * 8];

#pragma unroll
        for (int cf = 0; cf < 8; cf++) {
            bf16x8 bv0 = *(const bf16x8*)(qT + ((size_t)b * E_ + ebase + cf * 16 + r16) * S_ + kbase + kg * 8);
            bf16x8 bv1 = *(const bf16x8*)(qT + ((size_t)b * E_ + ebase + cf * 16 + r16) * S_ + kbase + 32 + kg * 8);
            acc[cf] = MFMA16(pa0, bv0, acc[cf]);
            acc[cf] = MFMA16(pa1, bv1, acc[cf]);
        }
    }

    // epilogue: reduce lrow across the 16 lanes of the row group
#pragma unroll
    for (int i = 0; i < 4; i++) {
        lrow[i] += __shfl_xor(lrow[i], 1);
        lrow[i] += __shfl_xor(lrow[i], 2);
        lrow[i] += __shfl_xor(lrow[i], 4);
        lrow[i] += __shfl_xor(lrow[i], 8);
    }
    size_t prow = (size_t)z * BS_ + (size_t)b * S_ + qbase;
#pragma unroll
    for (int i = 0; i < 4; i++) {
        size_t orow = prow + kg * 4 + i;
#pragma unroll
        for (int cf = 0; cf < 8; cf++)
            pacc[orow * E_ + ebase + cf * 16 + r16] = acc[cf][i];
    }
    if ((wv & 1) == 0 && r16 == 0) {
#pragma unroll
        for (int i = 0; i < 4; i++)
            pl[prow + kg * 4 + i] = lrow[i];
    }
}

// ---------------- merge the NSPLIT partials: (a0+a1)/(l0+l1) ----------------
__global__ __launch_bounds__(256) void k_amerge(const float* __restrict__ pacc,
                                                const float* __restrict__ pl,
                                                float* __restrict__ out) {
    int wv = threadIdx.x >> 6, lane = threadIdx.x & 63;
    size_t row = (size_t)blockIdx.x * 4 + wv;     // 0..BS_-1
    float inv = 1.0f / (pl[row] + pl[BS_ + row]);
    f32x4 a0 = ((const f32x4*)(pacc + row * E_))[lane];
    f32x4 a1 = ((const f32x4*)(pacc + (size_t)BS_ * E_ + row * E_))[lane];
    f32x4 o;
#pragma unroll
    for (int j = 0; j < 4; j++) o[j] = (a0[j] + a1[j]) * inv;
    ((f32x4*)(out + row * E_))[lane] = o;
}

// ---------------- layernorm: x = LN(x + y)*g + b ----------------
__global__ __launch_bounds__(256) void k_ln(float* __restrict__ x, const float* __restrict__ y,
                                            const float* __restrict__ g, const float* __restrict__ bb) {
    int wv = threadIdx.x >> 6, lane = threadIdx.x & 63;
    size_t row = (size_t)blockIdx.x * 4 + wv;
    f32x4 xv = ((const f32x4*)(x + row * E_))[lane];
    f32x4 yv = ((const f32x4*)(y + row * E_))[lane];
    f32x4 v;
    float s = 0.f, sq = 0.f;
#pragma unroll
    for (int j = 0; j < 4; j++) { v[j] = xv[j] + yv[j]; s += v[j]; sq += v[j] * v[j]; }
#pragma unroll
    for (int m = 1; m <= 32; m <<= 1) { s += __shfl_xor(s, m); sq += __shfl_xor(sq, m); }
    float mean = s * (1.f / E_);
    float var = sq * (1.f / E_) - mean * mean;
    float rstd = rsqrtf(var + 1e-5f);
    f32x4 gv = ((const f32x4*)g)[lane];
    f32x4 bv = ((const f32x4*)bb)[lane];
    f32x4 o;
#pragma unroll
    for (int j = 0; j < 4; j++) o[j] = (v[j] - mean) * rstd * gv[j] + bv[j];
    ((f32x4*)(x + row * E_))[lane] = o;
}

// ---------------- W2 transpose to bf16 (tiled): (1024,256) -> (256,1024) ----------------
__global__ __launch_bounds__(256) void k_w2t(const float* __restrict__ W2l,
                                             __hip_bfloat16* __restrict__ w2t) {
    __shared__ __align__(16) __bf16 tile[64][72];
    int k0 = blockIdx.x * 64, e0 = blockIdx.y * 64;
    int tid = threadIdx.x;
#pragma unroll
    for (int half = 0; half < 2; half++) {
        int r  = half * 32 + (tid >> 3);      // k row
        int c8 = (tid & 7) * 8;               // e offset
        f32x4 v0 = *(const f32x4*)(W2l + (size_t)(k0 + r) * E_ + e0 + c8);
        f32x4 v1 = *(const f32x4*)(W2l + (size_t)(k0 + r) * E_ + e0 + c8 + 4);
#pragma unroll
        for (int j = 0; j < 4; j++) { tile[r][c8 + j] = (__bf16)v0[j]; tile[r][c8 + 4 + j] = (__bf16)v1[j]; }
    }
    __syncthreads();
#pragma unroll
    for (int half = 0; half < 2; half++) {
        int e  = half * 32 + (tid >> 3);
        int k8 = (tid & 7) * 8;
        bf16x8 v;
#pragma unroll
        for (int j = 0; j < 8; j++) v[j] = tile[k8 + j][e];
        *(bf16x8*)(w2t + (size_t)(e0 + e) * FF_ + k0 + k8) = v;
    }
}

// ---------------- FFN stage 1: h = relu(qm@W1 + b1) (bf16 out) ----------------
__global__ __launch_bounds__(256) void k_ffn1(const float* __restrict__ x,
                                              const float* __restrict__ theta_l,
                                              const float* __restrict__ W1l,
                                              const float* __restrict__ b1l,
                                              __hip_bfloat16* __restrict__ hbf) {
    __shared__ float qm[8][8];
    int tid = threadIdx.x;
    int rbase = blockIdx.x * 8;
    if (tid < 64) {
        int r = tid >> 3, i = tid & 7;
        qm[r][i] = cosf(x[(size_t)(rbase + r) * E_ + i]) * cosf(theta_l[i]);
    }
    __syncthreads();
#pragma unroll
    for (int jj = 0; jj < 4; jj++) {
        int j = jj * 256 + tid;
        float w1v[8];
#pragma unroll
        for (int i = 0; i < 8; i++) w1v[i] = W1l[i * FF_ + j];
        float bj = b1l[j];
#pragma unroll
        for (int r = 0; r < 8; r++) {
            float a = bj;
#pragma unroll
            for (int i = 0; i < 8; i++) a += qm[r][i] * w1v[i];
            hbf[(size_t)(rbase + r) * FF_ + j] = __float2bfloat16(fmaxf(a, 0.f));
        }
    }
}

// ---------------- FFN stage 2: f = h@W2 + b2 (MFMA) ----------------
__global__ __launch_bounds__(256) void k_ffn2(const __hip_bfloat16* __restrict__ hbf,
                                              const __hip_bfloat16* __restrict__ w2t,
                                              const float* __restrict__ b2l,
                                              float* __restrict__ fout) {
    int wv = threadIdx.x >> 6, lane = threadIdx.x & 63;
    int r16 = lane & 15, kg = lane >> 4;
    int rbase = blockIdx.x * 32 + (wv >> 1) * 16;
    int ebase = (wv & 1) * 128;
    f32x4 acc[8];
#pragma unroll
    for (int cf = 0; cf < 8; cf++) acc[cf] = (f32x4){0.f, 0.f, 0.f, 0.f};
    for (int kt = 0; kt < FF_ / 32; kt++) {
        bf16x8 ah = *(const bf16x8*)(hbf + (size_t)(rbase + r16) * FF_ + kt * 32 + kg * 8);
#pragma unroll
        for (int cf = 0; cf < 8; cf++) {
            bf16x8 bw = *(const bf16x8*)(w2t + (size_t)(ebase + cf * 16 + r16) * FF_ + kt * 32 + kg * 8);
            acc[cf] = MFMA16(ah, bw, acc[cf]);
        }
    }
#pragma unroll
    for (int i = 0; i < 4; i++) {
        size_t orow = (size_t)rbase + kg * 4 + i;
#pragma unroll
        for (int cf = 0; cf < 8; cf++) {
            int e = ebase + cf * 16 + r16;
            fout[orow * E_ + e] = acc[cf][i] + b2l[e];
        }
    }
}

// ---------------- mean over S (two-stage, deterministic) ----------------
__global__ __launch_bounds__(256) void k_mean(const float* __restrict__ x, float* __restrict__ psum) {
    int c = blockIdx.x, b = blockIdx.y, e = threadIdx.x;
    float s = 0.f;
    size_t base = ((size_t)b * S_ + c * 128) * E_ + e;
    for (int r = 0; r < 128; r++) s += x[base + (size_t)r * E_];
    psum[(c * 8 + b) * E_ + e] = s;
}

__global__ __launch_bounds__(256) void k_mean2(const float* __restrict__ psum, float* __restrict__ xmean) {
    int idx = blockIdx.x * 256 + threadIdx.x;   // 0..2047 -> (b,e)
    int b = idx >> 8, e = idx & 255;
    float s = 0.f;
    for (int c = 0; c < 16; c++) s += psum[(c * 8 + b) * E_ + e];
    xmean[idx] = s * (1.f / S_);
}

// ---------------- classifier ----------------
__global__ __launch_bounds__(128) void k_cls(const float* __restrict__ xmean,
                                             const float* __restrict__ Wc,
                                             const float* __restrict__ bc,
                                             float* __restrict__ outp) {
    int t = threadIdx.x;
    if (t >= B_ * NC_) return;
    int b = t / NC_, c = t % NC_;
    float s = bc[c];
    for (int e = 0; e < E_; e++) s += xmean[b * E_ + e] * Wc[e * NC_ + c];
    outp[t] = s;
}

extern "C" void kernel_launch(void* const* d_in, const int* in_sizes, int n_in,
                              void* d_out, int out_size, void* d_ws, size_t ws_size,
                              hipStream_t stream) {
    (void)in_sizes; (void)n_in; (void)out_size; (void)ws_size;
    const int*   tokens = (const int*)d_in[0];
    const float* emb    = (const float*)d_in[1];
    const float* phi    = (const float*)d_in[2];
    const float* theta  = (const float*)d_in[3];
    const float* W1     = (const float*)d_in[4];
    const float* b1     = (const float*)d_in[5];
    const float* W2     = (const float*)d_in[6];
    const float* b2     = (const float*)d_in[7];
    const float* g1     = (const float*)d_in[8];
    const float* beta1  = (const float*)d_in[9];
    const float* g2     = (const float*)d_in[10];
    const float* beta2  = (const float*)d_in[11];
    const float* Wc     = (const float*)d_in[12];
    const float* bc     = (const float*)d_in[13];
    float* outp = (float*)d_out;

    // workspace layout
    float* xbuf = (float*)d_ws;                                   // BS_*E_ f32
    float* ybuf = xbuf + (size_t)BS_ * E_;                        // BS_*E_ f32
    __hip_bfloat16* qbf = (__hip_bfloat16*)(ybuf + (size_t)BS_ * E_);  // BS_*E_ bf16
    __hip_bfloat16* qT  = qbf + (size_t)BS_ * E_;                 // BS_*E_ bf16
    __hip_bfloat16* hbf = qT + (size_t)BS_ * E_;                  // BS_*FF_ bf16
    __hip_bfloat16* w2t = hbf + (size_t)BS_ * FF_;                // E_*FF_ bf16
    float* psum  = (float*)(w2t + (size_t)E_ * FF_);              // 16*8*E_ f32
    float* xmean = psum + 16 * 8 * E_;                            // B_*E_ f32
    float* pl    = xmean + B_ * E_;                               // NSPLIT*BS_ f32
    float* pacc  = (float*)hbf;                                   // overlay: NSPLIT*BS_*E_ f32 == BS_*FF_ bf16

    k_embed<<<BS_, 256, 0, stream>>>(tokens, emb, xbuf);

    for (int l = 0; l < 4; l++) {
        k_qcompute<<<BS_ * 32 / 256, 256, 0, stream>>>(xbuf, phi + l * NQ_, qbf);
        k_qtrans<<<dim3(S_ / 64, E_ / 64, B_), 256, 0, stream>>>(qbf, qT);
        k_attn<<<dim3(S_ / 32, B_, NSPLIT), 256, 0, stream>>>(qbf, qT, pacc, pl);
        k_amerge<<<BS_ / 4, 256, 0, stream>>>(pacc, pl, ybuf);
        k_ln<<<BS_ / 4, 256, 0, stream>>>(xbuf, ybuf, g1 + l * E_, beta1 + l * E_);
        k_w2t<<<dim3(FF_ / 64, E_ / 64), 256, 0, stream>>>(W2 + (size_t)l * FF_ * E_, w2t);
        k_ffn1<<<BS_ / 8, 256, 0, stream>>>(xbuf, theta + l * NQ_,
                                            W1 + (size_t)l * NQ_ * FF_, b1 + (size_t)l * FF_, hbf);
        k_ffn2<<<BS_ / 32, 256, 0, stream>>>(hbf, w2t, b2 + (size_t)l * E_, ybuf);
        k_ln<<<BS_ / 4, 256, 0, stream>>>(xbuf, ybuf, g2 + l * E_, beta2 + l * E_);
    }

    k_mean<<<dim3(16, B_), 256, 0, stream>>>(xbuf, psum);
    k_mean2<<<8, 256, 0, stream>>>(psum, xmean);
    k_cls<<<1, 128, 0, stream>>>(xmean, Wc, bc, outp);
}

// Round 4
// 921.420 us; speedup vs baseline: 2.1005x; 2.0713x over previous
//
#include <hip/hip_runtime.h>
#include <hip/hip_bf16.h>

#define B_ 8
#define S_ 2048
#define E_ 256
#define FF_ 1024
#define NQ_ 8
#define NC_ 10
#define BS_ (B_*S_)
#define NSPLIT 2
#define KVBLK 32

typedef __bf16 bf16x8 __attribute__((ext_vector_type(8)));
typedef float f32x4 __attribute__((ext_vector_type(4)));

#define MFMA16(a,b,c) __builtin_amdgcn_mfma_f32_16x16x32_bf16(a,b,c,0,0,0)

// ---------------- embed + positional encoding ----------------
__global__ __launch_bounds__(256) void k_embed(const int* __restrict__ tokens,
                                               const float* __restrict__ emb,
                                               float* __restrict__ x) {
    int row = blockIdx.x;           // 0..BS_-1
    int e = threadIdx.x;            // 0..255
    int s = row & (S_ - 1);
    int tok = tokens[row];
    int i2 = e & ~1;                // 2*(e/2)
    float d = expf((float)i2 * (-9.210340371976184f / 256.0f));
    float ang = (float)s * d;
    float pe = (e & 1) ? cosf(ang) : sinf(ang);
    x[(size_t)row * E_ + e] = emb[(size_t)tok * E_ + e] + pe;
}

// ---------------- quantum attention: q from x ----------------
__global__ __launch_bounds__(256) void k_qcompute(const float* __restrict__ x,
                                                  const float* __restrict__ phi_l,
                                                  __hip_bfloat16* __restrict__ qbf) {
    int t = blockIdx.x * 256 + threadIdx.x;   // over BS_*32 heads
    int head = t & 31;
    size_t row = (size_t)(t >> 5);
    const float* xp = x + row * E_ + head * 8;
    f32x4 x0 = *(const f32x4*)xp;
    f32x4 x1 = *(const f32x4*)(xp + 4);
    float c[8];
#pragma unroll
    for (int j = 0; j < 4; j++) {
        c[j]     = cosf(x0[j] + phi_l[j]);
        c[4 + j] = cosf(x1[j] + phi_l[4 + j]);
    }
    float q[8];
    float run = c[0];
#pragma unroll
    for (int i = 1; i < 8; i++) { run *= c[i]; q[i] = run; }
    float o0 = c[1];
#pragma unroll
    for (int i = 2; i < 8; i++) o0 *= c[i];
    q[0] = o0;
    bf16x8 v;
#pragma unroll
    for (int j = 0; j < 8; j++) v[j] = (__bf16)q[j];
    *(bf16x8*)(qbf + row * E_ + head * 8) = v;
}

// ---------------- transpose q: (b,t,e) -> (b,e,t) ----------------
__global__ __launch_bounds__(256) void k_qtrans(const __hip_bfloat16* __restrict__ qbf,
                                                __hip_bfloat16* __restrict__ qT) {
    __shared__ __align__(16) __bf16 tile[64][72];
    int t0 = blockIdx.x * 64;
    int e0 = blockIdx.y * 64;
    int b  = blockIdx.z;
    int tid = threadIdx.x;
#pragma unroll
    for (int half = 0; half < 2; half++) {
        int r  = half * 32 + (tid >> 3);
        int c8 = (tid & 7) * 8;
        *(bf16x8*)&tile[r][c8] =
            *(const bf16x8*)(qbf + ((size_t)b * S_ + t0 + r) * E_ + e0 + c8);
    }
    __syncthreads();
#pragma unroll
    for (int half = 0; half < 2; half++) {
        int el = half * 32 + (tid >> 3);
        int t8 = (tid & 7) * 8;
        bf16x8 v;
#pragma unroll
        for (int j = 0; j < 8; j++) v[j] = tile[t8 + j][el];
        *(bf16x8*)(qT + ((size_t)b * E_ + e0 + el) * S_ + t0 + t8) = v;
    }
}

// ---------------- flash attention: LDS-staged K/V tiles, shifted-exp softmax ----------------
// p = exp(s - 44): |s| <= 90.5 and diag s_ii >= 0 => no overflow, row-sum >= e^-44.
// Mathematically identical to softmax (shift cancels in acc/l).
// grid (S_/32, B_, NSPLIT). 256 thr = 4 waves; wave: 16 q-rows x 128 e-half.
// K/V tiles staged cooperatively in LDS (coalesced), fragments read with XOR swizzle.
__global__ __launch_bounds__(256, 3) void k_attn(const __hip_bfloat16* __restrict__ qbf,
                                                 const __hip_bfloat16* __restrict__ qT,
                                                 float* __restrict__ pacc,
                                                 float* __restrict__ pl) {
    __shared__ __align__(16) __bf16 ktile[KVBLK * 256];   // [kvrow][e], chunk16 ^= row&7
    __shared__ __align__(16) __bf16 vtile[256 * KVBLK];   // [erow][kv], chunk16 ^= row&3
    __shared__ __align__(16) __bf16 plds[4][16][40];      // per-wave P tile
    const float SCALE = 0.3535533905932738f;              // 1/sqrt(8)
    int b    = blockIdx.y;
    int z    = blockIdx.z;
    int tid  = threadIdx.x;
    int wv   = tid >> 6;
    int lane = tid & 63;
    int r16  = lane & 15;
    int kg   = lane >> 4;
    int qbase = blockIdx.x * 32 + (wv >> 1) * 16;
    int ebase = (wv & 1) * 128;

    bf16x8 aq[8];
#pragma unroll
    for (int kk = 0; kk < 8; kk++)
        aq[kk] = *(const bf16x8*)(qbf + ((size_t)b * S_ + qbase + r16) * E_ + kk * 32 + kg * 8);

    f32x4 acc[8];
#pragma unroll
    for (int cf = 0; cf < 8; cf++) acc[cf] = (f32x4){0.f, 0.f, 0.f, 0.f};
    float lrow[4] = {0.f, 0.f, 0.f, 0.f};

    int k0 = z * (S_ / NSPLIT);
    for (int kt = 0; kt < (S_ / NSPLIT) / KVBLK; kt++) {
        int kbase = k0 + kt * KVBLK;

        // ---- stage K tile: 32 rows x 512B, fully coalesced ----
        bf16x8 kst[4];
#pragma unroll
        for (int p = 0; p < 4; p++) {
            int slot = p * 256 + tid;
            kst[p] = *(const bf16x8*)(qbf + ((size_t)b * S_ + kbase + (slot >> 5)) * E_ + (slot & 31) * 8);
        }
#pragma unroll
        for (int p = 0; p < 4; p++) {
            int slot = p * 256 + tid;
            int row = slot >> 5, ch = slot & 31;
            *(bf16x8*)&ktile[row * 256 + ((ch ^ (row & 7)) * 8)] = kst[p];
        }
        // ---- stage V tile: 256 erows x 64B, each line fetched once ----
        bf16x8 vst[4];
#pragma unroll
        for (int p = 0; p < 4; p++) {
            int slot = p * 256 + tid;
            vst[p] = *(const bf16x8*)(qT + ((size_t)b * E_ + (slot >> 2)) * S_ + kbase + (slot & 3) * 8);
        }
#pragma unroll
        for (int p = 0; p < 4; p++) {
            int slot = p * 256 + tid;
            int row = slot >> 2, ch = slot & 3;
            *(bf16x8*)&vtile[row * KVBLK + ((ch ^ (row & 3)) * 8)] = vst[p];
        }
        __syncthreads();

        // ---- QK^T from LDS (swizzled, conflict-free) ----
        f32x4 s0 = (f32x4){0.f,0.f,0.f,0.f}, s1 = (f32x4){0.f,0.f,0.f,0.f};
#pragma unroll
        for (int kk = 0; kk < 8; kk++) {
            int sw = ((kk * 4 + kg) ^ (r16 & 7)) * 8;
            bf16x8 b0 = *(const bf16x8*)&ktile[r16 * 256 + sw];
            bf16x8 b1 = *(const bf16x8*)&ktile[(16 + r16) * 256 + sw];
            s0 = MFMA16(aq[kk], b0, s0);
            s1 = MFMA16(aq[kk], b1, s1);
        }
        // ---- p = exp(s*SCALE - 44) ----
#pragma unroll
        for (int i = 0; i < 4; i++) {
            float p0 = __expf(fmaf(s0[i], SCALE, -44.0f));
            float p1 = __expf(fmaf(s1[i], SCALE, -44.0f));
            plds[wv][kg * 4 + i][r16]      = (__bf16)p0;
            plds[wv][kg * 4 + i][16 + r16] = (__bf16)p1;
            lrow[i] += p0 + p1;
        }
        asm volatile("s_waitcnt lgkmcnt(0)" ::: "memory");
        bf16x8 pa = *(const bf16x8*)&plds[wv][r16][kg * 8];

        // ---- PV from LDS V tile (swizzled) ----
#pragma unroll
        for (int cf = 0; cf < 8; cf++) {
            int vrow = ebase + cf * 16 + r16;
            bf16x8 bv = *(const bf16x8*)&vtile[vrow * KVBLK + ((kg ^ (vrow & 3)) * 8)];
            acc[cf] = MFMA16(pa, bv, acc[cf]);
        }
        __syncthreads();
    }

    // epilogue: reduce lrow across the 16 lanes of the row group
#pragma unroll
    for (int i = 0; i < 4; i++) {
        lrow[i] += __shfl_xor(lrow[i], 1);
        lrow[i] += __shfl_xor(lrow[i], 2);
        lrow[i] += __shfl_xor(lrow[i], 4);
        lrow[i] += __shfl_xor(lrow[i], 8);
    }
    size_t prow = (size_t)z * BS_ + (size_t)b * S_ + qbase;
#pragma unroll
    for (int i = 0; i < 4; i++) {
        size_t orow = prow + kg * 4 + i;
#pragma unroll
        for (int cf = 0; cf < 8; cf++)
            pacc[orow * E_ + ebase + cf * 16 + r16] = acc[cf][i];
    }
    if ((wv & 1) == 0 && r16 == 0) {
#pragma unroll
        for (int i = 0; i < 4; i++)
            pl[prow + kg * 4 + i] = lrow[i];
    }
}

// ---------------- merge the NSPLIT partials: (a0+a1)/(l0+l1) ----------------
__global__ __launch_bounds__(256) void k_amerge(const float* __restrict__ pacc,
                                                const float* __restrict__ pl,
                                                float* __restrict__ out) {
    int wv = threadIdx.x >> 6, lane = threadIdx.x & 63;
    size_t row = (size_t)blockIdx.x * 4 + wv;     // 0..BS_-1
    float inv = 1.0f / (pl[row] + pl[BS_ + row]);
    f32x4 a0 = ((const f32x4*)(pacc + row * E_))[lane];
    f32x4 a1 = ((const f32x4*)(pacc + (size_t)BS_ * E_ + row * E_))[lane];
    f32x4 o;
#pragma unroll
    for (int j = 0; j < 4; j++) o[j] = (a0[j] + a1[j]) * inv;
    ((f32x4*)(out + row * E_))[lane] = o;
}

// ---------------- layernorm: x = LN(x + y)*g + b ----------------
__global__ __launch_bounds__(256) void k_ln(float* __restrict__ x, const float* __restrict__ y,
                                            const float* __restrict__ g, const float* __restrict__ bb) {
    int wv = threadIdx.x >> 6, lane = threadIdx.x & 63;
    size_t row = (size_t)blockIdx.x * 4 + wv;
    f32x4 xv = ((const f32x4*)(x + row * E_))[lane];
    f32x4 yv = ((const f32x4*)(y + row * E_))[lane];
    f32x4 v;
    float s = 0.f, sq = 0.f;
#pragma unroll
    for (int j = 0; j < 4; j++) { v[j] = xv[j] + yv[j]; s += v[j]; sq += v[j] * v[j]; }
#pragma unroll
    for (int m = 1; m <= 32; m <<= 1) { s += __shfl_xor(s, m); sq += __shfl_xor(sq, m); }
    float mean = s * (1.f / E_);
    float var = sq * (1.f / E_) - mean * mean;
    float rstd = rsqrtf(var + 1e-5f);
    f32x4 gv = ((const f32x4*)g)[lane];
    f32x4 bv = ((const f32x4*)bb)[lane];
    f32x4 o;
#pragma unroll
    for (int j = 0; j < 4; j++) o[j] = (v[j] - mean) * rstd * gv[j] + bv[j];
    ((f32x4*)(x + row * E_))[lane] = o;
}

// ---------------- W2 transpose to bf16 (tiled): (1024,256) -> (256,1024) ----------------
__global__ __launch_bounds__(256) void k_w2t(const float* __restrict__ W2l,
                                             __hip_bfloat16* __restrict__ w2t) {
    __shared__ __align__(16) __bf16 tile[64][72];
    int k0 = blockIdx.x * 64, e0 = blockIdx.y * 64;
    int tid = threadIdx.x;
#pragma unroll
    for (int half = 0; half < 2; half++) {
        int r  = half * 32 + (tid >> 3);      // k row
        int c8 = (tid & 7) * 8;               // e offset
        f32x4 v0 = *(const f32x4*)(W2l + (size_t)(k0 + r) * E_ + e0 + c8);
        f32x4 v1 = *(const f32x4*)(W2l + (size_t)(k0 + r) * E_ + e0 + c8 + 4);
#pragma unroll
        for (int j = 0; j < 4; j++) { tile[r][c8 + j] = (__bf16)v0[j]; tile[r][c8 + 4 + j] = (__bf16)v1[j]; }
    }
    __syncthreads();
#pragma unroll
    for (int half = 0; half < 2; half++) {
        int e  = half * 32 + (tid >> 3);
        int k8 = (tid & 7) * 8;
        bf16x8 v;
#pragma unroll
        for (int j = 0; j < 8; j++) v[j] = tile[k8 + j][e];
        *(bf16x8*)(w2t + (size_t)(e0 + e) * FF_ + k0 + k8) = v;
    }
}

// ---------------- FFN stage 1: h = relu(qm@W1 + b1) (bf16 out) ----------------
__global__ __launch_bounds__(256) void k_ffn1(const float* __restrict__ x,
                                              const float* __restrict__ theta_l,
                                              const float* __restrict__ W1l,
                                              const float* __restrict__ b1l,
                                              __hip_bfloat16* __restrict__ hbf) {
    __shared__ float qm[8][8];
    int tid = threadIdx.x;
    int rbase = blockIdx.x * 8;
    if (tid < 64) {
        int r = tid >> 3, i = tid & 7;
        qm[r][i] = cosf(x[(size_t)(rbase + r) * E_ + i]) * cosf(theta_l[i]);
    }
    __syncthreads();
#pragma unroll
    for (int jj = 0; jj < 4; jj++) {
        int j = jj * 256 + tid;
        float w1v[8];
#pragma unroll
        for (int i = 0; i < 8; i++) w1v[i] = W1l[i * FF_ + j];
        float bj = b1l[j];
#pragma unroll
        for (int r = 0; r < 8; r++) {
            float a = bj;
#pragma unroll
            for (int i = 0; i < 8; i++) a += qm[r][i] * w1v[i];
            hbf[(size_t)(rbase + r) * FF_ + j] = __float2bfloat16(fmaxf(a, 0.f));
        }
    }
}

// ---------------- FFN stage 2: f = h@W2 + b2 (MFMA) ----------------
__global__ __launch_bounds__(256) void k_ffn2(const __hip_bfloat16* __restrict__ hbf,
                                              const __hip_bfloat16* __restrict__ w2t,
                                              const float* __restrict__ b2l,
                                              float* __restrict__ fout) {
    int wv = threadIdx.x >> 6, lane = threadIdx.x & 63;
    int r16 = lane & 15, kg = lane >> 4;
    int rbase = blockIdx.x * 32 + (wv >> 1) * 16;
    int ebase = (wv & 1) * 128;
    f32x4 acc[8];
#pragma unroll
    for (int cf = 0; cf < 8; cf++) acc[cf] = (f32x4){0.f, 0.f, 0.f, 0.f};
    for (int kt = 0; kt < FF_ / 32; kt++) {
        bf16x8 ah = *(const bf16x8*)(hbf + (size_t)(rbase + r16) * FF_ + kt * 32 + kg * 8);
#pragma unroll
        for (int cf = 0; cf < 8; cf++) {
            bf16x8 bw = *(const bf16x8*)(w2t + (size_t)(ebase + cf * 16 + r16) * FF_ + kt * 32 + kg * 8);
            acc[cf] = MFMA16(ah, bw, acc[cf]);
        }
    }
#pragma unroll
    for (int i = 0; i < 4; i++) {
        size_t orow = (size_t)rbase + kg * 4 + i;
#pragma unroll
        for (int cf = 0; cf < 8; cf++) {
            int e = ebase + cf * 16 + r16;
            fout[orow * E_ + e] = acc[cf][i] + b2l[e];
        }
    }
}

// ---------------- mean over S (two-stage, deterministic) ----------------
__global__ __launch_bounds__(256) void k_mean(const float* __restrict__ x, float* __restrict__ psum) {
    int c = blockIdx.x, b = blockIdx.y, e = threadIdx.x;
    float s = 0.f;
    size_t base = ((size_t)b * S_ + c * 128) * E_ + e;
    for (int r = 0; r < 128; r++) s += x[base + (size_t)r * E_];
    psum[(c * 8 + b) * E_ + e] = s;
}

__global__ __launch_bounds__(256) void k_mean2(const float* __restrict__ psum, float* __restrict__ xmean) {
    int idx = blockIdx.x * 256 + threadIdx.x;   // 0..2047 -> (b,e)
    int b = idx >> 8, e = idx & 255;
    float s = 0.f;
    for (int c = 0; c < 16; c++) s += psum[(c * 8 + b) * E_ + e];
    xmean[idx] = s * (1.f / S_);
}

// ---------------- classifier ----------------
__global__ __launch_bounds__(128) void k_cls(const float* __restrict__ xmean,
                                             const float* __restrict__ Wc,
                                             const float* __restrict__ bc,
                                             float* __restrict__ outp) {
    int t = threadIdx.x;
    if (t >= B_ * NC_) return;
    int b = t / NC_, c = t % NC_;
    float s = bc[c];
    for (int e = 0; e < E_; e++) s += xmean[b * E_ + e] * Wc[e * NC_ + c];
    outp[t] = s;
}

extern "C" void kernel_launch(void* const* d_in, const int* in_sizes, int n_in,
                              void* d_out, int out_size, void* d_ws, size_t ws_size,
                              hipStream_t stream) {
    (void)in_sizes; (void)n_in; (void)out_size; (void)ws_size;
    const int*   tokens = (const int*)d_in[0];
    const float* emb    = (const float*)d_in[1];
    const float* phi    = (const float*)d_in[2];
    const float* theta  = (const float*)d_in[3];
    const float* W1     = (const float*)d_in[4];
    const float* b1     = (const float*)d_in[5];
    const float* W2     = (const float*)d_in[6];
    const float* b2     = (const float*)d_in[7];
    const float* g1     = (const float*)d_in[8];
    const float* beta1  = (const float*)d_in[9];
    const float* g2     = (const float*)d_in[10];
    const float* beta2  = (const float*)d_in[11];
    const float* Wc     = (const float*)d_in[12];
    const float* bc     = (const float*)d_in[13];
    float* outp = (float*)d_out;

    // workspace layout
    float* xbuf = (float*)d_ws;                                   // BS_*E_ f32
    float* ybuf = xbuf + (size_t)BS_ * E_;                        // BS_*E_ f32
    __hip_bfloat16* qbf = (__hip_bfloat16*)(ybuf + (size_t)BS_ * E_);  // BS_*E_ bf16
    __hip_bfloat16* qT  = qbf + (size_t)BS_ * E_;                 // BS_*E_ bf16
    __hip_bfloat16* hbf = qT + (size_t)BS_ * E_;                  // BS_*FF_ bf16
    __hip_bfloat16* w2t = hbf + (size_t)BS_ * FF_;                // E_*FF_ bf16
    float* psum  = (float*)(w2t + (size_t)E_ * FF_);              // 16*8*E_ f32
    float* xmean = psum + 16 * 8 * E_;                            // B_*E_ f32
    float* pl    = xmean + B_ * E_;                               // NSPLIT*BS_ f32
    float* pacc  = (float*)hbf;                                   // overlay: NSPLIT*BS_*E_ f32 == BS_*FF_ bf16

    k_embed<<<BS_, 256, 0, stream>>>(tokens, emb, xbuf);

    for (int l = 0; l < 4; l++) {
        k_qcompute<<<BS_ * 32 / 256, 256, 0, stream>>>(xbuf, phi + l * NQ_, qbf);
        k_qtrans<<<dim3(S_ / 64, E_ / 64, B_), 256, 0, stream>>>(qbf, qT);
        k_attn<<<dim3(S_ / 32, B_, NSPLIT), 256, 0, stream>>>(qbf, qT, pacc, pl);
        k_amerge<<<BS_ / 4, 256, 0, stream>>>(pacc, pl, ybuf);
        k_ln<<<BS_ / 4, 256, 0, stream>>>(xbuf, ybuf, g1 + l * E_, beta1 + l * E_);
        k_w2t<<<dim3(FF_ / 64, E_ / 64), 256, 0, stream>>>(W2 + (size_t)l * FF_ * E_, w2t);
        k_ffn1<<<BS_ / 8, 256, 0, stream>>>(xbuf, theta + l * NQ_,
                                            W1 + (size_t)l * NQ_ * FF_, b1 + (size_t)l * FF_, hbf);
        k_ffn2<<<BS_ / 32, 256, 0, stream>>>(hbf, w2t, b2 + (size_t)l * E_, ybuf);
        k_ln<<<BS_ / 4, 256, 0, stream>>>(xbuf, ybuf, g2 + l * E_, beta2 + l * E_);
    }

    k_mean<<<dim3(16, B_), 256, 0, stream>>>(xbuf, psum);
    k_mean2<<<8, 256, 0, stream>>>(psum, xmean);
    k_cls<<<1, 128, 0, stream>>>(xmean, Wc, bc, outp);
}

// Round 5
// 842.838 us; speedup vs baseline: 2.2964x; 1.0932x over previous
//
#include <hip/hip_runtime.h>
#include <hip/hip_bf16.h>

#define B_ 8
#define S_ 2048
#define E_ 256
#define FF_ 1024
#define NQ_ 8
#define NC_ 10
#define BS_ (B_*S_)
#define NSPLIT 2
#define KVBLK 32

typedef __bf16 bf16x8 __attribute__((ext_vector_type(8)));
typedef float f32x4 __attribute__((ext_vector_type(4)));

#define MFMA16(a,b,c) __builtin_amdgcn_mfma_f32_16x16x32_bf16(a,b,c,0,0,0)

// ---------------- embed + positional encoding ----------------
__global__ __launch_bounds__(256) void k_embed(const int* __restrict__ tokens,
                                               const float* __restrict__ emb,
                                               float* __restrict__ x) {
    int row = blockIdx.x;           // 0..BS_-1
    int e = threadIdx.x;            // 0..255
    int s = row & (S_ - 1);
    int tok = tokens[row];
    int i2 = e & ~1;                // 2*(e/2)
    float d = expf((float)i2 * (-9.210340371976184f / 256.0f));
    float ang = (float)s * d;
    float pe = (e & 1) ? cosf(ang) : sinf(ang);
    x[(size_t)row * E_ + e] = emb[(size_t)tok * E_ + e] + pe;
}

// ---------------- fused q-compute + transpose ----------------
// grid (S/64, E/64, B). Computes q tile 64t x 64e, writes qbf (row-major)
// and qT (col-major) via LDS transpose. Each element computed exactly once.
__global__ __launch_bounds__(256) void k_qt(const float* __restrict__ x,
                                            const float* __restrict__ phi_l,
                                            __hip_bfloat16* __restrict__ qbf,
                                            __hip_bfloat16* __restrict__ qT) {
    __shared__ __align__(16) __bf16 tile[64][76];
    int t0 = blockIdx.x * 64, e0 = blockIdx.y * 64, b = blockIdx.z;
    int tid = threadIdx.x;
    float ph[8];
#pragma unroll
    for (int j = 0; j < 8; j++) ph[j] = phi_l[j];
#pragma unroll
    for (int k = 0; k < 2; k++) {
        int idx = k * 256 + tid;
        int r = idx >> 3, hh = idx & 7;           // row, head-slot (8 e each)
        const float* xp = x + ((size_t)b * S_ + t0 + r) * E_ + e0 + hh * 8;
        f32x4 x0 = *(const f32x4*)xp;
        f32x4 x1 = *(const f32x4*)(xp + 4);
        float c[8];
#pragma unroll
        for (int j = 0; j < 4; j++) {
            c[j]     = cosf(x0[j] + ph[j]);
            c[4 + j] = cosf(x1[j] + ph[4 + j]);
        }
        float q[8];
        float run = c[0];
#pragma unroll
        for (int i = 1; i < 8; i++) { run *= c[i]; q[i] = run; }
        float o0 = c[1];
#pragma unroll
        for (int i = 2; i < 8; i++) o0 *= c[i];
        q[0] = o0;
        bf16x8 v;
#pragma unroll
        for (int j = 0; j < 8; j++) v[j] = (__bf16)q[j];
        *(bf16x8*)(qbf + ((size_t)b * S_ + t0 + r) * E_ + e0 + hh * 8) = v;
        *(bf16x8*)&tile[r][hh * 8] = v;
    }
    __syncthreads();
#pragma unroll
    for (int k = 0; k < 2; k++) {
        int idx = k * 256 + tid;
        int el = idx >> 3, tc = idx & 7;          // e-local, t-chunk
        bf16x8 v;
#pragma unroll
        for (int j = 0; j < 8; j++) v[j] = tile[tc * 8 + j][el];
        *(bf16x8*)(qT + ((size_t)b * E_ + e0 + el) * S_ + t0 + tc * 8) = v;
    }
}

// ---------------- flash attention: LDS-staged K/V, issue-early prefetch ----------------
// p = exp(s - 44): |s| <= 90.5, diag s_ii >= 0 => no overflow, row-sum >= e^-44.
// Mathematically identical to softmax. grid (S_/32, B_, NSPLIT), 4 waves.
__global__ __launch_bounds__(256, 3) void k_attn(const __hip_bfloat16* __restrict__ qbf,
                                                 const __hip_bfloat16* __restrict__ qT,
                                                 float* __restrict__ pacc,
                                                 float* __restrict__ pl) {
    __shared__ __align__(16) __bf16 ktile[KVBLK * 256];   // [kvrow][e], chunk16 ^= row&7
    __shared__ __align__(16) __bf16 vtile[256 * KVBLK];   // [erow][kv], chunk16 ^= (row>>1)&3
    __shared__ __align__(16) __bf16 plds[4][16][40];      // per-wave P tile
    const float SCALE = 0.3535533905932738f;              // 1/sqrt(8)
    int b    = blockIdx.y;
    int z    = blockIdx.z;
    int tid  = threadIdx.x;
    int wv   = tid >> 6;
    int lane = tid & 63;
    int r16  = lane & 15;
    int kg   = lane >> 4;
    int qbase = blockIdx.x * 32 + (wv >> 1) * 16;
    int ebase = (wv & 1) * 128;

    bf16x8 aq[8];
#pragma unroll
    for (int kk = 0; kk < 8; kk++)
        aq[kk] = *(const bf16x8*)(qbf + ((size_t)b * S_ + qbase + r16) * E_ + kk * 32 + kg * 8);

    f32x4 acc[8];
#pragma unroll
    for (int cf = 0; cf < 8; cf++) acc[cf] = (f32x4){0.f, 0.f, 0.f, 0.f};
    float lrow[4] = {0.f, 0.f, 0.f, 0.f};

    int k0 = z * (S_ / NSPLIT);
    const int NT = (S_ / NSPLIT) / KVBLK;
    bf16x8 kst[4], vst[4];
    // prologue: issue loads for tile 0
#pragma unroll
    for (int p = 0; p < 4; p++) {
        int slot = p * 256 + tid;
        kst[p] = *(const bf16x8*)(qbf + ((size_t)b * S_ + k0 + (slot >> 5)) * E_ + (slot & 31) * 8);
        vst[p] = *(const bf16x8*)(qT + ((size_t)b * E_ + (slot >> 2)) * S_ + k0 + (slot & 3) * 8);
    }
    int kbase = k0;
    for (int kt = 0; kt < NT; kt++) {
        // write staged regs to LDS (swizzled)
#pragma unroll
        for (int p = 0; p < 4; p++) {
            int slot = p * 256 + tid;
            int row = slot >> 5, ch = slot & 31;
            *(bf16x8*)&ktile[row * 256 + ((ch ^ (row & 7)) * 8)] = kst[p];
        }
#pragma unroll
        for (int p = 0; p < 4; p++) {
            int slot = p * 256 + tid;
            int row = slot >> 2, ch = slot & 3;
            *(bf16x8*)&vtile[row * KVBLK + ((ch ^ ((row >> 1) & 3)) * 8)] = vst[p];
        }
        __syncthreads();
        // issue-early: next tile's global loads fly under QK+softmax+PV
        int knext = kbase + KVBLK;
        if (kt + 1 < NT) {
#pragma unroll
            for (int p = 0; p < 4; p++) {
                int slot = p * 256 + tid;
                kst[p] = *(const bf16x8*)(qbf + ((size_t)b * S_ + knext + (slot >> 5)) * E_ + (slot & 31) * 8);
                vst[p] = *(const bf16x8*)(qT + ((size_t)b * E_ + (slot >> 2)) * S_ + knext + (slot & 3) * 8);
            }
        }

        // ---- QK^T from LDS ----
        f32x4 s0 = (f32x4){0.f,0.f,0.f,0.f}, s1 = (f32x4){0.f,0.f,0.f,0.f};
#pragma unroll
        for (int kk = 0; kk < 8; kk++) {
            int sw = ((kk * 4 + kg) ^ (r16 & 7)) * 8;
            bf16x8 b0 = *(const bf16x8*)&ktile[r16 * 256 + sw];
            bf16x8 b1 = *(const bf16x8*)&ktile[(16 + r16) * 256 + sw];
            s0 = MFMA16(aq[kk], b0, s0);
            s1 = MFMA16(aq[kk], b1, s1);
        }
        // ---- p = exp(s*SCALE - 44) ----
#pragma unroll
        for (int i = 0; i < 4; i++) {
            float p0 = __expf(fmaf(s0[i], SCALE, -44.0f));
            float p1 = __expf(fmaf(s1[i], SCALE, -44.0f));
            plds[wv][kg * 4 + i][r16]      = (__bf16)p0;
            plds[wv][kg * 4 + i][16 + r16] = (__bf16)p1;
            lrow[i] += p0 + p1;
        }
        asm volatile("s_waitcnt lgkmcnt(0)" ::: "memory");
        bf16x8 pa = *(const bf16x8*)&plds[wv][r16][kg * 8];

        // ---- PV from LDS V tile ----
#pragma unroll
        for (int cf = 0; cf < 8; cf++) {
            int vrow = ebase + cf * 16 + r16;
            bf16x8 bv = *(const bf16x8*)&vtile[vrow * KVBLK + ((kg ^ ((vrow >> 1) & 3)) * 8)];
            acc[cf] = MFMA16(pa, bv, acc[cf]);
        }
        __syncthreads();
        kbase = knext;
    }

    // epilogue: reduce lrow across the 16 lanes of the row group
#pragma unroll
    for (int i = 0; i < 4; i++) {
        lrow[i] += __shfl_xor(lrow[i], 1);
        lrow[i] += __shfl_xor(lrow[i], 2);
        lrow[i] += __shfl_xor(lrow[i], 4);
        lrow[i] += __shfl_xor(lrow[i], 8);
    }
    size_t prow = (size_t)z * BS_ + (size_t)b * S_ + qbase;
#pragma unroll
    for (int i = 0; i < 4; i++) {
        size_t orow = prow + kg * 4 + i;
#pragma unroll
        for (int cf = 0; cf < 8; cf++)
            pacc[orow * E_ + ebase + cf * 16 + r16] = acc[cf][i];
    }
    if ((wv & 1) == 0 && r16 == 0) {
#pragma unroll
        for (int i = 0; i < 4; i++)
            pl[prow + kg * 4 + i] = lrow[i];
    }
}

// ---------------- fused merge + residual + layernorm: x = LN(x + merge)*g + b ----------------
__global__ __launch_bounds__(256) void k_aln(const float* __restrict__ pacc,
                                             const float* __restrict__ pl,
                                             float* __restrict__ x,
                                             const float* __restrict__ g,
                                             const float* __restrict__ bb) {
    int wv = threadIdx.x >> 6, lane = threadIdx.x & 63;
    size_t row = (size_t)blockIdx.x * 4 + wv;
    float inv = 1.0f / (pl[row] + pl[BS_ + row]);
    f32x4 a0 = ((const f32x4*)(pacc + row * E_))[lane];
    f32x4 a1 = ((const f32x4*)(pacc + (size_t)BS_ * E_ + row * E_))[lane];
    f32x4 xv = ((const f32x4*)(x + row * E_))[lane];
    f32x4 v;
    float s = 0.f, sq = 0.f;
#pragma unroll
    for (int j = 0; j < 4; j++) {
        v[j] = xv[j] + (a0[j] + a1[j]) * inv;
        s += v[j]; sq += v[j] * v[j];
    }
#pragma unroll
    for (int m = 1; m <= 32; m <<= 1) { s += __shfl_xor(s, m); sq += __shfl_xor(sq, m); }
    float mean = s * (1.f / E_);
    float var = sq * (1.f / E_) - mean * mean;
    float rstd = rsqrtf(var + 1e-5f);
    f32x4 gv = ((const f32x4*)g)[lane];
    f32x4 bv = ((const f32x4*)bb)[lane];
    f32x4 o;
#pragma unroll
    for (int j = 0; j < 4; j++) o[j] = (v[j] - mean) * rstd * gv[j] + bv[j];
    ((f32x4*)(x + row * E_))[lane] = o;
}

// ---------------- W2 transpose to bf16 (tiled): (1024,256) -> (256,1024) ----------------
__global__ __launch_bounds__(256) void k_w2t(const float* __restrict__ W2l,
                                             __hip_bfloat16* __restrict__ w2t) {
    __shared__ __align__(16) __bf16 tile[64][72];
    int k0 = blockIdx.x * 64, e0 = blockIdx.y * 64;
    int tid = threadIdx.x;
#pragma unroll
    for (int half = 0; half < 2; half++) {
        int r  = half * 32 + (tid >> 3);      // k row
        int c8 = (tid & 7) * 8;               // e offset
        f32x4 v0 = *(const f32x4*)(W2l + (size_t)(k0 + r) * E_ + e0 + c8);
        f32x4 v1 = *(const f32x4*)(W2l + (size_t)(k0 + r) * E_ + e0 + c8 + 4);
#pragma unroll
        for (int j = 0; j < 4; j++) { tile[r][c8 + j] = (__bf16)v0[j]; tile[r][c8 + 4 + j] = (__bf16)v1[j]; }
    }
    __syncthreads();
#pragma unroll
    for (int half = 0; half < 2; half++) {
        int e  = half * 32 + (tid >> 3);
        int k8 = (tid & 7) * 8;
        bf16x8 v;
#pragma unroll
        for (int j = 0; j < 8; j++) v[j] = tile[k8 + j][e];
        *(bf16x8*)(w2t + (size_t)(e0 + e) * FF_ + k0 + k8) = v;
    }
}

// ---------------- FFN stage 1: h = relu(qm@W1 + b1) (bf16 out) ----------------
__global__ __launch_bounds__(256) void k_ffn1(const float* __restrict__ x,
                                              const float* __restrict__ theta_l,
                                              const float* __restrict__ W1l,
                                              const float* __restrict__ b1l,
                                              __hip_bfloat16* __restrict__ hbf) {
    __shared__ float qm[8][8];
    int tid = threadIdx.x;
    int rbase = blockIdx.x * 8;
    if (tid < 64) {
        int r = tid >> 3, i = tid & 7;
        qm[r][i] = cosf(x[(size_t)(rbase + r) * E_ + i]) * cosf(theta_l[i]);
    }
    __syncthreads();
#pragma unroll
    for (int jj = 0; jj < 4; jj++) {
        int j = jj * 256 + tid;
        float w1v[8];
#pragma unroll
        for (int i = 0; i < 8; i++) w1v[i] = W1l[i * FF_ + j];
        float bj = b1l[j];
#pragma unroll
        for (int r = 0; r < 8; r++) {
            float a = bj;
#pragma unroll
            for (int i = 0; i < 8; i++) a += qm[r][i] * w1v[i];
            hbf[(size_t)(rbase + r) * FF_ + j] = __float2bfloat16(fmaxf(a, 0.f));
        }
    }
}

// ---------------- fused FFN2 + bias + residual + layernorm ----------------
// grid BS_/32: block = 32 rows x 256 cols; wave: 16 rows x 128-col e-half.
// x = LN(x + h@W2 + b2)*g + b, row stats combined across e-halves via LDS.
__global__ __launch_bounds__(256) void k_ffn2ln(const __hip_bfloat16* __restrict__ hbf,
                                                const __hip_bfloat16* __restrict__ w2t,
                                                const float* __restrict__ b2l,
                                                float* __restrict__ x,
                                                const float* __restrict__ g,
                                                const float* __restrict__ bb) {
    __shared__ float red[32][2][2];
    int wv = threadIdx.x >> 6, lane = threadIdx.x & 63;
    int r16 = lane & 15, kg = lane >> 4;
    int rbase = blockIdx.x * 32 + (wv >> 1) * 16;
    int ebase = (wv & 1) * 128;
    f32x4 acc[8];
#pragma unroll
    for (int cf = 0; cf < 8; cf++) acc[cf] = (f32x4){0.f, 0.f, 0.f, 0.f};
    for (int kt = 0; kt < FF_ / 32; kt++) {
        bf16x8 ah = *(const bf16x8*)(hbf + (size_t)(rbase + r16) * FF_ + kt * 32 + kg * 8);
#pragma unroll
        for (int cf = 0; cf < 8; cf++) {
            bf16x8 bw = *(const bf16x8*)(w2t + (size_t)(ebase + cf * 16 + r16) * FF_ + kt * 32 + kg * 8);
            acc[cf] = MFMA16(ah, bw, acc[cf]);
        }
    }
    // bias + residual, accumulate row stats
    float s[4] = {0.f,0.f,0.f,0.f}, sq[4] = {0.f,0.f,0.f,0.f};
#pragma unroll
    for (int cf = 0; cf < 8; cf++) {
        int e = ebase + cf * 16 + r16;
        float b2v = b2l[e];
#pragma unroll
        for (int i = 0; i < 4; i++) {
            size_t orow = (size_t)rbase + kg * 4 + i;
            float t = acc[cf][i] + b2v + x[orow * E_ + e];
            acc[cf][i] = t;
            s[i] += t; sq[i] += t * t;
        }
    }
#pragma unroll
    for (int i = 0; i < 4; i++) {
#pragma unroll
        for (int m = 1; m <= 8; m <<= 1) { s[i] += __shfl_xor(s[i], m); sq[i] += __shfl_xor(sq[i], m); }
    }
    if (r16 == 0) {
#pragma unroll
        for (int i = 0; i < 4; i++) {
            int rowl = (wv >> 1) * 16 + kg * 4 + i;
            red[rowl][wv & 1][0] = s[i];
            red[rowl][wv & 1][1] = sq[i];
        }
    }
    __syncthreads();
    float mean[4], rstd[4];
#pragma unroll
    for (int i = 0; i < 4; i++) {
        int rowl = (wv >> 1) * 16 + kg * 4 + i;
        float S = red[rowl][0][0] + red[rowl][1][0];
        float Q = red[rowl][0][1] + red[rowl][1][1];
        mean[i] = S * (1.f / E_);
        float var = Q * (1.f / E_) - mean[i] * mean[i];
        rstd[i] = rsqrtf(var + 1e-5f);
    }
#pragma unroll
    for (int cf = 0; cf < 8; cf++) {
        int e = ebase + cf * 16 + r16;
        float gv = g[e], bv = bb[e];
#pragma unroll
        for (int i = 0; i < 4; i++) {
            size_t orow = (size_t)rbase + kg * 4 + i;
            x[orow * E_ + e] = (acc[cf][i] - mean[i]) * rstd[i] * gv + bv;
        }
    }
}

// ---------------- mean over S (two-stage, deterministic) ----------------
__global__ __launch_bounds__(256) void k_mean(const float* __restrict__ x, float* __restrict__ psum) {
    int c = blockIdx.x, b = blockIdx.y, e = threadIdx.x;
    float s = 0.f;
    size_t base = ((size_t)b * S_ + c * 128) * E_ + e;
    for (int r = 0; r < 128; r++) s += x[base + (size_t)r * E_];
    psum[(c * 8 + b) * E_ + e] = s;
}

__global__ __launch_bounds__(256) void k_mean2(const float* __restrict__ psum, float* __restrict__ xmean) {
    int idx = blockIdx.x * 256 + threadIdx.x;   // 0..2047 -> (b,e)
    int b = idx >> 8, e = idx & 255;
    float s = 0.f;
    for (int c = 0; c < 16; c++) s += psum[(c * 8 + b) * E_ + e];
    xmean[idx] = s * (1.f / S_);
}

// ---------------- classifier ----------------
__global__ __launch_bounds__(128) void k_cls(const float* __restrict__ xmean,
                                             const float* __restrict__ Wc,
                                             const float* __restrict__ bc,
                                             float* __restrict__ outp) {
    int t = threadIdx.x;
    if (t >= B_ * NC_) return;
    int b = t / NC_, c = t % NC_;
    float s = bc[c];
    for (int e = 0; e < E_; e++) s += xmean[b * E_ + e] * Wc[e * NC_ + c];
    outp[t] = s;
}

extern "C" void kernel_launch(void* const* d_in, const int* in_sizes, int n_in,
                              void* d_out, int out_size, void* d_ws, size_t ws_size,
                              hipStream_t stream) {
    (void)in_sizes; (void)n_in; (void)out_size; (void)ws_size;
    const int*   tokens = (const int*)d_in[0];
    const float* emb    = (const float*)d_in[1];
    const float* phi    = (const float*)d_in[2];
    const float* theta  = (const float*)d_in[3];
    const float* W1     = (const float*)d_in[4];
    const float* b1     = (const float*)d_in[5];
    const float* W2     = (const float*)d_in[6];
    const float* b2     = (const float*)d_in[7];
    const float* g1     = (const float*)d_in[8];
    const float* beta1  = (const float*)d_in[9];
    const float* g2     = (const float*)d_in[10];
    const float* beta2  = (const float*)d_in[11];
    const float* Wc     = (const float*)d_in[12];
    const float* bc     = (const float*)d_in[13];
    float* outp = (float*)d_out;

    // workspace layout
    float* xbuf = (float*)d_ws;                                   // BS_*E_ f32
    float* ybuf = xbuf + (size_t)BS_ * E_;                        // BS_*E_ f32 (spare)
    __hip_bfloat16* qbf = (__hip_bfloat16*)(ybuf + (size_t)BS_ * E_);  // BS_*E_ bf16
    __hip_bfloat16* qT  = qbf + (size_t)BS_ * E_;                 // BS_*E_ bf16
    __hip_bfloat16* hbf = qT + (size_t)BS_ * E_;                  // BS_*FF_ bf16
    __hip_bfloat16* w2t = hbf + (size_t)BS_ * FF_;                // E_*FF_ bf16
    float* psum  = (float*)(w2t + (size_t)E_ * FF_);              // 16*8*E_ f32
    float* xmean = psum + 16 * 8 * E_;                            // B_*E_ f32
    float* pl    = xmean + B_ * E_;                               // NSPLIT*BS_ f32
    float* pacc  = (float*)hbf;                                   // overlay: NSPLIT*BS_*E_ f32 == BS_*FF_ bf16

    k_embed<<<BS_, 256, 0, stream>>>(tokens, emb, xbuf);

    for (int l = 0; l < 4; l++) {
        k_qt<<<dim3(S_ / 64, E_ / 64, B_), 256, 0, stream>>>(xbuf, phi + l * NQ_, qbf, qT);
        k_attn<<<dim3(S_ / 32, B_, NSPLIT), 256, 0, stream>>>(qbf, qT, pacc, pl);
        k_aln<<<BS_ / 4, 256, 0, stream>>>(pacc, pl, xbuf, g1 + l * E_, beta1 + l * E_);
        k_w2t<<<dim3(FF_ / 64, E_ / 64), 256, 0, stream>>>(W2 + (size_t)l * FF_ * E_, w2t);
        k_ffn1<<<BS_ / 8, 256, 0, stream>>>(xbuf, theta + l * NQ_,
                                            W1 + (size_t)l * NQ_ * FF_, b1 + (size_t)l * FF_, hbf);
        k_ffn2ln<<<BS_ / 32, 256, 0, stream>>>(hbf, w2t, b2 + (size_t)l * E_,
                                               xbuf, g2 + l * E_, beta2 + l * E_);
    }

    k_mean<<<dim3(16, B_), 256, 0, stream>>>(xbuf, psum);
    k_mean2<<<8, 256, 0, stream>>>(psum, xmean);
    k_cls<<<1, 128, 0, stream>>>(xmean, Wc, bc, outp);
}

// Round 6
// 785.811 us; speedup vs baseline: 2.4630x; 1.0726x over previous
//
#include <hip/hip_runtime.h>
#include <hip/hip_bf16.h>

#define B_ 8
#define S_ 2048
#define E_ 256
#define FF_ 1024
#define NQ_ 8
#define NC_ 10
#define BS_ (B_*S_)
#define KVBLK 32

typedef __bf16 bf16x8 __attribute__((ext_vector_type(8)));
typedef float f32x4 __attribute__((ext_vector_type(4)));

#define MFMA16(a,b,c) __builtin_amdgcn_mfma_f32_16x16x32_bf16(a,b,c,0,0,0)

// ---------------- embed + positional encoding ----------------
__global__ __launch_bounds__(256) void k_embed(const int* __restrict__ tokens,
                                               const float* __restrict__ emb,
                                               float* __restrict__ x) {
    int row = blockIdx.x;           // 0..BS_-1
    int e = threadIdx.x;            // 0..255
    int s = row & (S_ - 1);
    int tok = tokens[row];
    int i2 = e & ~1;                // 2*(e/2)
    float d = __expf((float)i2 * (-9.210340371976184f / 256.0f));
    float ang = (float)s * d;
    float pe = (e & 1) ? __cosf(ang) : __sinf(ang);
    x[(size_t)row * E_ + e] = emb[(size_t)tok * E_ + e] + pe;
}

// ---------------- fused q-compute + transpose ----------------
// grid (S/64, E/64, B). Computes q tile 64t x 64e, writes qbf (row-major)
// and qT (col-major) via LDS transpose. Fast trig (args ~<=10 rad, err << bf16 eps).
__global__ __launch_bounds__(256) void k_qt(const float* __restrict__ x,
                                            const float* __restrict__ phi_l,
                                            __hip_bfloat16* __restrict__ qbf,
                                            __hip_bfloat16* __restrict__ qT) {
    __shared__ __align__(16) __bf16 tile[64][76];
    int t0 = blockIdx.x * 64, e0 = blockIdx.y * 64, b = blockIdx.z;
    int tid = threadIdx.x;
    float ph[8];
#pragma unroll
    for (int j = 0; j < 8; j++) ph[j] = phi_l[j];
#pragma unroll
    for (int k = 0; k < 2; k++) {
        int idx = k * 256 + tid;
        int r = idx >> 3, hh = idx & 7;           // row, head-slot (8 e each)
        const float* xp = x + ((size_t)b * S_ + t0 + r) * E_ + e0 + hh * 8;
        f32x4 x0 = *(const f32x4*)xp;
        f32x4 x1 = *(const f32x4*)(xp + 4);
        float c[8];
#pragma unroll
        for (int j = 0; j < 4; j++) {
            c[j]     = __cosf(x0[j] + ph[j]);
            c[4 + j] = __cosf(x1[j] + ph[4 + j]);
        }
        float q[8];
        float run = c[0];
#pragma unroll
        for (int i = 1; i < 8; i++) { run *= c[i]; q[i] = run; }
        float o0 = c[1];
#pragma unroll
        for (int i = 2; i < 8; i++) o0 *= c[i];
        q[0] = o0;
        bf16x8 v;
#pragma unroll
        for (int j = 0; j < 8; j++) v[j] = (__bf16)q[j];
        *(bf16x8*)(qbf + ((size_t)b * S_ + t0 + r) * E_ + e0 + hh * 8) = v;
        *(bf16x8*)&tile[r][hh * 8] = v;
    }
    __syncthreads();
#pragma unroll
    for (int k = 0; k < 2; k++) {
        int idx = k * 256 + tid;
        int el = idx >> 3, tc = idx & 7;          // e-local, t-chunk
        bf16x8 v;
#pragma unroll
        for (int j = 0; j < 8; j++) v[j] = tile[tc * 8 + j][el];
        *(bf16x8*)(qT + ((size_t)b * E_ + e0 + el) * S_ + t0 + tc * 8) = v;
    }
}

// ---------------- flash attention + residual + LN, kv-split QK, fused epilogue ----------------
// p = exp(s - 44): |s| <= 90.5, diag s_ii >= 0 => no overflow, row-sum >= e^-44.
// Mathematically identical to softmax. grid 512: b = bid&7 (batch->XCD pin).
// 4 waves: rowgroup rg = wv>>1 (16 q-rows), e-half eh = wv&1.
// QK kv-columns split across the two eh-waves of a rowgroup; P shared via plds.
__global__ __launch_bounds__(256) void k_attn(const __hip_bfloat16* __restrict__ qbf,
                                              const __hip_bfloat16* __restrict__ qT,
                                              float* __restrict__ x,
                                              const float* __restrict__ g,
                                              const float* __restrict__ bb) {
    __shared__ __align__(16) __bf16 ktile[KVBLK * 256];   // [kv][e] 512B rows, chunk16 ^= row&7
    __shared__ __align__(16) __bf16 vtile[256 * 40];      // [e][kv] 80B rows (32 kv + 8 pad)
    __shared__ __align__(16) __bf16 plds[2][16][40];      // [rg][q16][32 kv + pad]
    __shared__ float redl[2][16][2];
    __shared__ float reds[2][16][2][2];
    const float SCALE = 0.3535533905932738f;              // 1/sqrt(8)
    int bid  = blockIdx.x;
    int b    = bid & 7;                                   // batch == XCD
    int qt   = bid >> 3;
    int tid  = threadIdx.x;
    int wv   = tid >> 6;
    int lane = tid & 63;
    int r16  = lane & 15;
    int kg   = lane >> 4;
    int rg   = wv >> 1, eh = wv & 1;
    int qbase = qt * 32 + rg * 16;
    int ebase = eh * 128;

    bf16x8 aq[8];
#pragma unroll
    for (int kk = 0; kk < 8; kk++)
        aq[kk] = *(const bf16x8*)(qbf + ((size_t)b * S_ + qbase + r16) * E_ + kk * 32 + kg * 8);

    f32x4 acc[8];
#pragma unroll
    for (int cf = 0; cf < 8; cf++) acc[cf] = (f32x4){0.f, 0.f, 0.f, 0.f};
    float lrow[4] = {0.f, 0.f, 0.f, 0.f};

    const int NT = S_ / KVBLK;   // 64
    bf16x8 kst[4], vst[4];
#pragma unroll
    for (int p = 0; p < 4; p++) {
        int slot = p * 256 + tid;
        kst[p] = *(const bf16x8*)(qbf + ((size_t)b * S_ + (slot >> 5)) * E_ + (slot & 31) * 8);
        vst[p] = *(const bf16x8*)(qT + ((size_t)b * E_ + (slot >> 2)) * S_ + (slot & 3) * 8);
    }
    for (int kt = 0; kt < NT; kt++) {
        // write staged regs to LDS
#pragma unroll
        for (int p = 0; p < 4; p++) {
            int slot = p * 256 + tid;
            int row = slot >> 5, ch = slot & 31;
            *(bf16x8*)&ktile[row * 256 + ((ch ^ (row & 7)) * 8)] = kst[p];
        }
#pragma unroll
        for (int p = 0; p < 4; p++) {
            int slot = p * 256 + tid;
            int row = slot >> 2, ch = slot & 3;
            *(bf16x8*)&vtile[row * 40 + ch * 8] = vst[p];
        }
        __syncthreads();
        // prefetch next tile under compute
        if (kt + 1 < NT) {
            int knext = (kt + 1) * KVBLK;
#pragma unroll
            for (int p = 0; p < 4; p++) {
                int slot = p * 256 + tid;
                kst[p] = *(const bf16x8*)(qbf + ((size_t)b * S_ + knext + (slot >> 5)) * E_ + (slot & 31) * 8);
                vst[p] = *(const bf16x8*)(qT + ((size_t)b * E_ + (slot >> 2)) * S_ + knext + (slot & 3) * 8);
            }
        }

        // ---- QK^T: this wave computes kv-columns [eh*16, eh*16+16) only ----
        f32x4 s = (f32x4){0.f, 0.f, 0.f, 0.f};
#pragma unroll
        for (int kk = 0; kk < 8; kk++) {
            bf16x8 bk = *(const bf16x8*)&ktile[(eh * 16 + r16) * 256 + (((kk * 4 + kg) ^ (r16 & 7)) * 8)];
            s = MFMA16(aq[kk], bk, s);
        }
#pragma unroll
        for (int i = 0; i < 4; i++) {
            float p = __expf(fmaf(s[i], SCALE, -44.0f));
            plds[rg][kg * 4 + i][eh * 16 + r16] = (__bf16)p;
            lrow[i] += p;
        }
        __syncthreads();   // P halves exchanged across eh-waves
        bf16x8 pa = *(const bf16x8*)&plds[rg][r16][kg * 8];

        // ---- PV from vtile ----
#pragma unroll
        for (int cf = 0; cf < 8; cf++) {
            int vrow = ebase + cf * 16 + r16;
            bf16x8 bv = *(const bf16x8*)&vtile[vrow * 40 + kg * 8];
            acc[cf] = MFMA16(pa, bv, acc[cf]);
        }
        __syncthreads();   // protect LDS overwrite next iter
    }

    // ---- epilogue: l totals, residual, layernorm, store ----
#pragma unroll
    for (int i = 0; i < 4; i++) {
        lrow[i] += __shfl_xor(lrow[i], 1);
        lrow[i] += __shfl_xor(lrow[i], 2);
        lrow[i] += __shfl_xor(lrow[i], 4);
        lrow[i] += __shfl_xor(lrow[i], 8);
    }
    if (r16 == 0) {
#pragma unroll
        for (int i = 0; i < 4; i++) redl[rg][kg * 4 + i][eh] = lrow[i];
    }
    __syncthreads();
    float sA[4] = {0.f,0.f,0.f,0.f}, sQ[4] = {0.f,0.f,0.f,0.f};
    float linv[4];
#pragma unroll
    for (int i = 0; i < 4; i++)
        linv[i] = 1.0f / (redl[rg][kg * 4 + i][0] + redl[rg][kg * 4 + i][1]);
#pragma unroll
    for (int cf = 0; cf < 8; cf++) {
        int e = ebase + cf * 16 + r16;
#pragma unroll
        for (int i = 0; i < 4; i++) {
            size_t orow = (size_t)b * S_ + qbase + kg * 4 + i;
            float v = x[orow * E_ + e] + acc[cf][i] * linv[i];
            acc[cf][i] = v;
            sA[i] += v; sQ[i] += v * v;
        }
    }
#pragma unroll
    for (int i = 0; i < 4; i++) {
#pragma unroll
        for (int m = 1; m <= 8; m <<= 1) { sA[i] += __shfl_xor(sA[i], m); sQ[i] += __shfl_xor(sQ[i], m); }
    }
    if (r16 == 0) {
#pragma unroll
        for (int i = 0; i < 4; i++) { reds[rg][kg * 4 + i][eh][0] = sA[i]; reds[rg][kg * 4 + i][eh][1] = sQ[i]; }
    }
    __syncthreads();
    float mean[4], rstd[4];
#pragma unroll
    for (int i = 0; i < 4; i++) {
        int rowl = kg * 4 + i;
        float Sm = reds[rg][rowl][0][0] + reds[rg][rowl][1][0];
        float Qm = reds[rg][rowl][0][1] + reds[rg][rowl][1][1];
        mean[i] = Sm * (1.f / E_);
        float var = Qm * (1.f / E_) - mean[i] * mean[i];
        rstd[i] = rsqrtf(var + 1e-5f);
    }
#pragma unroll
    for (int cf = 0; cf < 8; cf++) {
        int e = ebase + cf * 16 + r16;
        float gv = g[e], bv = bb[e];
#pragma unroll
        for (int i = 0; i < 4; i++) {
            size_t orow = (size_t)b * S_ + qbase + kg * 4 + i;
            x[orow * E_ + e] = (acc[cf][i] - mean[i]) * rstd[i] * gv + bv;
        }
    }
}

// ---------------- W2 transpose to bf16 (tiled): (1024,256) -> (256,1024) ----------------
__global__ __launch_bounds__(256) void k_w2t(const float* __restrict__ W2l,
                                             __hip_bfloat16* __restrict__ w2t) {
    __shared__ __align__(16) __bf16 tile[64][72];
    int k0 = blockIdx.x * 64, e0 = blockIdx.y * 64;
    int tid = threadIdx.x;
#pragma unroll
    for (int half = 0; half < 2; half++) {
        int r  = half * 32 + (tid >> 3);      // k row
        int c8 = (tid & 7) * 8;               // e offset
        f32x4 v0 = *(const f32x4*)(W2l + (size_t)(k0 + r) * E_ + e0 + c8);
        f32x4 v1 = *(const f32x4*)(W2l + (size_t)(k0 + r) * E_ + e0 + c8 + 4);
#pragma unroll
        for (int j = 0; j < 4; j++) { tile[r][c8 + j] = (__bf16)v0[j]; tile[r][c8 + 4 + j] = (__bf16)v1[j]; }
    }
    __syncthreads();
#pragma unroll
    for (int half = 0; half < 2; half++) {
        int e  = half * 32 + (tid >> 3);
        int k8 = (tid & 7) * 8;
        bf16x8 v;
#pragma unroll
        for (int j = 0; j < 8; j++) v[j] = tile[k8 + j][e];
        *(bf16x8*)(w2t + (size_t)(e0 + e) * FF_ + k0 + k8) = v;
    }
}

// ---------------- FFN stage 1: h = relu(qm@W1 + b1) (bf16 out) ----------------
__global__ __launch_bounds__(256) void k_ffn1(const float* __restrict__ x,
                                              const float* __restrict__ theta_l,
                                              const float* __restrict__ W1l,
                                              const float* __restrict__ b1l,
                                              __hip_bfloat16* __restrict__ hbf) {
    __shared__ float qm[8][8];
    int tid = threadIdx.x;
    int rbase = blockIdx.x * 8;
    if (tid < 64) {
        int r = tid >> 3, i = tid & 7;
        qm[r][i] = __cosf(x[(size_t)(rbase + r) * E_ + i]) * __cosf(theta_l[i]);
    }
    __syncthreads();
#pragma unroll
    for (int jj = 0; jj < 4; jj++) {
        int j = jj * 256 + tid;
        float w1v[8];
#pragma unroll
        for (int i = 0; i < 8; i++) w1v[i] = W1l[i * FF_ + j];
        float bj = b1l[j];
#pragma unroll
        for (int r = 0; r < 8; r++) {
            float a = bj;
#pragma unroll
            for (int i = 0; i < 8; i++) a += qm[r][i] * w1v[i];
            hbf[(size_t)(rbase + r) * FF_ + j] = __float2bfloat16(fmaxf(a, 0.f));
        }
    }
}

// ---------------- fused FFN2 + bias + residual + layernorm ----------------
__global__ __launch_bounds__(256) void k_ffn2ln(const __hip_bfloat16* __restrict__ hbf,
                                                const __hip_bfloat16* __restrict__ w2t,
                                                const float* __restrict__ b2l,
                                                float* __restrict__ x,
                                                const float* __restrict__ g,
                                                const float* __restrict__ bb) {
    __shared__ float red[32][2][2];
    int wv = threadIdx.x >> 6, lane = threadIdx.x & 63;
    int r16 = lane & 15, kg = lane >> 4;
    int rbase = blockIdx.x * 32 + (wv >> 1) * 16;
    int ebase = (wv & 1) * 128;
    f32x4 acc[8];
#pragma unroll
    for (int cf = 0; cf < 8; cf++) acc[cf] = (f32x4){0.f, 0.f, 0.f, 0.f};
    for (int kt = 0; kt < FF_ / 32; kt++) {
        bf16x8 ah = *(const bf16x8*)(hbf + (size_t)(rbase + r16) * FF_ + kt * 32 + kg * 8);
#pragma unroll
        for (int cf = 0; cf < 8; cf++) {
            bf16x8 bw = *(const bf16x8*)(w2t + (size_t)(ebase + cf * 16 + r16) * FF_ + kt * 32 + kg * 8);
            acc[cf] = MFMA16(ah, bw, acc[cf]);
        }
    }
    float s[4] = {0.f,0.f,0.f,0.f}, sq[4] = {0.f,0.f,0.f,0.f};
#pragma unroll
    for (int cf = 0; cf < 8; cf++) {
        int e = ebase + cf * 16 + r16;
        float b2v = b2l[e];
#pragma unroll
        for (int i = 0; i < 4; i++) {
            size_t orow = (size_t)rbase + kg * 4 + i;
            float t = acc[cf][i] + b2v + x[orow * E_ + e];
            acc[cf][i] = t;
            s[i] += t; sq[i] += t * t;
        }
    }
#pragma unroll
    for (int i = 0; i < 4; i++) {
#pragma unroll
        for (int m = 1; m <= 8; m <<= 1) { s[i] += __shfl_xor(s[i], m); sq[i] += __shfl_xor(sq[i], m); }
    }
    if (r16 == 0) {
#pragma unroll
        for (int i = 0; i < 4; i++) {
            int rowl = (wv >> 1) * 16 + kg * 4 + i;
            red[rowl][wv & 1][0] = s[i];
            red[rowl][wv & 1][1] = sq[i];
        }
    }
    __syncthreads();
    float mean[4], rstd[4];
#pragma unroll
    for (int i = 0; i < 4; i++) {
        int rowl = (wv >> 1) * 16 + kg * 4 + i;
        float S = red[rowl][0][0] + red[rowl][1][0];
        float Q = red[rowl][0][1] + red[rowl][1][1];
        mean[i] = S * (1.f / E_);
        float var = Q * (1.f / E_) - mean[i] * mean[i];
        rstd[i] = rsqrtf(var + 1e-5f);
    }
#pragma unroll
    for (int cf = 0; cf < 8; cf++) {
        int e = ebase + cf * 16 + r16;
        float gv = g[e], bv = bb[e];
#pragma unroll
        for (int i = 0; i < 4; i++) {
            size_t orow = (size_t)rbase + kg * 4 + i;
            x[orow * E_ + e] = (acc[cf][i] - mean[i]) * rstd[i] * gv + bv;
        }
    }
}

// ---------------- mean over S (two-stage, deterministic) ----------------
__global__ __launch_bounds__(256) void k_mean(const float* __restrict__ x, float* __restrict__ psum) {
    int c = blockIdx.x, b = blockIdx.y, e = threadIdx.x;
    float s = 0.f;
    size_t base = ((size_t)b * S_ + c * 128) * E_ + e;
    for (int r = 0; r < 128; r++) s += x[base + (size_t)r * E_];
    psum[(c * 8 + b) * E_ + e] = s;
}

__global__ __launch_bounds__(256) void k_mean2(const float* __restrict__ psum, float* __restrict__ xmean) {
    int idx = blockIdx.x * 256 + threadIdx.x;   // 0..2047 -> (b,e)
    int b = idx >> 8, e = idx & 255;
    float s = 0.f;
    for (int c = 0; c < 16; c++) s += psum[(c * 8 + b) * E_ + e];
    xmean[idx] = s * (1.f / S_);
}

// ---------------- classifier ----------------
__global__ __launch_bounds__(128) void k_cls(const float* __restrict__ xmean,
                                             const float* __restrict__ Wc,
                                             const float* __restrict__ bc,
                                             float* __restrict__ outp) {
    int t = threadIdx.x;
    if (t >= B_ * NC_) return;
    int b = t / NC_, c = t % NC_;
    float s = bc[c];
    for (int e = 0; e < E_; e++) s += xmean[b * E_ + e] * Wc[e * NC_ + c];
    outp[t] = s;
}

extern "C" void kernel_launch(void* const* d_in, const int* in_sizes, int n_in,
                              void* d_out, int out_size, void* d_ws, size_t ws_size,
                              hipStream_t stream) {
    (void)in_sizes; (void)n_in; (void)out_size; (void)ws_size;
    const int*   tokens = (const int*)d_in[0];
    const float* emb    = (const float*)d_in[1];
    const float* phi    = (const float*)d_in[2];
    const float* theta  = (const float*)d_in[3];
    const float* W1     = (const float*)d_in[4];
    const float* b1     = (const float*)d_in[5];
    const float* W2     = (const float*)d_in[6];
    const float* b2     = (const float*)d_in[7];
    const float* g1     = (const float*)d_in[8];
    const float* beta1  = (const float*)d_in[9];
    const float* g2     = (const float*)d_in[10];
    const float* beta2  = (const float*)d_in[11];
    const float* Wc     = (const float*)d_in[12];
    const float* bc     = (const float*)d_in[13];
    float* outp = (float*)d_out;

    // workspace layout
    float* xbuf = (float*)d_ws;                                        // BS_*E_ f32
    __hip_bfloat16* qbf = (__hip_bfloat16*)(xbuf + (size_t)BS_ * E_);  // BS_*E_ bf16
    __hip_bfloat16* qT  = qbf + (size_t)BS_ * E_;                      // BS_*E_ bf16
    __hip_bfloat16* hbf = qT + (size_t)BS_ * E_;                       // BS_*FF_ bf16
    __hip_bfloat16* w2t = hbf + (size_t)BS_ * FF_;                     // E_*FF_ bf16
    float* psum  = (float*)(w2t + (size_t)E_ * FF_);                   // 16*8*E_ f32
    float* xmean = psum + 16 * 8 * E_;                                 // B_*E_ f32

    k_embed<<<BS_, 256, 0, stream>>>(tokens, emb, xbuf);

    for (int l = 0; l < 4; l++) {
        k_qt<<<dim3(S_ / 64, E_ / 64, B_), 256, 0, stream>>>(xbuf, phi + l * NQ_, qbf, qT);
        k_attn<<<(S_ / 32) * B_, 256, 0, stream>>>(qbf, qT, xbuf, g1 + l * E_, beta1 + l * E_);
        k_w2t<<<dim3(FF_ / 64, E_ / 64), 256, 0, stream>>>(W2 + (size_t)l * FF_ * E_, w2t);
        k_ffn1<<<BS_ / 8, 256, 0, stream>>>(xbuf, theta + l * NQ_,
                                            W1 + (size_t)l * NQ_ * FF_, b1 + (size_t)l * FF_, hbf);
        k_ffn2ln<<<BS_ / 32, 256, 0, stream>>>(hbf, w2t, b2 + (size_t)l * E_,
                                               xbuf, g2 + l * E_, beta2 + l * E_);
    }

    k_mean<<<dim3(16, B_), 256, 0, stream>>>(xbuf, psum);
    k_mean2<<<8, 256, 0, stream>>>(psum, xmean);
    k_cls<<<1, 128, 0, stream>>>(xmean, Wc, bc, outp);
}

// Round 7
// 709.867 us; speedup vs baseline: 2.7265x; 1.1070x over previous
//
#include <hip/hip_runtime.h>
#include <hip/hip_bf16.h>

#define B_ 8
#define S_ 2048
#define E_ 256
#define FF_ 1024
#define NQ_ 8
#define NC_ 10
#define BS_ (B_*S_)
#define NSPLIT 2
#define KVBLK 32

typedef __bf16 bf16x8 __attribute__((ext_vector_type(8)));
typedef float f32x4 __attribute__((ext_vector_type(4)));

#define MFMA16(a,b,c) __builtin_amdgcn_mfma_f32_16x16x32_bf16(a,b,c,0,0,0)

// ---------------- embed + positional encoding ----------------
__global__ __launch_bounds__(256) void k_embed(const int* __restrict__ tokens,
                                               const float* __restrict__ emb,
                                               float* __restrict__ x) {
    int row = blockIdx.x;           // 0..BS_-1
    int e = threadIdx.x;            // 0..255
    int s = row & (S_ - 1);
    int tok = tokens[row];
    int i2 = e & ~1;                // 2*(e/2)
    float d = __expf((float)i2 * (-9.210340371976184f / 256.0f));
    float ang = (float)s * d;
    float pe = (e & 1) ? __cosf(ang) : __sinf(ang);
    x[(size_t)row * E_ + e] = emb[(size_t)tok * E_ + e] + pe;
}

// ---------------- fused q-compute + transpose ----------------
__global__ __launch_bounds__(256) void k_qt(const float* __restrict__ x,
                                            const float* __restrict__ phi_l,
                                            __hip_bfloat16* __restrict__ qbf,
                                            __hip_bfloat16* __restrict__ qT) {
    __shared__ __align__(16) __bf16 tile[64][76];
    int t0 = blockIdx.x * 64, e0 = blockIdx.y * 64, b = blockIdx.z;
    int tid = threadIdx.x;
    float ph[8];
#pragma unroll
    for (int j = 0; j < 8; j++) ph[j] = phi_l[j];
#pragma unroll
    for (int k = 0; k < 2; k++) {
        int idx = k * 256 + tid;
        int r = idx >> 3, hh = idx & 7;           // row, head-slot (8 e each)
        const float* xp = x + ((size_t)b * S_ + t0 + r) * E_ + e0 + hh * 8;
        f32x4 x0 = *(const f32x4*)xp;
        f32x4 x1 = *(const f32x4*)(xp + 4);
        float c[8];
#pragma unroll
        for (int j = 0; j < 4; j++) {
            c[j]     = __cosf(x0[j] + ph[j]);
            c[4 + j] = __cosf(x1[j] + ph[4 + j]);
        }
        float q[8];
        float run = c[0];
#pragma unroll
        for (int i = 1; i < 8; i++) { run *= c[i]; q[i] = run; }
        float o0 = c[1];
#pragma unroll
        for (int i = 2; i < 8; i++) o0 *= c[i];
        q[0] = o0;
        bf16x8 v;
#pragma unroll
        for (int j = 0; j < 8; j++) v[j] = (__bf16)q[j];
        *(bf16x8*)(qbf + ((size_t)b * S_ + t0 + r) * E_ + e0 + hh * 8) = v;
        *(bf16x8*)&tile[r][hh * 8] = v;
    }
    __syncthreads();
#pragma unroll
    for (int k = 0; k < 2; k++) {
        int idx = k * 256 + tid;
        int el = idx >> 3, tc = idx & 7;          // e-local, t-chunk
        bf16x8 v;
#pragma unroll
        for (int j = 0; j < 8; j++) v[j] = tile[tc * 8 + j][el];
        *(bf16x8*)(qT + ((size_t)b * E_ + e0 + el) * S_ + t0 + tc * 8) = v;
    }
}

// ---------------- flash attention, Wq=32, async K-stage, 2 barriers/iter ----------------
// p = exp(s - 44): |s| <= 90.5, diag s_ii >= 0 => no overflow, row-sum >= e^-44.
// Mathematically identical to softmax. grid (S_/64, B_, NSPLIT), 4 waves.
// wave: rg = wv>>1 -> 32 q-rows (2 subtiles), eh = wv&1 -> 128-col e-half.
// QK kv-columns split across eh pair; P shared via plds (rg-shared).
// K staged via global_load_lds (linear dest, pre-swizzled source); V reg-staged.
__global__ __launch_bounds__(256, 2) void k_attn(const __hip_bfloat16* __restrict__ qbf,
                                                 const __hip_bfloat16* __restrict__ qT,
                                                 float* __restrict__ pacc,
                                                 float* __restrict__ pl) {
    __shared__ __align__(16) __bf16 ktile[KVBLK * 256];   // [kv32][e256], chunk16 ^= row&7
    __shared__ __align__(16) __bf16 vtile[256 * 36];      // [e][kv32+4 pad] (18-word rows)
    __shared__ __align__(16) __bf16 plds[2][32][36];      // [rg][q32][kv32+4]
    __shared__ float redl[2][32][2];
    const float SCALE = 0.3535533905932738f;              // 1/sqrt(8)
    int qt   = blockIdx.x;
    int b    = blockIdx.y;
    int z    = blockIdx.z;
    int tid  = threadIdx.x;
    int wv   = tid >> 6;
    int lane = tid & 63;
    int r16  = lane & 15;
    int kg   = lane >> 4;
    int rg   = wv >> 1, eh = wv & 1;
    int qrow0 = qt * 64 + rg * 32;
    int ebase = eh * 128;

    bf16x8 aq[2][8];
#pragma unroll
    for (int qs = 0; qs < 2; qs++)
#pragma unroll
        for (int kk = 0; kk < 8; kk++)
            aq[qs][kk] = *(const bf16x8*)(qbf + ((size_t)b * S_ + qrow0 + qs * 16 + r16) * E_ + kk * 32 + kg * 8);

    f32x4 acc0[8], acc1[8];
#pragma unroll
    for (int cf = 0; cf < 8; cf++) { acc0[cf] = (f32x4){0.f,0.f,0.f,0.f}; acc1[cf] = (f32x4){0.f,0.f,0.f,0.f}; }
    float lrow0[4] = {0.f,0.f,0.f,0.f}, lrow1[4] = {0.f,0.f,0.f,0.f};

    int k0 = z * (S_ / NSPLIT);
    const int NT = (S_ / NSPLIT) / KVBLK;   // 32
    bf16x8 vst[4];

    auto issue_k = [&](int kb) {
#pragma unroll
        for (int c = 0; c < 4; c++) {
            int seg = wv * 4 + c;                       // 16 x 1KB segments
            int r = seg * 2 + (lane >> 5);
            int ch = lane & 31;
            const __hip_bfloat16* src = qbf + ((size_t)b * S_ + kb + r) * E_ + ((ch ^ (r & 7)) * 8);
            __builtin_amdgcn_global_load_lds((const __attribute__((address_space(1))) void*)src,
                                             (__attribute__((address_space(3))) void*)(ktile + seg * 512),
                                             16, 0, 0);
        }
    };
    auto issue_v = [&](int kb) {
#pragma unroll
        for (int p = 0; p < 4; p++) {
            int slot = p * 256 + tid;
            vst[p] = *(const bf16x8*)(qT + ((size_t)b * E_ + (slot >> 2)) * S_ + kb + (slot & 3) * 8);
        }
    };
    auto write_v = [&]() {
#pragma unroll
        for (int p = 0; p < 4; p++) {
            int slot = p * 256 + tid;
            *(bf16x8*)&vtile[(slot >> 2) * 36 + (slot & 3) * 8] = vst[p];
        }
    };

    // prologue: tile 0
    issue_k(k0);
    issue_v(k0);
    asm volatile("s_waitcnt vmcnt(0)" ::: "memory");
    write_v();
    __syncthreads();

    for (int kt = 0; kt < NT; kt++) {
        // ---- QK^T: this wave's kv-half [eh*16, eh*16+16) ----
        f32x4 s0 = (f32x4){0.f,0.f,0.f,0.f}, s1 = (f32x4){0.f,0.f,0.f,0.f};
#pragma unroll
        for (int kk = 0; kk < 8; kk++) {
            bf16x8 bk = *(const bf16x8*)&ktile[(eh * 16 + r16) * 256 + (((kk * 4 + kg) ^ (r16 & 7)) * 8)];
            s0 = MFMA16(aq[0][kk], bk, s0);
            s1 = MFMA16(aq[1][kk], bk, s1);
        }
#pragma unroll
        for (int i = 0; i < 4; i++) {
            float p0 = __expf(fmaf(s0[i], SCALE, -44.0f));
            float p1 = __expf(fmaf(s1[i], SCALE, -44.0f));
            plds[rg][kg * 4 + i][eh * 16 + r16]      = (__bf16)p0;
            plds[rg][16 + kg * 4 + i][eh * 16 + r16] = (__bf16)p1;
            lrow0[i] += p0;
            lrow1[i] += p1;
        }
        __syncthreads();                         // B2: P complete, QK reads done
        bool more = (kt + 1 < NT);
        if (more) {                              // async: land under PV + barrier
            int kn = k0 + (kt + 1) * KVBLK;
            issue_k(kn);
            issue_v(kn);
        }
        // ---- PV ----
        bf16x8 pa0 = *(const bf16x8*)&plds[rg][r16][kg * 8];
        bf16x8 pa1 = *(const bf16x8*)&plds[rg][16 + r16][kg * 8];
#pragma unroll
        for (int cf = 0; cf < 8; cf++) {
            bf16x8 bv = *(const bf16x8*)&vtile[(ebase + cf * 16 + r16) * 36 + kg * 8];
            acc0[cf] = MFMA16(pa0, bv, acc0[cf]);
            acc1[cf] = MFMA16(pa1, bv, acc1[cf]);
        }
        if (more) {
            asm volatile("s_waitcnt vmcnt(0)" ::: "memory");
            __syncthreads();                     // B1: PV reads done, K landed
            write_v();
        }
    }

    // ---- epilogue: l totals then partial writes ----
#pragma unroll
    for (int i = 0; i < 4; i++) {
#pragma unroll
        for (int m = 1; m <= 8; m <<= 1) {
            lrow0[i] += __shfl_xor(lrow0[i], m);
            lrow1[i] += __shfl_xor(lrow1[i], m);
        }
    }
    if (r16 == 0) {
#pragma unroll
        for (int i = 0; i < 4; i++) {
            redl[rg][kg * 4 + i][eh]      = lrow0[i];
            redl[rg][16 + kg * 4 + i][eh] = lrow1[i];
        }
    }
    __syncthreads();
    size_t prow0 = (size_t)z * BS_ + (size_t)b * S_ + qrow0;
    if (eh == 0 && r16 == 0) {
#pragma unroll
        for (int i = 0; i < 4; i++) {
            int q = kg * 4 + i;
            pl[prow0 + q]      = redl[rg][q][0] + redl[rg][q][1];
            pl[prow0 + 16 + q] = redl[rg][16 + q][0] + redl[rg][16 + q][1];
        }
    }
#pragma unroll
    for (int i = 0; i < 4; i++) {
#pragma unroll
        for (int cf = 0; cf < 8; cf++) {
            pacc[(prow0 + kg * 4 + i) * E_ + ebase + cf * 16 + r16]      = acc0[cf][i];
            pacc[(prow0 + 16 + kg * 4 + i) * E_ + ebase + cf * 16 + r16] = acc1[cf][i];
        }
    }
}

// ---------------- fused merge + residual + layernorm: x = LN(x + merge)*g + b ----------------
__global__ __launch_bounds__(256) void k_aln(const float* __restrict__ pacc,
                                             const float* __restrict__ pl,
                                             float* __restrict__ x,
                                             const float* __restrict__ g,
                                             const float* __restrict__ bb) {
    int wv = threadIdx.x >> 6, lane = threadIdx.x & 63;
    size_t row = (size_t)blockIdx.x * 4 + wv;
    float inv = 1.0f / (pl[row] + pl[BS_ + row]);
    f32x4 a0 = ((const f32x4*)(pacc + row * E_))[lane];
    f32x4 a1 = ((const f32x4*)(pacc + (size_t)BS_ * E_ + row * E_))[lane];
    f32x4 xv = ((const f32x4*)(x + row * E_))[lane];
    f32x4 v;
    float s = 0.f, sq = 0.f;
#pragma unroll
    for (int j = 0; j < 4; j++) {
        v[j] = xv[j] + (a0[j] + a1[j]) * inv;
        s += v[j]; sq += v[j] * v[j];
    }
#pragma unroll
    for (int m = 1; m <= 32; m <<= 1) { s += __shfl_xor(s, m); sq += __shfl_xor(sq, m); }
    float mean = s * (1.f / E_);
    float var = sq * (1.f / E_) - mean * mean;
    float rstd = rsqrtf(var + 1e-5f);
    f32x4 gv = ((const f32x4*)g)[lane];
    f32x4 bv = ((const f32x4*)bb)[lane];
    f32x4 o;
#pragma unroll
    for (int j = 0; j < 4; j++) o[j] = (v[j] - mean) * rstd * gv[j] + bv[j];
    ((f32x4*)(x + row * E_))[lane] = o;
}

// ---------------- W2 transpose to bf16 (tiled): (1024,256) -> (256,1024) ----------------
__global__ __launch_bounds__(256) void k_w2t(const float* __restrict__ W2l,
                                             __hip_bfloat16* __restrict__ w2t) {
    __shared__ __align__(16) __bf16 tile[64][72];
    int k0 = blockIdx.x * 64, e0 = blockIdx.y * 64;
    int tid = threadIdx.x;
#pragma unroll
    for (int half = 0; half < 2; half++) {
        int r  = half * 32 + (tid >> 3);      // k row
        int c8 = (tid & 7) * 8;               // e offset
        f32x4 v0 = *(const f32x4*)(W2l + (size_t)(k0 + r) * E_ + e0 + c8);
        f32x4 v1 = *(const f32x4*)(W2l + (size_t)(k0 + r) * E_ + e0 + c8 + 4);
#pragma unroll
        for (int j = 0; j < 4; j++) { tile[r][c8 + j] = (__bf16)v0[j]; tile[r][c8 + 4 + j] = (__bf16)v1[j]; }
    }
    __syncthreads();
#pragma unroll
    for (int half = 0; half < 2; half++) {
        int e  = half * 32 + (tid >> 3);
        int k8 = (tid & 7) * 8;
        bf16x8 v;
#pragma unroll
        for (int j = 0; j < 8; j++) v[j] = tile[k8 + j][e];
        *(bf16x8*)(w2t + (size_t)(e0 + e) * FF_ + k0 + k8) = v;
    }
}

// ---------------- FFN stage 1: h = relu(qm@W1 + b1) (bf16 out) ----------------
__global__ __launch_bounds__(256) void k_ffn1(const float* __restrict__ x,
                                              const float* __restrict__ theta_l,
                                              const float* __restrict__ W1l,
                                              const float* __restrict__ b1l,
                                              __hip_bfloat16* __restrict__ hbf) {
    __shared__ float qm[8][8];
    int tid = threadIdx.x;
    int rbase = blockIdx.x * 8;
    if (tid < 64) {
        int r = tid >> 3, i = tid & 7;
        qm[r][i] = __cosf(x[(size_t)(rbase + r) * E_ + i]) * __cosf(theta_l[i]);
    }
    __syncthreads();
#pragma unroll
    for (int jj = 0; jj < 4; jj++) {
        int j = jj * 256 + tid;
        float w1v[8];
#pragma unroll
        for (int i = 0; i < 8; i++) w1v[i] = W1l[i * FF_ + j];
        float bj = b1l[j];
#pragma unroll
        for (int r = 0; r < 8; r++) {
            float a = bj;
#pragma unroll
            for (int i = 0; i < 8; i++) a += qm[r][i] * w1v[i];
            hbf[(size_t)(rbase + r) * FF_ + j] = __float2bfloat16(fmaxf(a, 0.f));
        }
    }
}

// ---------------- fused FFN2 + bias + residual + layernorm ----------------
__global__ __launch_bounds__(256) void k_ffn2ln(const __hip_bfloat16* __restrict__ hbf,
                                                const __hip_bfloat16* __restrict__ w2t,
                                                const float* __restrict__ b2l,
                                                float* __restrict__ x,
                                                const float* __restrict__ g,
                                                const float* __restrict__ bb) {
    __shared__ float red[32][2][2];
    int wv = threadIdx.x >> 6, lane = threadIdx.x & 63;
    int r16 = lane & 15, kg = lane >> 4;
    int rbase = blockIdx.x * 32 + (wv >> 1) * 16;
    int ebase = (wv & 1) * 128;
    f32x4 acc[8];
#pragma unroll
    for (int cf = 0; cf < 8; cf++) acc[cf] = (f32x4){0.f, 0.f, 0.f, 0.f};
    for (int kt = 0; kt < FF_ / 32; kt++) {
        bf16x8 ah = *(const bf16x8*)(hbf + (size_t)(rbase + r16) * FF_ + kt * 32 + kg * 8);
#pragma unroll
        for (int cf = 0; cf < 8; cf++) {
            bf16x8 bw = *(const bf16x8*)(w2t + (size_t)(ebase + cf * 16 + r16) * FF_ + kt * 32 + kg * 8);
            acc[cf] = MFMA16(ah, bw, acc[cf]);
        }
    }
    float s[4] = {0.f,0.f,0.f,0.f}, sq[4] = {0.f,0.f,0.f,0.f};
#pragma unroll
    for (int cf = 0; cf < 8; cf++) {
        int e = ebase + cf * 16 + r16;
        float b2v = b2l[e];
#pragma unroll
        for (int i = 0; i < 4; i++) {
            size_t orow = (size_t)rbase + kg * 4 + i;
            float t = acc[cf][i] + b2v + x[orow * E_ + e];
            acc[cf][i] = t;
            s[i] += t; sq[i] += t * t;
        }
    }
#pragma unroll
    for (int i = 0; i < 4; i++) {
#pragma unroll
        for (int m = 1; m <= 8; m <<= 1) { s[i] += __shfl_xor(s[i], m); sq[i] += __shfl_xor(sq[i], m); }
    }
    if (r16 == 0) {
#pragma unroll
        for (int i = 0; i < 4; i++) {
            int rowl = (wv >> 1) * 16 + kg * 4 + i;
            red[rowl][wv & 1][0] = s[i];
            red[rowl][wv & 1][1] = sq[i];
        }
    }
    __syncthreads();
    float mean[4], rstd[4];
#pragma unroll
    for (int i = 0; i < 4; i++) {
        int rowl = (wv >> 1) * 16 + kg * 4 + i;
        float S = red[rowl][0][0] + red[rowl][1][0];
        float Q = red[rowl][0][1] + red[rowl][1][1];
        mean[i] = S * (1.f / E_);
        float var = Q * (1.f / E_) - mean[i] * mean[i];
        rstd[i] = rsqrtf(var + 1e-5f);
    }
#pragma unroll
    for (int cf = 0; cf < 8; cf++) {
        int e = ebase + cf * 16 + r16;
        float gv = g[e], bv = bb[e];
#pragma unroll
        for (int i = 0; i < 4; i++) {
            size_t orow = (size_t)rbase + kg * 4 + i;
            x[orow * E_ + e] = (acc[cf][i] - mean[i]) * rstd[i] * gv + bv;
        }
    }
}

// ---------------- mean over S (two-stage, deterministic) ----------------
__global__ __launch_bounds__(256) void k_mean(const float* __restrict__ x, float* __restrict__ psum) {
    int c = blockIdx.x, b = blockIdx.y, e = threadIdx.x;
    float s = 0.f;
    size_t base = ((size_t)b * S_ + c * 128) * E_ + e;
    for (int r = 0; r < 128; r++) s += x[base + (size_t)r * E_];
    psum[(c * 8 + b) * E_ + e] = s;
}

__global__ __launch_bounds__(256) void k_mean2(const float* __restrict__ psum, float* __restrict__ xmean) {
    int idx = blockIdx.x * 256 + threadIdx.x;   // 0..2047 -> (b,e)
    int b = idx >> 8, e = idx & 255;
    float s = 0.f;
    for (int c = 0; c < 16; c++) s += psum[(c * 8 + b) * E_ + e];
    xmean[idx] = s * (1.f / S_);
}

// ---------------- classifier ----------------
__global__ __launch_bounds__(128) void k_cls(const float* __restrict__ xmean,
                                             const float* __restrict__ Wc,
                                             const float* __restrict__ bc,
                                             float* __restrict__ outp) {
    int t = threadIdx.x;
    if (t >= B_ * NC_) return;
    int b = t / NC_, c = t % NC_;
    float s = bc[c];
    for (int e = 0; e < E_; e++) s += xmean[b * E_ + e] * Wc[e * NC_ + c];
    outp[t] = s;
}

extern "C" void kernel_launch(void* const* d_in, const int* in_sizes, int n_in,
                              void* d_out, int out_size, void* d_ws, size_t ws_size,
                              hipStream_t stream) {
    (void)in_sizes; (void)n_in; (void)out_size; (void)ws_size;
    const int*   tokens = (const int*)d_in[0];
    const float* emb    = (const float*)d_in[1];
    const float* phi    = (const float*)d_in[2];
    const float* theta  = (const float*)d_in[3];
    const float* W1     = (const float*)d_in[4];
    const float* b1     = (const float*)d_in[5];
    const float* W2     = (const float*)d_in[6];
    const float* b2     = (const float*)d_in[7];
    const float* g1     = (const float*)d_in[8];
    const float* beta1  = (const float*)d_in[9];
    const float* g2     = (const float*)d_in[10];
    const float* beta2  = (const float*)d_in[11];
    const float* Wc     = (const float*)d_in[12];
    const float* bc     = (const float*)d_in[13];
    float* outp = (float*)d_out;

    // workspace layout
    float* xbuf = (float*)d_ws;                                        // BS_*E_ f32
    __hip_bfloat16* qbf = (__hip_bfloat16*)(xbuf + (size_t)BS_ * E_);  // BS_*E_ bf16
    __hip_bfloat16* qT  = qbf + (size_t)BS_ * E_;                      // BS_*E_ bf16
    __hip_bfloat16* hbf = qT + (size_t)BS_ * E_;                       // BS_*FF_ bf16
    __hip_bfloat16* w2t = hbf + (size_t)BS_ * FF_;                     // E_*FF_ bf16
    float* psum  = (float*)(w2t + (size_t)E_ * FF_);                   // 16*8*E_ f32
    float* xmean = psum + 16 * 8 * E_;                                 // B_*E_ f32
    float* pl    = xmean + B_ * E_;                                    // NSPLIT*BS_ f32
    float* pacc  = (float*)hbf;                                        // overlay: NSPLIT*BS_*E_ f32 == BS_*FF_ bf16

    k_embed<<<BS_, 256, 0, stream>>>(tokens, emb, xbuf);

    for (int l = 0; l < 4; l++) {
        k_qt<<<dim3(S_ / 64, E_ / 64, B_), 256, 0, stream>>>(xbuf, phi + l * NQ_, qbf, qT);
        k_attn<<<dim3(S_ / 64, B_, NSPLIT), 256, 0, stream>>>(qbf, qT, pacc, pl);
        k_aln<<<BS_ / 4, 256, 0, stream>>>(pacc, pl, xbuf, g1 + l * E_, beta1 + l * E_);
        k_w2t<<<dim3(FF_ / 64, E_ / 64), 256, 0, stream>>>(W2 + (size_t)l * FF_ * E_, w2t);
        k_ffn1<<<BS_ / 8, 256, 0, stream>>>(xbuf, theta + l * NQ_,
                                            W1 + (size_t)l * NQ_ * FF_, b1 + (size_t)l * FF_, hbf);
        k_ffn2ln<<<BS_ / 32, 256, 0, stream>>>(hbf, w2t, b2 + (size_t)l * E_,
                                               xbuf, g2 + l * E_, beta2 + l * E_);
    }

    k_mean<<<dim3(16, B_), 256, 0, stream>>>(xbuf, psum);
    k_mean2<<<8, 256, 0, stream>>>(psum, xmean);
    k_cls<<<1, 128, 0, stream>>>(xmean, Wc, bc, outp);
}

// Round 8
// 555.120 us; speedup vs baseline: 3.4866x; 1.2788x over previous
//
#include <hip/hip_runtime.h>
#include <hip/hip_bf16.h>

#define B_ 8
#define S_ 2048
#define E_ 256
#define FF_ 1024
#define NQ_ 8
#define NC_ 10
#define BS_ (B_*S_)
#define NSPLIT 2
#define KVBLK 32

typedef __bf16 bf16x8 __attribute__((ext_vector_type(8)));
typedef float f32x4 __attribute__((ext_vector_type(4)));

#define MFMA16(a,b,c) __builtin_amdgcn_mfma_f32_16x16x32_bf16(a,b,c,0,0,0)

// ---------------- embed + positional encoding ----------------
__global__ __launch_bounds__(256) void k_embed(const int* __restrict__ tokens,
                                               const float* __restrict__ emb,
                                               float* __restrict__ x) {
    int row = blockIdx.x;           // 0..BS_-1
    int e = threadIdx.x;            // 0..255
    int s = row & (S_ - 1);
    int tok = tokens[row];
    int i2 = e & ~1;                // 2*(e/2)
    float d = __expf((float)i2 * (-9.210340371976184f / 256.0f));
    float ang = (float)s * d;
    float pe = (e & 1) ? __cosf(ang) : __sinf(ang);
    x[(size_t)row * E_ + e] = emb[(size_t)tok * E_ + e] + pe;
}

// ---------------- fused q-compute + transpose ----------------
__global__ __launch_bounds__(256) void k_qt(const float* __restrict__ x,
                                            const float* __restrict__ phi_l,
                                            __hip_bfloat16* __restrict__ qbf,
                                            __hip_bfloat16* __restrict__ qT) {
    __shared__ __align__(16) __bf16 tile[64][76];
    int t0 = blockIdx.x * 64, e0 = blockIdx.y * 64, b = blockIdx.z;
    int tid = threadIdx.x;
    float ph[8];
#pragma unroll
    for (int j = 0; j < 8; j++) ph[j] = phi_l[j];
#pragma unroll
    for (int k = 0; k < 2; k++) {
        int idx = k * 256 + tid;
        int r = idx >> 3, hh = idx & 7;           // row, head-slot (8 e each)
        const float* xp = x + ((size_t)b * S_ + t0 + r) * E_ + e0 + hh * 8;
        f32x4 x0 = *(const f32x4*)xp;
        f32x4 x1 = *(const f32x4*)(xp + 4);
        float c[8];
#pragma unroll
        for (int j = 0; j < 4; j++) {
            c[j]     = __cosf(x0[j] + ph[j]);
            c[4 + j] = __cosf(x1[j] + ph[4 + j]);
        }
        float q[8];
        float run = c[0];
#pragma unroll
        for (int i = 1; i < 8; i++) { run *= c[i]; q[i] = run; }
        float o0 = c[1];
#pragma unroll
        for (int i = 2; i < 8; i++) o0 *= c[i];
        q[0] = o0;
        bf16x8 v;
#pragma unroll
        for (int j = 0; j < 8; j++) v[j] = (__bf16)q[j];
        *(bf16x8*)(qbf + ((size_t)b * S_ + t0 + r) * E_ + e0 + hh * 8) = v;
        *(bf16x8*)&tile[r][hh * 8] = v;
    }
    __syncthreads();
#pragma unroll
    for (int k = 0; k < 2; k++) {
        int idx = k * 256 + tid;
        int el = idx >> 3, tc = idx & 7;          // e-local, t-chunk
        bf16x8 v;
#pragma unroll
        for (int j = 0; j < 8; j++) v[j] = tile[tc * 8 + j][el];
        *(bf16x8*)(qT + ((size_t)b * E_ + e0 + el) * S_ + t0 + tc * 8) = v;
    }
}

// ---------------- flash attention, Wq=32, async K-stage, 2 barriers/iter ----------------
// p = exp(s - 44): |s| <= 90.5, diag s_ii >= 0 => no overflow, row-sum >= e^-44.
// Mathematically identical to softmax. grid (S_/64, B_, NSPLIT), 4 waves.
__global__ __launch_bounds__(256, 2) void k_attn(const __hip_bfloat16* __restrict__ qbf,
                                                 const __hip_bfloat16* __restrict__ qT,
                                                 float* __restrict__ pacc,
                                                 float* __restrict__ pl) {
    __shared__ __align__(16) __bf16 ktile[KVBLK * 256];   // [kv32][e256], chunk16 ^= row&7
    __shared__ __align__(16) __bf16 vtile[256 * 36];      // [e][kv32+4 pad] (18-word rows)
    __shared__ __align__(16) __bf16 plds[2][32][36];      // [rg][q32][kv32+4]
    __shared__ float redl[2][32][2];
    const float SCALE = 0.3535533905932738f;              // 1/sqrt(8)
    int qt   = blockIdx.x;
    int b    = blockIdx.y;
    int z    = blockIdx.z;
    int tid  = threadIdx.x;
    int wv   = tid >> 6;
    int lane = tid & 63;
    int r16  = lane & 15;
    int kg   = lane >> 4;
    int rg   = wv >> 1, eh = wv & 1;
    int qrow0 = qt * 64 + rg * 32;
    int ebase = eh * 128;

    bf16x8 aq[2][8];
#pragma unroll
    for (int qs = 0; qs < 2; qs++)
#pragma unroll
        for (int kk = 0; kk < 8; kk++)
            aq[qs][kk] = *(const bf16x8*)(qbf + ((size_t)b * S_ + qrow0 + qs * 16 + r16) * E_ + kk * 32 + kg * 8);

    f32x4 acc0[8], acc1[8];
#pragma unroll
    for (int cf = 0; cf < 8; cf++) { acc0[cf] = (f32x4){0.f,0.f,0.f,0.f}; acc1[cf] = (f32x4){0.f,0.f,0.f,0.f}; }
    float lrow0[4] = {0.f,0.f,0.f,0.f}, lrow1[4] = {0.f,0.f,0.f,0.f};

    int k0 = z * (S_ / NSPLIT);
    const int NT = (S_ / NSPLIT) / KVBLK;   // 32
    bf16x8 vst[4];

    auto issue_k = [&](int kb) {
#pragma unroll
        for (int c = 0; c < 4; c++) {
            int seg = wv * 4 + c;                       // 16 x 1KB segments
            int r = seg * 2 + (lane >> 5);
            int ch = lane & 31;
            const __hip_bfloat16* src = qbf + ((size_t)b * S_ + kb + r) * E_ + ((ch ^ (r & 7)) * 8);
            __builtin_amdgcn_global_load_lds((const __attribute__((address_space(1))) void*)src,
                                             (__attribute__((address_space(3))) void*)(ktile + seg * 512),
                                             16, 0, 0);
        }
    };
    auto issue_v = [&](int kb) {
#pragma unroll
        for (int p = 0; p < 4; p++) {
            int slot = p * 256 + tid;
            vst[p] = *(const bf16x8*)(qT + ((size_t)b * E_ + (slot >> 2)) * S_ + kb + (slot & 3) * 8);
        }
    };
    auto write_v = [&]() {
#pragma unroll
        for (int p = 0; p < 4; p++) {
            int slot = p * 256 + tid;
            *(bf16x8*)&vtile[(slot >> 2) * 36 + (slot & 3) * 8] = vst[p];
        }
    };

    // prologue: tile 0
    issue_k(k0);
    issue_v(k0);
    asm volatile("s_waitcnt vmcnt(0)" ::: "memory");
    write_v();
    __syncthreads();

    for (int kt = 0; kt < NT; kt++) {
        // ---- QK^T: this wave's kv-half [eh*16, eh*16+16) ----
        f32x4 s0 = (f32x4){0.f,0.f,0.f,0.f}, s1 = (f32x4){0.f,0.f,0.f,0.f};
#pragma unroll
        for (int kk = 0; kk < 8; kk++) {
            bf16x8 bk = *(const bf16x8*)&ktile[(eh * 16 + r16) * 256 + (((kk * 4 + kg) ^ (r16 & 7)) * 8)];
            s0 = MFMA16(aq[0][kk], bk, s0);
            s1 = MFMA16(aq[1][kk], bk, s1);
        }
#pragma unroll
        for (int i = 0; i < 4; i++) {
            float p0 = __expf(fmaf(s0[i], SCALE, -44.0f));
            float p1 = __expf(fmaf(s1[i], SCALE, -44.0f));
            plds[rg][kg * 4 + i][eh * 16 + r16]      = (__bf16)p0;
            plds[rg][16 + kg * 4 + i][eh * 16 + r16] = (__bf16)p1;
            lrow0[i] += p0;
            lrow1[i] += p1;
        }
        __syncthreads();                         // B2: P complete, QK reads done
        bool more = (kt + 1 < NT);
        if (more) {                              // async: land under PV + barrier
            int kn = k0 + (kt + 1) * KVBLK;
            issue_k(kn);
            issue_v(kn);
        }
        // ---- PV ----
        bf16x8 pa0 = *(const bf16x8*)&plds[rg][r16][kg * 8];
        bf16x8 pa1 = *(const bf16x8*)&plds[rg][16 + r16][kg * 8];
#pragma unroll
        for (int cf = 0; cf < 8; cf++) {
            bf16x8 bv = *(const bf16x8*)&vtile[(ebase + cf * 16 + r16) * 36 + kg * 8];
            acc0[cf] = MFMA16(pa0, bv, acc0[cf]);
            acc1[cf] = MFMA16(pa1, bv, acc1[cf]);
        }
        if (more) {
            asm volatile("s_waitcnt vmcnt(0)" ::: "memory");
            __syncthreads();                     // B1: PV reads done, K landed
            write_v();
        }
    }

    // ---- epilogue: l totals then partial writes ----
#pragma unroll
    for (int i = 0; i < 4; i++) {
#pragma unroll
        for (int m = 1; m <= 8; m <<= 1) {
            lrow0[i] += __shfl_xor(lrow0[i], m);
            lrow1[i] += __shfl_xor(lrow1[i], m);
        }
    }
    if (r16 == 0) {
#pragma unroll
        for (int i = 0; i < 4; i++) {
            redl[rg][kg * 4 + i][eh]      = lrow0[i];
            redl[rg][16 + kg * 4 + i][eh] = lrow1[i];
        }
    }
    __syncthreads();
    size_t prow0 = (size_t)z * BS_ + (size_t)b * S_ + qrow0;
    if (eh == 0 && r16 == 0) {
#pragma unroll
        for (int i = 0; i < 4; i++) {
            int q = kg * 4 + i;
            pl[prow0 + q]      = redl[rg][q][0] + redl[rg][q][1];
            pl[prow0 + 16 + q] = redl[rg][16 + q][0] + redl[rg][16 + q][1];
        }
    }
#pragma unroll
    for (int i = 0; i < 4; i++) {
#pragma unroll
        for (int cf = 0; cf < 8; cf++) {
            pacc[(prow0 + kg * 4 + i) * E_ + ebase + cf * 16 + r16]      = acc0[cf][i];
            pacc[(prow0 + 16 + kg * 4 + i) * E_ + ebase + cf * 16 + r16] = acc1[cf][i];
        }
    }
}

// ---------------- fused merge + residual + layernorm: x = LN(x + merge)*g + b ----------------
__global__ __launch_bounds__(256) void k_aln(const float* __restrict__ pacc,
                                             const float* __restrict__ pl,
                                             float* __restrict__ x,
                                             const float* __restrict__ g,
                                             const float* __restrict__ bb) {
    int wv = threadIdx.x >> 6, lane = threadIdx.x & 63;
    size_t row = (size_t)blockIdx.x * 4 + wv;
    float inv = 1.0f / (pl[row] + pl[BS_ + row]);
    f32x4 a0 = ((const f32x4*)(pacc + row * E_))[lane];
    f32x4 a1 = ((const f32x4*)(pacc + (size_t)BS_ * E_ + row * E_))[lane];
    f32x4 xv = ((const f32x4*)(x + row * E_))[lane];
    f32x4 v;
    float s = 0.f, sq = 0.f;
#pragma unroll
    for (int j = 0; j < 4; j++) {
        v[j] = xv[j] + (a0[j] + a1[j]) * inv;
        s += v[j]; sq += v[j] * v[j];
    }
#pragma unroll
    for (int m = 1; m <= 32; m <<= 1) { s += __shfl_xor(s, m); sq += __shfl_xor(sq, m); }
    float mean = s * (1.f / E_);
    float var = sq * (1.f / E_) - mean * mean;
    float rstd = rsqrtf(var + 1e-5f);
    f32x4 gv = ((const f32x4*)g)[lane];
    f32x4 bv = ((const f32x4*)bb)[lane];
    f32x4 o;
#pragma unroll
    for (int j = 0; j < 4; j++) o[j] = (v[j] - mean) * rstd * gv[j] + bv[j];
    ((f32x4*)(x + row * E_))[lane] = o;
}

// ---------------- W2 transpose to bf16 (tiled): (1024,256) -> (256,1024) ----------------
__global__ __launch_bounds__(256) void k_w2t(const float* __restrict__ W2l,
                                             __hip_bfloat16* __restrict__ w2t) {
    __shared__ __align__(16) __bf16 tile[64][72];
    int k0 = blockIdx.x * 64, e0 = blockIdx.y * 64;
    int tid = threadIdx.x;
#pragma unroll
    for (int half = 0; half < 2; half++) {
        int r  = half * 32 + (tid >> 3);      // k row
        int c8 = (tid & 7) * 8;               // e offset
        f32x4 v0 = *(const f32x4*)(W2l + (size_t)(k0 + r) * E_ + e0 + c8);
        f32x4 v1 = *(const f32x4*)(W2l + (size_t)(k0 + r) * E_ + e0 + c8 + 4);
#pragma unroll
        for (int j = 0; j < 4; j++) { tile[r][c8 + j] = (__bf16)v0[j]; tile[r][c8 + 4 + j] = (__bf16)v1[j]; }
    }
    __syncthreads();
#pragma unroll
    for (int half = 0; half < 2; half++) {
        int e  = half * 32 + (tid >> 3);
        int k8 = (tid & 7) * 8;
        bf16x8 v;
#pragma unroll
        for (int j = 0; j < 8; j++) v[j] = tile[k8 + j][e];
        *(bf16x8*)(w2t + (size_t)(e0 + e) * FF_ + k0 + k8) = v;
    }
}

// ---------------- fused FFN: rank-8 h-compute + GEMM + bias + residual + LN ----------------
// h[r][k] = relu(sum_i qm[r][i] W1[i][k] + b1[k]) computed per 64-k chunk into LDS (A-tile);
// B-tile (w2t rows) staged via global_load_lds with pre-swizzled source.
// grid BS_/32, 4 waves; wave = 32 rows x 64 cols (ebQ = wv*64).
__global__ __launch_bounds__(256) void k_ffn(const float* __restrict__ x,
                                             const float* __restrict__ theta_l,
                                             const float* __restrict__ W1l,
                                             const float* __restrict__ b1l,
                                             const __hip_bfloat16* __restrict__ w2t,
                                             const float* __restrict__ b2l,
                                             const float* __restrict__ g,
                                             const float* __restrict__ bb) {
    __shared__ __align__(16) __bf16 Bld[256 * 64];   // [e][k64] linear (dest of global_load_lds)
    __shared__ __align__(16) __bf16 Ald[32 * 64];    // [r][k64], chunk ^= r&7
    __shared__ float qmld[32][9];
    __shared__ float reds[32][4][2];
    int tid = threadIdx.x;
    int wv = tid >> 6, lane = tid & 63;
    int r16 = lane & 15, kg = lane >> 4;
    int rbase = blockIdx.x * 32;
    int ebQ = wv * 64;

    {   // qm[r][i] = cos(x[row][i]) * cos(theta[i])
        int r = tid >> 3, i = tid & 7;
        qmld[r][i] = __cosf(x[(size_t)(rbase + r) * E_ + i]) * __cosf(theta_l[i]);
    }

    auto issue_B = [&](int kt) {
#pragma unroll
        for (int s = 0; s < 8; s++) {
            int seg = wv * 8 + s;                       // 32 x 1KB segments
            int e = seg * 8 + (lane >> 3);
            int c = lane & 7;
            const __hip_bfloat16* src = w2t + (size_t)e * FF_ + kt * 64 + ((c ^ (e & 7)) * 8);
            __builtin_amdgcn_global_load_lds((const __attribute__((address_space(1))) void*)src,
                                             (__attribute__((address_space(3))) void*)(Bld + seg * 512),
                                             16, 0, 0);
        }
    };
    auto compute_h = [&](int kt) {
        int r = tid >> 3, c = tid & 7;
        int k = kt * 64 + c * 8;
        f32x4 h0 = *(const f32x4*)(b1l + k);
        f32x4 h1 = *(const f32x4*)(b1l + k + 4);
#pragma unroll
        for (int i = 0; i < 8; i++) {
            float qv = qmld[r][i];
            f32x4 w0 = *(const f32x4*)(W1l + (size_t)i * FF_ + k);
            f32x4 w1 = *(const f32x4*)(W1l + (size_t)i * FF_ + k + 4);
#pragma unroll
            for (int j = 0; j < 4; j++) { h0[j] = fmaf(qv, w0[j], h0[j]); h1[j] = fmaf(qv, w1[j], h1[j]); }
        }
        bf16x8 hv;
#pragma unroll
        for (int j = 0; j < 4; j++) {
            hv[j]     = (__bf16)fmaxf(h0[j], 0.f);
            hv[4 + j] = (__bf16)fmaxf(h1[j], 0.f);
        }
        *(bf16x8*)&Ald[r * 64 + ((c ^ (r & 7)) * 8)] = hv;
    };

    // prologue
    issue_B(0);
    __syncthreads();          // qmld visible (also drains B(0))
    compute_h(0);
    __syncthreads();          // Ald(0) visible

    f32x4 acc[2][4];
#pragma unroll
    for (int qs = 0; qs < 2; qs++)
#pragma unroll
        for (int cf = 0; cf < 4; cf++) acc[qs][cf] = (f32x4){0.f, 0.f, 0.f, 0.f};

    for (int kt = 0; kt < FF_ / 64; kt++) {
        bf16x8 aq[2][2];
#pragma unroll
        for (int qs = 0; qs < 2; qs++)
#pragma unroll
            for (int kk = 0; kk < 2; kk++)
                aq[qs][kk] = *(const bf16x8*)&Ald[(qs * 16 + r16) * 64 + (((kk * 4 + kg) ^ (r16 & 7)) * 8)];
#pragma unroll
        for (int cf = 0; cf < 4; cf++) {
            int e = ebQ + cf * 16 + r16;
#pragma unroll
            for (int kk = 0; kk < 2; kk++) {
                bf16x8 bv = *(const bf16x8*)&Bld[e * 64 + (((kk * 4 + kg) ^ (e & 7)) * 8)];
                acc[0][cf] = MFMA16(aq[0][kk], bv, acc[0][cf]);
                acc[1][cf] = MFMA16(aq[1][kk], bv, acc[1][cf]);
            }
        }
        __syncthreads();                 // reads of tile kt complete
        if (kt + 1 < FF_ / 64) {
            issue_B(kt + 1);             // in flight under h-compute
            compute_h(kt + 1);
            __syncthreads();             // drains vmcnt (B landed) + Ald writes
        }
    }

    // epilogue: bias + residual + layernorm
    float sA[2][4] = {{0.f,0.f,0.f,0.f},{0.f,0.f,0.f,0.f}};
    float sQ[2][4] = {{0.f,0.f,0.f,0.f},{0.f,0.f,0.f,0.f}};
#pragma unroll
    for (int qs = 0; qs < 2; qs++)
#pragma unroll
        for (int cf = 0; cf < 4; cf++) {
            int e = ebQ + cf * 16 + r16;
            float b2v = b2l[e];
#pragma unroll
            for (int i = 0; i < 4; i++) {
                size_t orow = (size_t)rbase + qs * 16 + kg * 4 + i;
                float t = acc[qs][cf][i] + b2v + x[orow * E_ + e];
                acc[qs][cf][i] = t;
                sA[qs][i] += t; sQ[qs][i] += t * t;
            }
        }
#pragma unroll
    for (int qs = 0; qs < 2; qs++)
#pragma unroll
        for (int i = 0; i < 4; i++) {
#pragma unroll
            for (int m = 1; m <= 8; m <<= 1) {
                sA[qs][i] += __shfl_xor(sA[qs][i], m);
                sQ[qs][i] += __shfl_xor(sQ[qs][i], m);
            }
        }
    if (r16 == 0) {
#pragma unroll
        for (int qs = 0; qs < 2; qs++)
#pragma unroll
            for (int i = 0; i < 4; i++) {
                int row = qs * 16 + kg * 4 + i;
                reds[row][wv][0] = sA[qs][i];
                reds[row][wv][1] = sQ[qs][i];
            }
    }
    __syncthreads();
    float mean[2][4], rstd[2][4];
#pragma unroll
    for (int qs = 0; qs < 2; qs++)
#pragma unroll
        for (int i = 0; i < 4; i++) {
            int row = qs * 16 + kg * 4 + i;
            float S = reds[row][0][0] + reds[row][1][0] + reds[row][2][0] + reds[row][3][0];
            float Q = reds[row][0][1] + reds[row][1][1] + reds[row][2][1] + reds[row][3][1];
            mean[qs][i] = S * (1.f / E_);
            float var = Q * (1.f / E_) - mean[qs][i] * mean[qs][i];
            rstd[qs][i] = rsqrtf(var + 1e-5f);
        }
    float* xo = (float*)x;
#pragma unroll
    for (int qs = 0; qs < 2; qs++)
#pragma unroll
        for (int cf = 0; cf < 4; cf++) {
            int e = ebQ + cf * 16 + r16;
            float gv = g[e], bv = bb[e];
#pragma unroll
            for (int i = 0; i < 4; i++) {
                size_t orow = (size_t)rbase + qs * 16 + kg * 4 + i;
                xo[orow * E_ + e] = (acc[qs][cf][i] - mean[qs][i]) * rstd[qs][i] * gv + bv;
            }
        }
}

// ---------------- mean over S (two-stage, deterministic) ----------------
__global__ __launch_bounds__(256) void k_mean(const float* __restrict__ x, float* __restrict__ psum) {
    int c = blockIdx.x, b = blockIdx.y, e = threadIdx.x;
    float s = 0.f;
    size_t base = ((size_t)b * S_ + c * 128) * E_ + e;
    for (int r = 0; r < 128; r++) s += x[base + (size_t)r * E_];
    psum[(c * 8 + b) * E_ + e] = s;
}

__global__ __launch_bounds__(256) void k_mean2(const float* __restrict__ psum, float* __restrict__ xmean) {
    int idx = blockIdx.x * 256 + threadIdx.x;   // 0..2047 -> (b,e)
    int b = idx >> 8, e = idx & 255;
    float s = 0.f;
    for (int c = 0; c < 16; c++) s += psum[(c * 8 + b) * E_ + e];
    xmean[idx] = s * (1.f / S_);
}

// ---------------- classifier ----------------
__global__ __launch_bounds__(128) void k_cls(const float* __restrict__ xmean,
                                             const float* __restrict__ Wc,
                                             const float* __restrict__ bc,
                                             float* __restrict__ outp) {
    int t = threadIdx.x;
    if (t >= B_ * NC_) return;
    int b = t / NC_, c = t % NC_;
    float s = bc[c];
    for (int e = 0; e < E_; e++) s += xmean[b * E_ + e] * Wc[e * NC_ + c];
    outp[t] = s;
}

extern "C" void kernel_launch(void* const* d_in, const int* in_sizes, int n_in,
                              void* d_out, int out_size, void* d_ws, size_t ws_size,
                              hipStream_t stream) {
    (void)in_sizes; (void)n_in; (void)out_size; (void)ws_size;
    const int*   tokens = (const int*)d_in[0];
    const float* emb    = (const float*)d_in[1];
    const float* phi    = (const float*)d_in[2];
    const float* theta  = (const float*)d_in[3];
    const float* W1     = (const float*)d_in[4];
    const float* b1     = (const float*)d_in[5];
    const float* W2     = (const float*)d_in[6];
    const float* b2     = (const float*)d_in[7];
    const float* g1     = (const float*)d_in[8];
    const float* beta1  = (const float*)d_in[9];
    const float* g2     = (const float*)d_in[10];
    const float* beta2  = (const float*)d_in[11];
    const float* Wc     = (const float*)d_in[12];
    const float* bc     = (const float*)d_in[13];
    float* outp = (float*)d_out;

    // workspace layout
    float* xbuf = (float*)d_ws;                                        // BS_*E_ f32
    __hip_bfloat16* qbf = (__hip_bfloat16*)(xbuf + (size_t)BS_ * E_);  // BS_*E_ bf16
    __hip_bfloat16* qT  = qbf + (size_t)BS_ * E_;                      // BS_*E_ bf16
    __hip_bfloat16* w2t = qT + (size_t)BS_ * E_;                       // E_*FF_ bf16
    float* psum  = (float*)(w2t + (size_t)E_ * FF_);                   // 16*8*E_ f32
    float* xmean = psum + 16 * 8 * E_;                                 // B_*E_ f32
    float* pl    = xmean + B_ * E_;                                    // NSPLIT*BS_ f32
    float* pacc  = pl + NSPLIT * BS_;                                  // NSPLIT*BS_*E_ f32

    k_embed<<<BS_, 256, 0, stream>>>(tokens, emb, xbuf);

    for (int l = 0; l < 4; l++) {
        k_qt<<<dim3(S_ / 64, E_ / 64, B_), 256, 0, stream>>>(xbuf, phi + l * NQ_, qbf, qT);
        k_attn<<<dim3(S_ / 64, B_, NSPLIT), 256, 0, stream>>>(qbf, qT, pacc, pl);
        k_aln<<<BS_ / 4, 256, 0, stream>>>(pacc, pl, xbuf, g1 + l * E_, beta1 + l * E_);
        k_w2t<<<dim3(FF_ / 64, E_ / 64), 256, 0, stream>>>(W2 + (size_t)l * FF_ * E_, w2t);
        k_ffn<<<BS_ / 32, 256, 0, stream>>>(xbuf, theta + l * NQ_,
                                            W1 + (size_t)l * NQ_ * FF_, b1 + (size_t)l * FF_,
                                            w2t, b2 + (size_t)l * E_,
                                            g2 + l * E_, beta2 + l * E_);
    }

    k_mean<<<dim3(16, B_), 256, 0, stream>>>(xbuf, psum);
    k_mean2<<<8, 256, 0, stream>>>(psum, xmean);
    k_cls<<<1, 128, 0, stream>>>(xmean, Wc, bc, outp);
}

// Round 9
// 477.667 us; speedup vs baseline: 4.0519x; 1.1621x over previous
//
#include <hip/hip_runtime.h>
#include <hip/hip_bf16.h>

#define B_ 8
#define S_ 2048
#define E_ 256
#define FF_ 1024
#define NQ_ 8
#define NC_ 10
#define BS_ (B_*S_)
#define NSPLIT 2
#define KVBLK 32

typedef __bf16 bf16x8 __attribute__((ext_vector_type(8)));
typedef float f32x4 __attribute__((ext_vector_type(4)));

#define MFMA16(a,b,c) __builtin_amdgcn_mfma_f32_16x16x32_bf16(a,b,c,0,0,0)

// ---------------- embed + positional encoding ----------------
__global__ __launch_bounds__(256) void k_embed(const int* __restrict__ tokens,
                                               const float* __restrict__ emb,
                                               float* __restrict__ x) {
    int row = blockIdx.x;           // 0..BS_-1
    int e = threadIdx.x;            // 0..255
    int s = row & (S_ - 1);
    int tok = tokens[row];
    int i2 = e & ~1;                // 2*(e/2)
    float d = __expf((float)i2 * (-9.210340371976184f / 256.0f));
    float ang = (float)s * d;
    float pe = (e & 1) ? __cosf(ang) : __sinf(ang);
    x[(size_t)row * E_ + e] = emb[(size_t)tok * E_ + e] + pe;
}

// ---------------- fused q-compute + transpose ----------------
__global__ __launch_bounds__(256) void k_qt(const float* __restrict__ x,
                                            const float* __restrict__ phi_l,
                                            __hip_bfloat16* __restrict__ qbf,
                                            __hip_bfloat16* __restrict__ qT) {
    __shared__ __align__(16) __bf16 tile[64][76];
    int t0 = blockIdx.x * 64, e0 = blockIdx.y * 64, b = blockIdx.z;
    int tid = threadIdx.x;
    float ph[8];
#pragma unroll
    for (int j = 0; j < 8; j++) ph[j] = phi_l[j];
#pragma unroll
    for (int k = 0; k < 2; k++) {
        int idx = k * 256 + tid;
        int r = idx >> 3, hh = idx & 7;           // row, head-slot (8 e each)
        const float* xp = x + ((size_t)b * S_ + t0 + r) * E_ + e0 + hh * 8;
        f32x4 x0 = *(const f32x4*)xp;
        f32x4 x1 = *(const f32x4*)(xp + 4);
        float c[8];
#pragma unroll
        for (int j = 0; j < 4; j++) {
            c[j]     = __cosf(x0[j] + ph[j]);
            c[4 + j] = __cosf(x1[j] + ph[4 + j]);
        }
        float q[8];
        float run = c[0];
#pragma unroll
        for (int i = 1; i < 8; i++) { run *= c[i]; q[i] = run; }
        float o0 = c[1];
#pragma unroll
        for (int i = 2; i < 8; i++) o0 *= c[i];
        q[0] = o0;
        bf16x8 v;
#pragma unroll
        for (int j = 0; j < 8; j++) v[j] = (__bf16)q[j];
        *(bf16x8*)(qbf + ((size_t)b * S_ + t0 + r) * E_ + e0 + hh * 8) = v;
        *(bf16x8*)&tile[r][hh * 8] = v;
    }
    __syncthreads();
#pragma unroll
    for (int k = 0; k < 2; k++) {
        int idx = k * 256 + tid;
        int el = idx >> 3, tc = idx & 7;          // e-local, t-chunk
        bf16x8 v;
#pragma unroll
        for (int j = 0; j < 8; j++) v[j] = tile[tc * 8 + j][el];
        *(bf16x8*)(qT + ((size_t)b * E_ + e0 + el) * S_ + t0 + tc * 8) = v;
    }
}

// ---------------- flash attention, Wq=32, async K-stage, 2 barriers/iter ----------------
// p = exp(s - 44): |s| <= 90.5, diag s_ii >= 0 => no overflow, row-sum >= e^-44.
// Mathematically identical to softmax. grid (S_/64, B_, NSPLIT), 4 waves.
__global__ __launch_bounds__(256, 2) void k_attn(const __hip_bfloat16* __restrict__ qbf,
                                                 const __hip_bfloat16* __restrict__ qT,
                                                 float* __restrict__ pacc,
                                                 float* __restrict__ pl) {
    __shared__ __align__(16) __bf16 ktile[KVBLK * 256];   // [kv32][e256], chunk16 ^= row&7
    __shared__ __align__(16) __bf16 vtile[256 * 36];      // [e][kv32+4 pad] (18-word rows)
    __shared__ __align__(16) __bf16 plds[2][32][36];      // [rg][q32][kv32+4]
    __shared__ float redl[2][32][2];
    const float SCALE = 0.3535533905932738f;              // 1/sqrt(8)
    int qt   = blockIdx.x;
    int b    = blockIdx.y;
    int z    = blockIdx.z;
    int tid  = threadIdx.x;
    int wv   = tid >> 6;
    int lane = tid & 63;
    int r16  = lane & 15;
    int kg   = lane >> 4;
    int rg   = wv >> 1, eh = wv & 1;
    int qrow0 = qt * 64 + rg * 32;
    int ebase = eh * 128;

    bf16x8 aq[2][8];
#pragma unroll
    for (int qs = 0; qs < 2; qs++)
#pragma unroll
        for (int kk = 0; kk < 8; kk++)
            aq[qs][kk] = *(const bf16x8*)(qbf + ((size_t)b * S_ + qrow0 + qs * 16 + r16) * E_ + kk * 32 + kg * 8);

    f32x4 acc0[8], acc1[8];
#pragma unroll
    for (int cf = 0; cf < 8; cf++) { acc0[cf] = (f32x4){0.f,0.f,0.f,0.f}; acc1[cf] = (f32x4){0.f,0.f,0.f,0.f}; }
    float lrow0[4] = {0.f,0.f,0.f,0.f}, lrow1[4] = {0.f,0.f,0.f,0.f};

    int k0 = z * (S_ / NSPLIT);
    const int NT = (S_ / NSPLIT) / KVBLK;   // 32
    bf16x8 vst[4];

    auto issue_k = [&](int kb) {
#pragma unroll
        for (int c = 0; c < 4; c++) {
            int seg = wv * 4 + c;                       // 16 x 1KB segments
            int r = seg * 2 + (lane >> 5);
            int ch = lane & 31;
            const __hip_bfloat16* src = qbf + ((size_t)b * S_ + kb + r) * E_ + ((ch ^ (r & 7)) * 8);
            __builtin_amdgcn_global_load_lds((const __attribute__((address_space(1))) void*)src,
                                             (__attribute__((address_space(3))) void*)(ktile + seg * 512),
                                             16, 0, 0);
        }
    };
    auto issue_v = [&](int kb) {
#pragma unroll
        for (int p = 0; p < 4; p++) {
            int slot = p * 256 + tid;
            vst[p] = *(const bf16x8*)(qT + ((size_t)b * E_ + (slot >> 2)) * S_ + kb + (slot & 3) * 8);
        }
    };
    auto write_v = [&]() {
#pragma unroll
        for (int p = 0; p < 4; p++) {
            int slot = p * 256 + tid;
            *(bf16x8*)&vtile[(slot >> 2) * 36 + (slot & 3) * 8] = vst[p];
        }
    };

    // prologue: tile 0
    issue_k(k0);
    issue_v(k0);
    asm volatile("s_waitcnt vmcnt(0)" ::: "memory");
    write_v();
    __syncthreads();

    for (int kt = 0; kt < NT; kt++) {
        // ---- QK^T: this wave's kv-half [eh*16, eh*16+16) ----
        f32x4 s0 = (f32x4){0.f,0.f,0.f,0.f}, s1 = (f32x4){0.f,0.f,0.f,0.f};
#pragma unroll
        for (int kk = 0; kk < 8; kk++) {
            bf16x8 bk = *(const bf16x8*)&ktile[(eh * 16 + r16) * 256 + (((kk * 4 + kg) ^ (r16 & 7)) * 8)];
            s0 = MFMA16(aq[0][kk], bk, s0);
            s1 = MFMA16(aq[1][kk], bk, s1);
        }
#pragma unroll
        for (int i = 0; i < 4; i++) {
            float p0 = __expf(fmaf(s0[i], SCALE, -44.0f));
            float p1 = __expf(fmaf(s1[i], SCALE, -44.0f));
            plds[rg][kg * 4 + i][eh * 16 + r16]      = (__bf16)p0;
            plds[rg][16 + kg * 4 + i][eh * 16 + r16] = (__bf16)p1;
            lrow0[i] += p0;
            lrow1[i] += p1;
        }
        __syncthreads();                         // B2: P complete, QK reads done
        bool more = (kt + 1 < NT);
        if (more) {                              // async: land under PV + barrier
            int kn = k0 + (kt + 1) * KVBLK;
            issue_k(kn);
            issue_v(kn);
        }
        // ---- PV ----
        bf16x8 pa0 = *(const bf16x8*)&plds[rg][r16][kg * 8];
        bf16x8 pa1 = *(const bf16x8*)&plds[rg][16 + r16][kg * 8];
#pragma unroll
        for (int cf = 0; cf < 8; cf++) {
            bf16x8 bv = *(const bf16x8*)&vtile[(ebase + cf * 16 + r16) * 36 + kg * 8];
            acc0[cf] = MFMA16(pa0, bv, acc0[cf]);
            acc1[cf] = MFMA16(pa1, bv, acc1[cf]);
        }
        if (more) {
            asm volatile("s_waitcnt vmcnt(0)" ::: "memory");
            __syncthreads();                     // B1: PV reads done, K landed
            write_v();
        }
    }

    // ---- epilogue: l totals then partial writes ----
#pragma unroll
    for (int i = 0; i < 4; i++) {
#pragma unroll
        for (int m = 1; m <= 8; m <<= 1) {
            lrow0[i] += __shfl_xor(lrow0[i], m);
            lrow1[i] += __shfl_xor(lrow1[i], m);
        }
    }
    if (r16 == 0) {
#pragma unroll
        for (int i = 0; i < 4; i++) {
            redl[rg][kg * 4 + i][eh]      = lrow0[i];
            redl[rg][16 + kg * 4 + i][eh] = lrow1[i];
        }
    }
    __syncthreads();
    size_t prow0 = (size_t)z * BS_ + (size_t)b * S_ + qrow0;
    if (eh == 0 && r16 == 0) {
#pragma unroll
        for (int i = 0; i < 4; i++) {
            int q = kg * 4 + i;
            pl[prow0 + q]      = redl[rg][q][0] + redl[rg][q][1];
            pl[prow0 + 16 + q] = redl[rg][16 + q][0] + redl[rg][16 + q][1];
        }
    }
#pragma unroll
    for (int i = 0; i < 4; i++) {
#pragma unroll
        for (int cf = 0; cf < 8; cf++) {
            pacc[(prow0 + kg * 4 + i) * E_ + ebase + cf * 16 + r16]      = acc0[cf][i];
            pacc[(prow0 + 16 + kg * 4 + i) * E_ + ebase + cf * 16 + r16] = acc1[cf][i];
        }
    }
}

// ---------------- fused merge + residual + layernorm: x = LN(x + merge)*g + b ----------------
__global__ __launch_bounds__(256) void k_aln(const float* __restrict__ pacc,
                                             const float* __restrict__ pl,
                                             float* __restrict__ x,
                                             const float* __restrict__ g,
                                             const float* __restrict__ bb) {
    int wv = threadIdx.x >> 6, lane = threadIdx.x & 63;
    size_t row = (size_t)blockIdx.x * 4 + wv;
    float inv = 1.0f / (pl[row] + pl[BS_ + row]);
    f32x4 a0 = ((const f32x4*)(pacc + row * E_))[lane];
    f32x4 a1 = ((const f32x4*)(pacc + (size_t)BS_ * E_ + row * E_))[lane];
    f32x4 xv = ((const f32x4*)(x + row * E_))[lane];
    f32x4 v;
    float s = 0.f, sq = 0.f;
#pragma unroll
    for (int j = 0; j < 4; j++) {
        v[j] = xv[j] + (a0[j] + a1[j]) * inv;
        s += v[j]; sq += v[j] * v[j];
    }
#pragma unroll
    for (int m = 1; m <= 32; m <<= 1) { s += __shfl_xor(s, m); sq += __shfl_xor(sq, m); }
    float mean = s * (1.f / E_);
    float var = sq * (1.f / E_) - mean * mean;
    float rstd = rsqrtf(var + 1e-5f);
    f32x4 gv = ((const f32x4*)g)[lane];
    f32x4 bv = ((const f32x4*)bb)[lane];
    f32x4 o;
#pragma unroll
    for (int j = 0; j < 4; j++) o[j] = (v[j] - mean) * rstd * gv[j] + bv[j];
    ((f32x4*)(x + row * E_))[lane] = o;
}

// ---------------- W2 transpose to bf16 (tiled): (1024,256) -> (256,1024) ----------------
__global__ __launch_bounds__(256) void k_w2t(const float* __restrict__ W2l,
                                             __hip_bfloat16* __restrict__ w2t) {
    __shared__ __align__(16) __bf16 tile[64][72];
    int k0 = blockIdx.x * 64, e0 = blockIdx.y * 64;
    int tid = threadIdx.x;
#pragma unroll
    for (int half = 0; half < 2; half++) {
        int r  = half * 32 + (tid >> 3);      // k row
        int c8 = (tid & 7) * 8;               // e offset
        f32x4 v0 = *(const f32x4*)(W2l + (size_t)(k0 + r) * E_ + e0 + c8);
        f32x4 v1 = *(const f32x4*)(W2l + (size_t)(k0 + r) * E_ + e0 + c8 + 4);
#pragma unroll
        for (int j = 0; j < 4; j++) { tile[r][c8 + j] = (__bf16)v0[j]; tile[r][c8 + 4 + j] = (__bf16)v1[j]; }
    }
    __syncthreads();
#pragma unroll
    for (int half = 0; half < 2; half++) {
        int e  = half * 32 + (tid >> 3);
        int k8 = (tid & 7) * 8;
        bf16x8 v;
#pragma unroll
        for (int j = 0; j < 8; j++) v[j] = tile[k8 + j][e];
        *(bf16x8*)(w2t + (size_t)(e0 + e) * FF_ + k0 + k8) = v;
    }
}

// ---------------- fused FFN: rank-8 h + GEMM + bias + residual + LN, dbuf 1-barrier/iter ----------------
// h[r][k] = relu(qm[r]·W1[:,k] + b1[k]) computed into LDS A-tile (double-buffered);
// B-tile (w2t) staged via global_load_lds (double-buffered), issued a full iter ahead.
// W1/b1 chunk prefetched to regs at top of iter, consumed after MFMA.
__global__ __launch_bounds__(256) void k_ffn(const float* __restrict__ x,
                                             const float* __restrict__ theta_l,
                                             const float* __restrict__ W1l,
                                             const float* __restrict__ b1l,
                                             const __hip_bfloat16* __restrict__ w2t,
                                             const float* __restrict__ b2l,
                                             const float* __restrict__ g,
                                             const float* __restrict__ bb) {
    __shared__ __align__(16) __bf16 Bld[2][256 * 64];   // [buf][e][k64] linear (global_load_lds dest)
    __shared__ __align__(16) __bf16 Ald[2][32 * 64];    // [buf][r][k64], chunk ^= r&7
    __shared__ float qmld[32][9];
    __shared__ float reds[32][4][2];
    int tid = threadIdx.x;
    int wv = tid >> 6, lane = tid & 63;
    int r16 = lane & 15, kg = lane >> 4;
    int rbase = blockIdx.x * 32;
    int ebQ = wv * 64;
    const int NT = FF_ / 64;   // 16

    {   // qm[r][i] = cos(x[row][i]) * cos(theta[i])
        int r = tid >> 3, i = tid & 7;
        qmld[r][i] = __cosf(x[(size_t)(rbase + r) * E_ + i]) * __cosf(theta_l[i]);
    }

    f32x4 w[18];   // W1 chunk (16) + b1 chunk (2), all constant-indexed

    auto issue_B = [&](int kt, int buf) {
#pragma unroll
        for (int s = 0; s < 8; s++) {
            int seg = wv * 8 + s;                       // 32 x 1KB segments
            int e = seg * 8 + (lane >> 3);
            int c = lane & 7;
            const __hip_bfloat16* src = w2t + (size_t)e * FF_ + kt * 64 + ((c ^ (e & 7)) * 8);
            __builtin_amdgcn_global_load_lds((const __attribute__((address_space(1))) void*)src,
                                             (__attribute__((address_space(3))) void*)(&Bld[buf][seg * 512]),
                                             16, 0, 0);
        }
    };
    auto load_W1 = [&](int kt) {
        int c = tid & 7;
        int k = kt * 64 + c * 8;
#pragma unroll
        for (int i = 0; i < 8; i++) {
            w[2 * i]     = *(const f32x4*)(W1l + (size_t)i * FF_ + k);
            w[2 * i + 1] = *(const f32x4*)(W1l + (size_t)i * FF_ + k + 4);
        }
        w[16] = *(const f32x4*)(b1l + k);
        w[17] = *(const f32x4*)(b1l + k + 4);
    };
    auto math_h = [&](int buf) {
        int r = tid >> 3, c = tid & 7;
        f32x4 h0 = w[16], h1 = w[17];
#pragma unroll
        for (int i = 0; i < 8; i++) {
            float qv = qmld[r][i];
#pragma unroll
            for (int j = 0; j < 4; j++) {
                h0[j] = fmaf(qv, w[2 * i][j], h0[j]);
                h1[j] = fmaf(qv, w[2 * i + 1][j], h1[j]);
            }
        }
        bf16x8 hv;
#pragma unroll
        for (int j = 0; j < 4; j++) {
            hv[j]     = (__bf16)fmaxf(h0[j], 0.f);
            hv[4 + j] = (__bf16)fmaxf(h1[j], 0.f);
        }
        *(bf16x8*)&Ald[buf][r * 64 + ((c ^ (r & 7)) * 8)] = hv;
    };

    // prologue
    issue_B(0, 0);
    load_W1(0);
    __syncthreads();          // qmld visible; B(0) drained
    math_h(0);
    __syncthreads();          // Ald[0] visible

    f32x4 acc[2][4];
#pragma unroll
    for (int qs = 0; qs < 2; qs++)
#pragma unroll
        for (int cf = 0; cf < 4; cf++) acc[qs][cf] = (f32x4){0.f, 0.f, 0.f, 0.f};

    for (int kt = 0; kt < NT; kt++) {
        int cur = kt & 1;
        bool more = (kt + 1 < NT);
        if (more) {
            issue_B(kt + 1, cur ^ 1);   // in flight across MFMA phase
            load_W1(kt + 1);            // reg prefetch, consumed after MFMA
        }
        bf16x8 aq[2][2];
#pragma unroll
        for (int qs = 0; qs < 2; qs++)
#pragma unroll
            for (int kk = 0; kk < 2; kk++)
                aq[qs][kk] = *(const bf16x8*)&Ald[cur][(qs * 16 + r16) * 64 + (((kk * 4 + kg) ^ (r16 & 7)) * 8)];
#pragma unroll
        for (int cf = 0; cf < 4; cf++) {
            int e = ebQ + cf * 16 + r16;
#pragma unroll
            for (int kk = 0; kk < 2; kk++) {
                bf16x8 bv = *(const bf16x8*)&Bld[cur][e * 64 + (((kk * 4 + kg) ^ (e & 7)) * 8)];
                acc[0][cf] = MFMA16(aq[0][kk], bv, acc[0][cf]);
                acc[1][cf] = MFMA16(aq[1][kk], bv, acc[1][cf]);
            }
        }
        if (more) {
            math_h(cur ^ 1);            // W1 regs already resident
            __syncthreads();            // drains B(kt+1) + Ald writes; guards buf reuse
        }
    }

    // epilogue: bias + residual + layernorm
    float sA[2][4] = {{0.f,0.f,0.f,0.f},{0.f,0.f,0.f,0.f}};
    float sQ[2][4] = {{0.f,0.f,0.f,0.f},{0.f,0.f,0.f,0.f}};
#pragma unroll
    for (int qs = 0; qs < 2; qs++)
#pragma unroll
        for (int cf = 0; cf < 4; cf++) {
            int e = ebQ + cf * 16 + r16;
            float b2v = b2l[e];
#pragma unroll
            for (int i = 0; i < 4; i++) {
                size_t orow = (size_t)rbase + qs * 16 + kg * 4 + i;
                float t = acc[qs][cf][i] + b2v + x[orow * E_ + e];
                acc[qs][cf][i] = t;
                sA[qs][i] += t; sQ[qs][i] += t * t;
            }
        }
#pragma unroll
    for (int qs = 0; qs < 2; qs++)
#pragma unroll
        for (int i = 0; i < 4; i++) {
#pragma unroll
            for (int m = 1; m <= 8; m <<= 1) {
                sA[qs][i] += __shfl_xor(sA[qs][i], m);
                sQ[qs][i] += __shfl_xor(sQ[qs][i], m);
            }
        }
    if (r16 == 0) {
#pragma unroll
        for (int qs = 0; qs < 2; qs++)
#pragma unroll
            for (int i = 0; i < 4; i++) {
                int row = qs * 16 + kg * 4 + i;
                reds[row][wv][0] = sA[qs][i];
                reds[row][wv][1] = sQ[qs][i];
            }
    }
    __syncthreads();
    float mean[2][4], rstd[2][4];
#pragma unroll
    for (int qs = 0; qs < 2; qs++)
#pragma unroll
        for (int i = 0; i < 4; i++) {
            int row = qs * 16 + kg * 4 + i;
            float S = reds[row][0][0] + reds[row][1][0] + reds[row][2][0] + reds[row][3][0];
            float Q = reds[row][0][1] + reds[row][1][1] + reds[row][2][1] + reds[row][3][1];
            mean[qs][i] = S * (1.f / E_);
            float var = Q * (1.f / E_) - mean[qs][i] * mean[qs][i];
            rstd[qs][i] = rsqrtf(var + 1e-5f);
        }
    float* xo = (float*)x;
#pragma unroll
    for (int qs = 0; qs < 2; qs++)
#pragma unroll
        for (int cf = 0; cf < 4; cf++) {
            int e = ebQ + cf * 16 + r16;
            float gv = g[e], bv = bb[e];
#pragma unroll
            for (int i = 0; i < 4; i++) {
                size_t orow = (size_t)rbase + qs * 16 + kg * 4 + i;
                xo[orow * E_ + e] = (acc[qs][cf][i] - mean[qs][i]) * rstd[qs][i] * gv + bv;
            }
        }
}

// ---------------- mean over S (two-stage, deterministic) ----------------
__global__ __launch_bounds__(256) void k_mean(const float* __restrict__ x, float* __restrict__ psum) {
    int c = blockIdx.x, b = blockIdx.y, e = threadIdx.x;
    float s = 0.f;
    size_t base = ((size_t)b * S_ + c * 128) * E_ + e;
    for (int r = 0; r < 128; r++) s += x[base + (size_t)r * E_];
    psum[(c * 8 + b) * E_ + e] = s;
}

__global__ __launch_bounds__(256) void k_mean2(const float* __restrict__ psum, float* __restrict__ xmean) {
    int idx = blockIdx.x * 256 + threadIdx.x;   // 0..2047 -> (b,e)
    int b = idx >> 8, e = idx & 255;
    float s = 0.f;
    for (int c = 0; c < 16; c++) s += psum[(c * 8 + b) * E_ + e];
    xmean[idx] = s * (1.f / S_);
}

// ---------------- classifier ----------------
__global__ __launch_bounds__(128) void k_cls(const float* __restrict__ xmean,
                                             const float* __restrict__ Wc,
                                             const float* __restrict__ bc,
                                             float* __restrict__ outp) {
    int t = threadIdx.x;
    if (t >= B_ * NC_) return;
    int b = t / NC_, c = t % NC_;
    float s = bc[c];
    for (int e = 0; e < E_; e++) s += xmean[b * E_ + e] * Wc[e * NC_ + c];
    outp[t] = s;
}

extern "C" void kernel_launch(void* const* d_in, const int* in_sizes, int n_in,
                              void* d_out, int out_size, void* d_ws, size_t ws_size,
                              hipStream_t stream) {
    (void)in_sizes; (void)n_in; (void)out_size; (void)ws_size;
    const int*   tokens = (const int*)d_in[0];
    const float* emb    = (const float*)d_in[1];
    const float* phi    = (const float*)d_in[2];
    const float* theta  = (const float*)d_in[3];
    const float* W1     = (const float*)d_in[4];
    const float* b1     = (const float*)d_in[5];
    const float* W2     = (const float*)d_in[6];
    const float* b2     = (const float*)d_in[7];
    const float* g1     = (const float*)d_in[8];
    const float* beta1  = (const float*)d_in[9];
    const float* g2     = (const float*)d_in[10];
    const float* beta2  = (const float*)d_in[11];
    const float* Wc     = (const float*)d_in[12];
    const float* bc     = (const float*)d_in[13];
    float* outp = (float*)d_out;

    // workspace layout
    float* xbuf = (float*)d_ws;                                        // BS_*E_ f32
    __hip_bfloat16* qbf = (__hip_bfloat16*)(xbuf + (size_t)BS_ * E_);  // BS_*E_ bf16
    __hip_bfloat16* qT  = qbf + (size_t)BS_ * E_;                      // BS_*E_ bf16
    __hip_bfloat16* w2t = qT + (size_t)BS_ * E_;                       // E_*FF_ bf16
    float* psum  = (float*)(w2t + (size_t)E_ * FF_);                   // 16*8*E_ f32
    float* xmean = psum + 16 * 8 * E_;                                 // B_*E_ f32
    float* pl    = xmean + B_ * E_;                                    // NSPLIT*BS_ f32
    float* pacc  = pl + NSPLIT * BS_;                                  // NSPLIT*BS_*E_ f32

    k_embed<<<BS_, 256, 0, stream>>>(tokens, emb, xbuf);

    for (int l = 0; l < 4; l++) {
        k_qt<<<dim3(S_ / 64, E_ / 64, B_), 256, 0, stream>>>(xbuf, phi + l * NQ_, qbf, qT);
        k_attn<<<dim3(S_ / 64, B_, NSPLIT), 256, 0, stream>>>(qbf, qT, pacc, pl);
        k_aln<<<BS_ / 4, 256, 0, stream>>>(pacc, pl, xbuf, g1 + l * E_, beta1 + l * E_);
        k_w2t<<<dim3(FF_ / 64, E_ / 64), 256, 0, stream>>>(W2 + (size_t)l * FF_ * E_, w2t);
        k_ffn<<<BS_ / 32, 256, 0, stream>>>(xbuf, theta + l * NQ_,
                                            W1 + (size_t)l * NQ_ * FF_, b1 + (size_t)l * FF_,
                                            w2t, b2 + (size_t)l * E_,
                                            g2 + l * E_, beta2 + l * E_);
    }

    k_mean<<<dim3(16, B_), 256, 0, stream>>>(xbuf, psum);
    k_mean2<<<8, 256, 0, stream>>>(psum, xmean);
    k_cls<<<1, 128, 0, stream>>>(xmean, Wc, bc, outp);
}

// Round 10
// 464.533 us; speedup vs baseline: 4.1665x; 1.0283x over previous
//
#include <hip/hip_runtime.h>
#include <hip/hip_bf16.h>

#define B_ 8
#define S_ 2048
#define E_ 256
#define FF_ 1024
#define NQ_ 8
#define NC_ 10
#define BS_ (B_*S_)
#define NSPLIT 2
#define KVBLK 32

typedef __bf16 bf16x8 __attribute__((ext_vector_type(8)));
typedef float f32x4 __attribute__((ext_vector_type(4)));

#define MFMA16(a,b,c) __builtin_amdgcn_mfma_f32_16x16x32_bf16(a,b,c,0,0,0)

// ---------------- embed + positional encoding ----------------
__global__ __launch_bounds__(256) void k_embed(const int* __restrict__ tokens,
                                               const float* __restrict__ emb,
                                               float* __restrict__ x) {
    int row = blockIdx.x;           // 0..BS_-1
    int e = threadIdx.x;            // 0..255
    int s = row & (S_ - 1);
    int tok = tokens[row];
    int i2 = e & ~1;                // 2*(e/2)
    float d = __expf((float)i2 * (-9.210340371976184f / 256.0f));
    float ang = (float)s * d;
    float pe = (e & 1) ? __cosf(ang) : __sinf(ang);
    x[(size_t)row * E_ + e] = emb[(size_t)tok * E_ + e] + pe;
}

// ---------------- fused q-compute + transpose ----------------
__global__ __launch_bounds__(256) void k_qt(const float* __restrict__ x,
                                            const float* __restrict__ phi_l,
                                            __hip_bfloat16* __restrict__ qbf,
                                            __hip_bfloat16* __restrict__ qT) {
    __shared__ __align__(16) __bf16 tile[64][76];
    int t0 = blockIdx.x * 64, e0 = blockIdx.y * 64, b = blockIdx.z;
    int tid = threadIdx.x;
    float ph[8];
#pragma unroll
    for (int j = 0; j < 8; j++) ph[j] = phi_l[j];
#pragma unroll
    for (int k = 0; k < 2; k++) {
        int idx = k * 256 + tid;
        int r = idx >> 3, hh = idx & 7;           // row, head-slot (8 e each)
        const float* xp = x + ((size_t)b * S_ + t0 + r) * E_ + e0 + hh * 8;
        f32x4 x0 = *(const f32x4*)xp;
        f32x4 x1 = *(const f32x4*)(xp + 4);
        float c[8];
#pragma unroll
        for (int j = 0; j < 4; j++) {
            c[j]     = __cosf(x0[j] + ph[j]);
            c[4 + j] = __cosf(x1[j] + ph[4 + j]);
        }
        float q[8];
        float run = c[0];
#pragma unroll
        for (int i = 1; i < 8; i++) { run *= c[i]; q[i] = run; }
        float o0 = c[1];
#pragma unroll
        for (int i = 2; i < 8; i++) o0 *= c[i];
        q[0] = o0;
        bf16x8 v;
#pragma unroll
        for (int j = 0; j < 8; j++) v[j] = (__bf16)q[j];
        *(bf16x8*)(qbf + ((size_t)b * S_ + t0 + r) * E_ + e0 + hh * 8) = v;
        *(bf16x8*)&tile[r][hh * 8] = v;
    }
    __syncthreads();
#pragma unroll
    for (int k = 0; k < 2; k++) {
        int idx = k * 256 + tid;
        int el = idx >> 3, tc = idx & 7;          // e-local, t-chunk
        bf16x8 v;
#pragma unroll
        for (int j = 0; j < 8; j++) v[j] = tile[tc * 8 + j][el];
        *(bf16x8*)(qT + ((size_t)b * E_ + e0 + el) * S_ + t0 + tc * 8) = v;
    }
}

// ---------------- flash attention, Wq=32, async K-stage, XCD-pinned batches ----------------
// p = exp(s - 44): |s| <= 90.5, diag s_ii >= 0 => no overflow, row-sum >= e^-44.
// Mathematically identical to softmax. 1D grid 512: b = bid&7 pins each batch's
// 2MB K/V working set to one XCD's L2 (R6-measured: FETCH 68.8->16.5MB).
__global__ __launch_bounds__(256, 2) void k_attn(const __hip_bfloat16* __restrict__ qbf,
                                                 const __hip_bfloat16* __restrict__ qT,
                                                 float* __restrict__ pacc,
                                                 float* __restrict__ pl) {
    __shared__ __align__(16) __bf16 ktile[KVBLK * 256];   // [kv32][e256], chunk16 ^= row&7
    __shared__ __align__(16) __bf16 vtile[256 * 36];      // [e][kv32+4 pad] (18-word rows)
    __shared__ __align__(16) __bf16 plds[2][32][36];      // [rg][q32][kv32+4]
    __shared__ float redl[2][32][2];
    const float SCALE = 0.3535533905932738f;              // 1/sqrt(8)
    int bid  = blockIdx.x;
    int b    = bid & 7;                                   // batch == XCD
    int qt   = (bid >> 3) & 31;
    int z    = bid >> 8;
    int tid  = threadIdx.x;
    int wv   = tid >> 6;
    int lane = tid & 63;
    int r16  = lane & 15;
    int kg   = lane >> 4;
    int rg   = wv >> 1, eh = wv & 1;
    int qrow0 = qt * 64 + rg * 32;
    int ebase = eh * 128;

    bf16x8 aq[2][8];
#pragma unroll
    for (int qs = 0; qs < 2; qs++)
#pragma unroll
        for (int kk = 0; kk < 8; kk++)
            aq[qs][kk] = *(const bf16x8*)(qbf + ((size_t)b * S_ + qrow0 + qs * 16 + r16) * E_ + kk * 32 + kg * 8);

    f32x4 acc0[8], acc1[8];
#pragma unroll
    for (int cf = 0; cf < 8; cf++) { acc0[cf] = (f32x4){0.f,0.f,0.f,0.f}; acc1[cf] = (f32x4){0.f,0.f,0.f,0.f}; }
    float lrow0[4] = {0.f,0.f,0.f,0.f}, lrow1[4] = {0.f,0.f,0.f,0.f};

    int k0 = z * (S_ / NSPLIT);
    const int NT = (S_ / NSPLIT) / KVBLK;   // 32
    bf16x8 vst[4];

    auto issue_k = [&](int kb) {
#pragma unroll
        for (int c = 0; c < 4; c++) {
            int seg = wv * 4 + c;                       // 16 x 1KB segments
            int r = seg * 2 + (lane >> 5);
            int ch = lane & 31;
            const __hip_bfloat16* src = qbf + ((size_t)b * S_ + kb + r) * E_ + ((ch ^ (r & 7)) * 8);
            __builtin_amdgcn_global_load_lds((const __attribute__((address_space(1))) void*)src,
                                             (__attribute__((address_space(3))) void*)(ktile + seg * 512),
                                             16, 0, 0);
        }
    };
    auto issue_v = [&](int kb) {
#pragma unroll
        for (int p = 0; p < 4; p++) {
            int slot = p * 256 + tid;
            vst[p] = *(const bf16x8*)(qT + ((size_t)b * E_ + (slot >> 2)) * S_ + kb + (slot & 3) * 8);
        }
    };
    auto write_v = [&]() {
#pragma unroll
        for (int p = 0; p < 4; p++) {
            int slot = p * 256 + tid;
            *(bf16x8*)&vtile[(slot >> 2) * 36 + (slot & 3) * 8] = vst[p];
        }
    };

    // prologue: tile 0
    issue_k(k0);
    issue_v(k0);
    asm volatile("s_waitcnt vmcnt(0)" ::: "memory");
    write_v();
    __syncthreads();

    for (int kt = 0; kt < NT; kt++) {
        // ---- QK^T: this wave's kv-half [eh*16, eh*16+16) ----
        f32x4 s0 = (f32x4){0.f,0.f,0.f,0.f}, s1 = (f32x4){0.f,0.f,0.f,0.f};
#pragma unroll
        for (int kk = 0; kk < 8; kk++) {
            bf16x8 bk = *(const bf16x8*)&ktile[(eh * 16 + r16) * 256 + (((kk * 4 + kg) ^ (r16 & 7)) * 8)];
            s0 = MFMA16(aq[0][kk], bk, s0);
            s1 = MFMA16(aq[1][kk], bk, s1);
        }
#pragma unroll
        for (int i = 0; i < 4; i++) {
            float p0 = __expf(fmaf(s0[i], SCALE, -44.0f));
            float p1 = __expf(fmaf(s1[i], SCALE, -44.0f));
            plds[rg][kg * 4 + i][eh * 16 + r16]      = (__bf16)p0;
            plds[rg][16 + kg * 4 + i][eh * 16 + r16] = (__bf16)p1;
            lrow0[i] += p0;
            lrow1[i] += p1;
        }
        __syncthreads();                         // B2: P complete, QK reads done
        bool more = (kt + 1 < NT);
        if (more) {                              // async: land under PV + barrier
            int kn = k0 + (kt + 1) * KVBLK;
            issue_k(kn);
            issue_v(kn);
        }
        // ---- PV ----
        bf16x8 pa0 = *(const bf16x8*)&plds[rg][r16][kg * 8];
        bf16x8 pa1 = *(const bf16x8*)&plds[rg][16 + r16][kg * 8];
#pragma unroll
        for (int cf = 0; cf < 8; cf++) {
            bf16x8 bv = *(const bf16x8*)&vtile[(ebase + cf * 16 + r16) * 36 + kg * 8];
            acc0[cf] = MFMA16(pa0, bv, acc0[cf]);
            acc1[cf] = MFMA16(pa1, bv, acc1[cf]);
        }
        if (more) {
            asm volatile("s_waitcnt vmcnt(0)" ::: "memory");
            __syncthreads();                     // B1: PV reads done, K landed
            write_v();
        }
    }

    // ---- epilogue: l totals then partial writes ----
#pragma unroll
    for (int i = 0; i < 4; i++) {
#pragma unroll
        for (int m = 1; m <= 8; m <<= 1) {
            lrow0[i] += __shfl_xor(lrow0[i], m);
            lrow1[i] += __shfl_xor(lrow1[i], m);
        }
    }
    if (r16 == 0) {
#pragma unroll
        for (int i = 0; i < 4; i++) {
            redl[rg][kg * 4 + i][eh]      = lrow0[i];
            redl[rg][16 + kg * 4 + i][eh] = lrow1[i];
        }
    }
    __syncthreads();
    size_t prow0 = (size_t)z * BS_ + (size_t)b * S_ + qrow0;
    if (eh == 0 && r16 == 0) {
#pragma unroll
        for (int i = 0; i < 4; i++) {
            int q = kg * 4 + i;
            pl[prow0 + q]      = redl[rg][q][0] + redl[rg][q][1];
            pl[prow0 + 16 + q] = redl[rg][16 + q][0] + redl[rg][16 + q][1];
        }
    }
#pragma unroll
    for (int i = 0; i < 4; i++) {
#pragma unroll
        for (int cf = 0; cf < 8; cf++) {
            pacc[(prow0 + kg * 4 + i) * E_ + ebase + cf * 16 + r16]      = acc0[cf][i];
            pacc[(prow0 + 16 + kg * 4 + i) * E_ + ebase + cf * 16 + r16] = acc1[cf][i];
        }
    }
}

// ---------------- fused merge + residual + layernorm: x = LN(x + merge)*g + b ----------------
__global__ __launch_bounds__(256) void k_aln(const float* __restrict__ pacc,
                                             const float* __restrict__ pl,
                                             float* __restrict__ x,
                                             const float* __restrict__ g,
                                             const float* __restrict__ bb) {
    int wv = threadIdx.x >> 6, lane = threadIdx.x & 63;
    size_t row = (size_t)blockIdx.x * 4 + wv;
    float inv = 1.0f / (pl[row] + pl[BS_ + row]);
    f32x4 a0 = ((const f32x4*)(pacc + row * E_))[lane];
    f32x4 a1 = ((const f32x4*)(pacc + (size_t)BS_ * E_ + row * E_))[lane];
    f32x4 xv = ((const f32x4*)(x + row * E_))[lane];
    f32x4 v;
    float s = 0.f, sq = 0.f;
#pragma unroll
    for (int j = 0; j < 4; j++) {
        v[j] = xv[j] + (a0[j] + a1[j]) * inv;
        s += v[j]; sq += v[j] * v[j];
    }
#pragma unroll
    for (int m = 1; m <= 32; m <<= 1) { s += __shfl_xor(s, m); sq += __shfl_xor(sq, m); }
    float mean = s * (1.f / E_);
    float var = sq * (1.f / E_) - mean * mean;
    float rstd = rsqrtf(var + 1e-5f);
    f32x4 gv = ((const f32x4*)g)[lane];
    f32x4 bv = ((const f32x4*)bb)[lane];
    f32x4 o;
#pragma unroll
    for (int j = 0; j < 4; j++) o[j] = (v[j] - mean) * rstd * gv[j] + bv[j];
    ((f32x4*)(x + row * E_))[lane] = o;
}

// ---------------- W2 transpose to bf16 (tiled): (1024,256) -> (256,1024) ----------------
__global__ __launch_bounds__(256) void k_w2t(const float* __restrict__ W2l,
                                             __hip_bfloat16* __restrict__ w2t) {
    __shared__ __align__(16) __bf16 tile[64][72];
    int k0 = blockIdx.x * 64, e0 = blockIdx.y * 64;
    int tid = threadIdx.x;
#pragma unroll
    for (int half = 0; half < 2; half++) {
        int r  = half * 32 + (tid >> 3);      // k row
        int c8 = (tid & 7) * 8;               // e offset
        f32x4 v0 = *(const f32x4*)(W2l + (size_t)(k0 + r) * E_ + e0 + c8);
        f32x4 v1 = *(const f32x4*)(W2l + (size_t)(k0 + r) * E_ + e0 + c8 + 4);
#pragma unroll
        for (int j = 0; j < 4; j++) { tile[r][c8 + j] = (__bf16)v0[j]; tile[r][c8 + 4 + j] = (__bf16)v1[j]; }
    }
    __syncthreads();
#pragma unroll
    for (int half = 0; half < 2; half++) {
        int e  = half * 32 + (tid >> 3);
        int k8 = (tid & 7) * 8;
        bf16x8 v;
#pragma unroll
        for (int j = 0; j < 8; j++) v[j] = tile[k8 + j][e];
        *(bf16x8*)(w2t + (size_t)(e0 + e) * FF_ + k0 + k8) = v;
    }
}

// ---------------- fused FFN: rank-8 h + GEMM + bias + residual + LN, dbuf 1-barrier/iter ----------------
__global__ __launch_bounds__(256) void k_ffn(const float* __restrict__ x,
                                             const float* __restrict__ theta_l,
                                             const float* __restrict__ W1l,
                                             const float* __restrict__ b1l,
                                             const __hip_bfloat16* __restrict__ w2t,
                                             const float* __restrict__ b2l,
                                             const float* __restrict__ g,
                                             const float* __restrict__ bb) {
    __shared__ __align__(16) __bf16 Bld[2][256 * 64];   // [buf][e][k64] linear (global_load_lds dest)
    __shared__ __align__(16) __bf16 Ald[2][32 * 64];    // [buf][r][k64], chunk ^= r&7
    __shared__ float qmld[32][9];
    __shared__ float reds[32][4][2];
    int tid = threadIdx.x;
    int wv = tid >> 6, lane = tid & 63;
    int r16 = lane & 15, kg = lane >> 4;
    int rbase = blockIdx.x * 32;
    int ebQ = wv * 64;
    const int NT = FF_ / 64;   // 16

    {   // qm[r][i] = cos(x[row][i]) * cos(theta[i])
        int r = tid >> 3, i = tid & 7;
        qmld[r][i] = __cosf(x[(size_t)(rbase + r) * E_ + i]) * __cosf(theta_l[i]);
    }

    f32x4 w[18];   // W1 chunk (16) + b1 chunk (2), all constant-indexed

    auto issue_B = [&](int kt, int buf) {
#pragma unroll
        for (int s = 0; s < 8; s++) {
            int seg = wv * 8 + s;                       // 32 x 1KB segments
            int e = seg * 8 + (lane >> 3);
            int c = lane & 7;
            const __hip_bfloat16* src = w2t + (size_t)e * FF_ + kt * 64 + ((c ^ (e & 7)) * 8);
            __builtin_amdgcn_global_load_lds((const __attribute__((address_space(1))) void*)src,
                                             (__attribute__((address_space(3))) void*)(&Bld[buf][seg * 512]),
                                             16, 0, 0);
        }
    };
    auto load_W1 = [&](int kt) {
        int c = tid & 7;
        int k = kt * 64 + c * 8;
#pragma unroll
        for (int i = 0; i < 8; i++) {
            w[2 * i]     = *(const f32x4*)(W1l + (size_t)i * FF_ + k);
            w[2 * i + 1] = *(const f32x4*)(W1l + (size_t)i * FF_ + k + 4);
        }
        w[16] = *(const f32x4*)(b1l + k);
        w[17] = *(const f32x4*)(b1l + k + 4);
    };
    auto math_h = [&](int buf) {
        int r = tid >> 3, c = tid & 7;
        f32x4 h0 = w[16], h1 = w[17];
#pragma unroll
        for (int i = 0; i < 8; i++) {
            float qv = qmld[r][i];
#pragma unroll
            for (int j = 0; j < 4; j++) {
                h0[j] = fmaf(qv, w[2 * i][j], h0[j]);
                h1[j] = fmaf(qv, w[2 * i + 1][j], h1[j]);
            }
        }
        bf16x8 hv;
#pragma unroll
        for (int j = 0; j < 4; j++) {
            hv[j]     = (__bf16)fmaxf(h0[j], 0.f);
            hv[4 + j] = (__bf16)fmaxf(h1[j], 0.f);
        }
        *(bf16x8*)&Ald[buf][r * 64 + ((c ^ (r & 7)) * 8)] = hv;
    };

    // prologue
    issue_B(0, 0);
    load_W1(0);
    __syncthreads();          // qmld visible; B(0) drained
    math_h(0);
    __syncthreads();          // Ald[0] visible

    f32x4 acc[2][4];
#pragma unroll
    for (int qs = 0; qs < 2; qs++)
#pragma unroll
        for (int cf = 0; cf < 4; cf++) acc[qs][cf] = (f32x4){0.f, 0.f, 0.f, 0.f};

    for (int kt = 0; kt < NT; kt++) {
        int cur = kt & 1;
        bool more = (kt + 1 < NT);
        if (more) {
            issue_B(kt + 1, cur ^ 1);   // in flight across MFMA phase
            load_W1(kt + 1);            // reg prefetch, consumed after MFMA
        }
        bf16x8 aq[2][2];
#pragma unroll
        for (int qs = 0; qs < 2; qs++)
#pragma unroll
            for (int kk = 0; kk < 2; kk++)
                aq[qs][kk] = *(const bf16x8*)&Ald[cur][(qs * 16 + r16) * 64 + (((kk * 4 + kg) ^ (r16 & 7)) * 8)];
#pragma unroll
        for (int cf = 0; cf < 4; cf++) {
            int e = ebQ + cf * 16 + r16;
#pragma unroll
            for (int kk = 0; kk < 2; kk++) {
                bf16x8 bv = *(const bf16x8*)&Bld[cur][e * 64 + (((kk * 4 + kg) ^ (e & 7)) * 8)];
                acc[0][cf] = MFMA16(aq[0][kk], bv, acc[0][cf]);
                acc[1][cf] = MFMA16(aq[1][kk], bv, acc[1][cf]);
            }
        }
        if (more) {
            math_h(cur ^ 1);            // W1 regs already resident
            __syncthreads();            // drains B(kt+1) + Ald writes; guards buf reuse
        }
    }

    // epilogue: bias + residual + layernorm
    float sA[2][4] = {{0.f,0.f,0.f,0.f},{0.f,0.f,0.f,0.f}};
    float sQ[2][4] = {{0.f,0.f,0.f,0.f},{0.f,0.f,0.f,0.f}};
#pragma unroll
    for (int qs = 0; qs < 2; qs++)
#pragma unroll
        for (int cf = 0; cf < 4; cf++) {
            int e = ebQ + cf * 16 + r16;
            float b2v = b2l[e];
#pragma unroll
            for (int i = 0; i < 4; i++) {
                size_t orow = (size_t)rbase + qs * 16 + kg * 4 + i;
                float t = acc[qs][cf][i] + b2v + x[orow * E_ + e];
                acc[qs][cf][i] = t;
                sA[qs][i] += t; sQ[qs][i] += t * t;
            }
        }
#pragma unroll
    for (int qs = 0; qs < 2; qs++)
#pragma unroll
        for (int i = 0; i < 4; i++) {
#pragma unroll
            for (int m = 1; m <= 8; m <<= 1) {
                sA[qs][i] += __shfl_xor(sA[qs][i], m);
                sQ[qs][i] += __shfl_xor(sQ[qs][i], m);
            }
        }
    if (r16 == 0) {
#pragma unroll
        for (int qs = 0; qs < 2; qs++)
#pragma unroll
            for (int i = 0; i < 4; i++) {
                int row = qs * 16 + kg * 4 + i;
                reds[row][wv][0] = sA[qs][i];
                reds[row][wv][1] = sQ[qs][i];
            }
    }
    __syncthreads();
    float mean[2][4], rstd[2][4];
#pragma unroll
    for (int qs = 0; qs < 2; qs++)
#pragma unroll
        for (int i = 0; i < 4; i++) {
            int row = qs * 16 + kg * 4 + i;
            float S = reds[row][0][0] + reds[row][1][0] + reds[row][2][0] + reds[row][3][0];
            float Q = reds[row][0][1] + reds[row][1][1] + reds[row][2][1] + reds[row][3][1];
            mean[qs][i] = S * (1.f / E_);
            float var = Q * (1.f / E_) - mean[qs][i] * mean[qs][i];
            rstd[qs][i] = rsqrtf(var + 1e-5f);
        }
    float* xo = (float*)x;
#pragma unroll
    for (int qs = 0; qs < 2; qs++)
#pragma unroll
        for (int cf = 0; cf < 4; cf++) {
            int e = ebQ + cf * 16 + r16;
            float gv = g[e], bv = bb[e];
#pragma unroll
            for (int i = 0; i < 4; i++) {
                size_t orow = (size_t)rbase + qs * 16 + kg * 4 + i;
                xo[orow * E_ + e] = (acc[qs][cf][i] - mean[qs][i]) * rstd[qs][i] * gv + bv;
            }
        }
}

// ---------------- mean over S (two-stage, deterministic) ----------------
__global__ __launch_bounds__(256) void k_mean(const float* __restrict__ x, float* __restrict__ psum) {
    int c = blockIdx.x, b = blockIdx.y, e = threadIdx.x;
    float s = 0.f;
    size_t base = ((size_t)b * S_ + c * 128) * E_ + e;
    for (int r = 0; r < 128; r++) s += x[base + (size_t)r * E_];
    psum[(c * 8 + b) * E_ + e] = s;
}

__global__ __launch_bounds__(256) void k_mean2(const float* __restrict__ psum, float* __restrict__ xmean) {
    int idx = blockIdx.x * 256 + threadIdx.x;   // 0..2047 -> (b,e)
    int b = idx >> 8, e = idx & 255;
    float s = 0.f;
    for (int c = 0; c < 16; c++) s += psum[(c * 8 + b) * E_ + e];
    xmean[idx] = s * (1.f / S_);
}

// ---------------- classifier ----------------
__global__ __launch_bounds__(128) void k_cls(const float* __restrict__ xmean,
                                             const float* __restrict__ Wc,
                                             const float* __restrict__ bc,
                                             float* __restrict__ outp) {
    int t = threadIdx.x;
    if (t >= B_ * NC_) return;
    int b = t / NC_, c = t % NC_;
    float s = bc[c];
    for (int e = 0; e < E_; e++) s += xmean[b * E_ + e] * Wc[e * NC_ + c];
    outp[t] = s;
}

extern "C" void kernel_launch(void* const* d_in, const int* in_sizes, int n_in,
                              void* d_out, int out_size, void* d_ws, size_t ws_size,
                              hipStream_t stream) {
    (void)in_sizes; (void)n_in; (void)out_size; (void)ws_size;
    const int*   tokens = (const int*)d_in[0];
    const float* emb    = (const float*)d_in[1];
    const float* phi    = (const float*)d_in[2];
    const float* theta  = (const float*)d_in[3];
    const float* W1     = (const float*)d_in[4];
    const float* b1     = (const float*)d_in[5];
    const float* W2     = (const float*)d_in[6];
    const float* b2     = (const float*)d_in[7];
    const float* g1     = (const float*)d_in[8];
    const float* beta1  = (const float*)d_in[9];
    const float* g2     = (const float*)d_in[10];
    const float* beta2  = (const float*)d_in[11];
    const float* Wc     = (const float*)d_in[12];
    const float* bc     = (const float*)d_in[13];
    float* outp = (float*)d_out;

    // workspace layout
    float* xbuf = (float*)d_ws;                                        // BS_*E_ f32
    __hip_bfloat16* qbf = (__hip_bfloat16*)(xbuf + (size_t)BS_ * E_);  // BS_*E_ bf16
    __hip_bfloat16* qT  = qbf + (size_t)BS_ * E_;                      // BS_*E_ bf16
    __hip_bfloat16* w2t = qT + (size_t)BS_ * E_;                       // E_*FF_ bf16
    float* psum  = (float*)(w2t + (size_t)E_ * FF_);                   // 16*8*E_ f32
    float* xmean = psum + 16 * 8 * E_;                                 // B_*E_ f32
    float* pl    = xmean + B_ * E_;                                    // NSPLIT*BS_ f32
    float* pacc  = pl + NSPLIT * BS_;                                  // NSPLIT*BS_*E_ f32

    k_embed<<<BS_, 256, 0, stream>>>(tokens, emb, xbuf);

    for (int l = 0; l < 4; l++) {
        k_qt<<<dim3(S_ / 64, E_ / 64, B_), 256, 0, stream>>>(xbuf, phi + l * NQ_, qbf, qT);
        k_attn<<<(S_ / 64) * B_ * NSPLIT, 256, 0, stream>>>(qbf, qT, pacc, pl);
        k_aln<<<BS_ / 4, 256, 0, stream>>>(pacc, pl, xbuf, g1 + l * E_, beta1 + l * E_);
        k_w2t<<<dim3(FF_ / 64, E_ / 64), 256, 0, stream>>>(W2 + (size_t)l * FF_ * E_, w2t);
        k_ffn<<<BS_ / 32, 256, 0, stream>>>(xbuf, theta + l * NQ_,
                                            W1 + (size_t)l * NQ_ * FF_, b1 + (size_t)l * FF_,
                                            w2t, b2 + (size_t)l * E_,
                                            g2 + l * E_, beta2 + l * E_);
    }

    k_mean<<<dim3(16, B_), 256, 0, stream>>>(xbuf, psum);
    k_mean2<<<8, 256, 0, stream>>>(psum, xmean);
    k_cls<<<1, 128, 0, stream>>>(xmean, Wc, bc, outp);
}